// Round 6
// baseline (567.282 us; speedup 1.0000x reference)
//
#include <hip/hip_runtime.h>
#include <math.h>

// Problem constants (fixed by the reference)
#define NN   32768
#define BG   128
#define SG   256
#define EE   524288
#define DIN_ 128
#define DH_  256
#define NH   8
#define HD_  32
#define DFF_ 1024
#define EPS_ 1e-5f

typedef __attribute__((ext_vector_type(8))) short bf16x8;
typedef __attribute__((ext_vector_type(4))) float f32x4;
typedef __attribute__((ext_vector_type(2))) unsigned int u32x2;
typedef __attribute__((ext_vector_type(4))) unsigned int u32x4;

__device__ __forceinline__ unsigned short f2bf(float f) {
    unsigned int u = __builtin_bit_cast(unsigned int, f);
    unsigned int r = u + 0x7FFFu + ((u >> 16) & 1u);
    return (unsigned short)(r >> 16);
}
__device__ __forceinline__ float bf2f(unsigned short u) {
    return __builtin_bit_cast(float, (unsigned int)u << 16);
}
__device__ __forceinline__ unsigned int pack2bf(float a, float b) {
    return (unsigned int)f2bf(a) | ((unsigned int)f2bf(b) << 16);
}
// Async global->LDS DMA, 16 B per lane (dest = wave-uniform base + lane*16).
__device__ __forceinline__ void glds16(const unsigned short* g, unsigned short* l) {
    __builtin_amdgcn_global_load_lds(
        (const __attribute__((address_space(1))) void*)g,
        (__attribute__((address_space(3))) void*)l, 16, 0, 0);
}
// s_waitcnt with vmcnt(N) only (exp/lgkm masked off).
#define WAIT_VM8() __builtin_amdgcn_s_waitcnt(0x0F78)
#define WAIT_VM4() __builtin_amdgcn_s_waitcnt(0x0F74)
#define WAIT_VM2() __builtin_amdgcn_s_waitcnt(0x0F72)
#define WAIT_VM1() __builtin_amdgcn_s_waitcnt(0x0F71)
#define WAIT_VM0() __builtin_amdgcn_s_waitcnt(0x0F70)

// Softmax pre-scale: 1/sqrt(32) * log2(e), folded into wq/bq at transpose time.
#define QSCALE (0.17677669529663689f * 1.4426950408889634f)

// ---------------------------------------------------------------------------
// init_avg_h: per-graph mean of raw x (graph b = rows [b*256, b*256+256)).
__global__ __launch_bounds__(128) void initavg_kernel(const float* __restrict__ X,
                                                      float* __restrict__ out2) {
    int b = blockIdx.x, j = threadIdx.x;
    float s = 0.f;
    for (int r = 0; r < SG; ++r) s += X[(size_t)(b * SG + r) * DIN_ + j];
    out2[b * DIN_ + j] = s * (1.f / (float)SG);
}

// Column sum / sumsq partials for BatchNorm stats; fp32 input (BN1).
template <int C>
__global__ __launch_bounds__(C) void colstats_kernel(const float* __restrict__ X,
                                                     float* __restrict__ csum,
                                                     float* __restrict__ csumsq) {
    int j = threadIdx.x;
    size_t r0 = (size_t)blockIdx.x * 256;
    float s = 0.f, sq = 0.f;
    for (int r = 0; r < 256; ++r) {
        float v = X[(r0 + r) * C + j];
        s += v; sq += v * v;
    }
    atomicAdd(&csum[j], s);
    atomicAdd(&csumsq[j], sq);
}

// bf16-input variant (BN2 stats over h1b).
template <int C>
__global__ __launch_bounds__(C) void colstats_b_kernel(const unsigned short* __restrict__ X,
                                                       float* __restrict__ csum,
                                                       float* __restrict__ csumsq) {
    int j = threadIdx.x;
    size_t r0 = (size_t)blockIdx.x * 256;
    float s = 0.f, sq = 0.f;
    for (int r = 0; r < 256; ++r) {
        float v = bf2f(X[(r0 + r) * C + j]);
        s += v; sq += v * v;
    }
    atomicAdd(&csum[j], s);
    atomicAdd(&csumsq[j], sq);
}

template <int C>
__global__ __launch_bounds__(C) void bnfin_kernel(const float* __restrict__ csum,
                                                  const float* __restrict__ csumsq,
                                                  const float* __restrict__ g,
                                                  const float* __restrict__ b,
                                                  float* __restrict__ scale,
                                                  float* __restrict__ shift) {
    int j = threadIdx.x;
    float mu  = csum[j] * (1.f / (float)NN);
    float var = csumsq[j] * (1.f / (float)NN) - mu * mu;
    float s = g[j] * rsqrtf(var + EPS_);
    scale[j] = s;
    shift[j] = b[j] - mu * s;
}

// BN apply, fp32 in -> bf16 out (BN1).
template <int C>
__global__ __launch_bounds__(256) void bnapply_kernel(const float* __restrict__ X,
                                                      const float* __restrict__ sc,
                                                      const float* __restrict__ sh,
                                                      unsigned short* __restrict__ Y) {
    int i = blockIdx.x * 256 + threadIdx.x;
    int j = i & (C - 1);
    Y[i] = f2bf(X[i] * sc[j] + sh[j]);
}

// Weight cast+transpose: W[K,N] fp32 -> Wt[N,K] bf16, optional scalar scale.
__global__ __launch_bounds__(256) void wtrans_kernel(const float* __restrict__ W,
                                                     unsigned short* __restrict__ Wt,
                                                     int K, int N, float scale) {
    int idx = blockIdx.x * 256 + threadIdx.x;
    if (idx < K * N) {
        int n = idx / K, k = idx - n * K;
        Wt[idx] = f2bf(W[(size_t)k * N + n] * scale);
    }
}

// Concat Q/K/V biases into one fp32[768]; Q part pre-scaled by QSCALE.
__global__ __launch_bounds__(256) void bcat_kernel(const float* __restrict__ bq,
                                                   const float* __restrict__ bk,
                                                   const float* __restrict__ bv,
                                                   float* __restrict__ o) {
    int j = threadIdx.x;
    if (blockIdx.x == 0) o[j] = bq[j] * QSCALE;
    else if (blockIdx.x == 1) o[DH_ + j] = bk[j];
    else o[2 * DH_ + j] = bv[j];
}

// ---------------------------------------------------------------------------
// CSR build
__global__ __launch_bounds__(256) void deg_kernel(const int* __restrict__ col,
                                                  int* __restrict__ deg) {
    int e = blockIdx.x * 256 + threadIdx.x;
    if (e < EE) atomicAdd(&deg[col[e]], 1);
}

__global__ __launch_bounds__(1024) void scan_kernel(const int* __restrict__ deg,
                                                    int* __restrict__ off,
                                                    float* __restrict__ dis) {
    __shared__ int sums[1024];
    int t = threadIdx.x;
    int base = t * 32;
    int loc[32];
    int run = 0;
#pragma unroll
    for (int i = 0; i < 32; ++i) { loc[i] = run; run += deg[base + i]; }
    sums[t] = run;
    __syncthreads();
    for (int d = 1; d < 1024; d <<= 1) {
        int tmp = (t >= d) ? sums[t - d] : 0;
        __syncthreads();
        sums[t] += tmp;
        __syncthreads();
    }
    int excl = sums[t] - run;
#pragma unroll
    for (int i = 0; i < 32; ++i) {
        off[base + i] = excl + loc[i];
        dis[base + i] = rsqrtf((float)(deg[base + i] + 1));
    }
    if (t == 1023) off[NN] = sums[1023];
}

__global__ __launch_bounds__(256) void scatter_kernel(const int* __restrict__ row,
                                                      const int* __restrict__ col,
                                                      const int* __restrict__ off,
                                                      int* __restrict__ cnt,
                                                      int* __restrict__ srow) {
    int e = blockIdx.x * 256 + threadIdx.x;
    if (e < EE) {
        int c = col[e];
        int p = off[c] + atomicAdd(&cnt[c], 1);
        srow[p] = row[e];
    }
}

// ---------------------------------------------------------------------------
// bf16 GCN aggregation, 4x-unrolled edge loop for MLP.
template <int C, int FUSE_BN>
__global__ __launch_bounds__(256) void aggb_kernel(const unsigned short* __restrict__ X,
                                                   const int* __restrict__ off,
                                                   const int* __restrict__ srow,
                                                   const float* __restrict__ dis,
                                                   const float* __restrict__ scl,
                                                   const float* __restrict__ shf,
                                                   unsigned short* __restrict__ Y) {
    constexpr int EPL = C / 64;
    int lane = threadIdx.x & 63;
    int c = blockIdx.x * 4 + (threadIdx.x >> 6);
    float dc = dis[c];
    float acc[EPL];
    float wsum = dc;
    {
        unsigned short t[EPL];
        const unsigned short* xc = X + (size_t)c * C + lane * EPL;
        if constexpr (EPL == 4) *(uint2*)t = *(const uint2*)xc;
        else *(unsigned int*)t = *(const unsigned int*)xc;
#pragma unroll
        for (int e2 = 0; e2 < EPL; ++e2) acc[e2] = dc * bf2f(t[e2]);
    }
    int s = off[c], en = off[c + 1];
    int i = s;
    for (; i + 4 <= en; i += 4) {
        int r0 = srow[i], r1 = srow[i + 1], r2 = srow[i + 2], r3 = srow[i + 3];
        float d0 = dis[r0], d1 = dis[r1], d2 = dis[r2], d3 = dis[r3];
        unsigned short t0[EPL], t1[EPL], t2[EPL], t3[EPL];
        const unsigned short* p0 = X + (size_t)r0 * C + lane * EPL;
        const unsigned short* p1 = X + (size_t)r1 * C + lane * EPL;
        const unsigned short* p2 = X + (size_t)r2 * C + lane * EPL;
        const unsigned short* p3 = X + (size_t)r3 * C + lane * EPL;
        if constexpr (EPL == 4) {
            *(uint2*)t0 = *(const uint2*)p0;
            *(uint2*)t1 = *(const uint2*)p1;
            *(uint2*)t2 = *(const uint2*)p2;
            *(uint2*)t3 = *(const uint2*)p3;
        } else {
            *(unsigned int*)t0 = *(const unsigned int*)p0;
            *(unsigned int*)t1 = *(const unsigned int*)p1;
            *(unsigned int*)t2 = *(const unsigned int*)p2;
            *(unsigned int*)t3 = *(const unsigned int*)p3;
        }
        wsum += d0 + d1 + d2 + d3;
#pragma unroll
        for (int e2 = 0; e2 < EPL; ++e2) {
            acc[e2] += d0 * bf2f(t0[e2]) + d1 * bf2f(t1[e2]) +
                       d2 * bf2f(t2[e2]) + d3 * bf2f(t3[e2]);
        }
    }
    for (; i < en; ++i) {
        int r = srow[i];
        float dr = dis[r];
        unsigned short t[EPL];
        const unsigned short* xr = X + (size_t)r * C + lane * EPL;
        if constexpr (EPL == 4) *(uint2*)t = *(const uint2*)xr;
        else *(unsigned int*)t = *(const unsigned int*)xr;
        wsum += dr;
#pragma unroll
        for (int e2 = 0; e2 < EPL; ++e2) acc[e2] += dr * bf2f(t[e2]);
    }
    unsigned short t[EPL];
#pragma unroll
    for (int e2 = 0; e2 < EPL; ++e2) {
        float v;
        if constexpr (FUSE_BN) {
            int j = lane * EPL + e2;
            v = dc * (scl[j] * acc[e2] + shf[j] * wsum);
        } else {
            v = dc * acc[e2];
        }
        t[e2] = f2bf(v);
    }
    unsigned short* yc = Y + (size_t)c * C + lane * EPL;
    if constexpr (EPL == 4) *(uint2*)yc = *(const uint2*)t;
    else *(unsigned int*)yc = *(const unsigned int*)t;
}

// ---------------------------------------------------------------------------
// MT=64 bf16 MFMA GEMM (conv1/conv2/oproj), proven round-3 structure:
// triple-buffered glds staging (depth-2 in flight, counted vmcnt), raw
// s_barrier, XCD swizzle, XOR-swizzled staging, coalesced LDS C epilogue.
// Waves 0-3 stage B (2 glds), waves 4-7 stage A (1 glds). 36 KB -> 4 blk/CU.
template <int MT>
__global__ __launch_bounds__(512, 8) void gemm_bf16_kernel(
    const unsigned short* __restrict__ A,
    const unsigned short* __restrict__ Bt,
    unsigned short* __restrict__ Cb,
    int M, int K, int N,
    const float* __restrict__ bias,
    const unsigned short* __restrict__ resb,
    const float* __restrict__ inter,
    int do_relu, int relu_first) {
    constexpr int LDP = 32;
    constexpr int CP = 136;
    constexpr int MI = MT / 64;
    constexpr int STG = 6144;
    constexpr int BOFS = 2048;
    constexpr int SMEMSZ = 3 * STG;
    __shared__ unsigned short Smem[SMEMSZ];
    unsigned short* Cs = Smem;
    int gx = gridDim.x, gyP = gridDim.y >> 3;
    int d = blockIdx.y * gx + blockIdx.x;
    int xcd = d & 7, j2 = d >> 3;
    int bm = (xcd * gyP + j2 / gx) * MT;
    int bn = (j2 % gx) * 128;
    int tid = threadIdx.x;
    int wave = tid >> 6, lane = tid & 63;
    int wm = (wave >> 1) * (MT / 4);
    int wn = (wave & 1) * 64;
    int lrc = lane & 15;
    int koct = lane >> 4;
    int rsw = (lrc >> 1) & 3;
    int rofs = (koct ^ rsw) * 8;

    int cg = (lane & 3) ^ ((lane >> 3) & 3);
    int skk = cg * 8;

    const unsigned short* g0 = nullptr;
    int lofs64 = 0;
    int nloads = 2;
    size_t gstride16 = 0;
    if (wave < 4) {                       // B-stager: rows wave*32..+31
        int sr = wave * 32 + (lane >> 2);
        g0 = Bt + (size_t)(bn + sr) * K + skk;
        lofs64 = BOFS + wave * 1024 + lane * 8;
        nloads = 2;
        gstride16 = (size_t)16 * K;
    } else {                              // A-stager: rows (wave-4)*16..+15
        int sr = (wave - 4) * 16 + (lane >> 2);
        g0 = A + (size_t)(bm + sr) * K + skk;
        lofs64 = (wave - 4) * 512 + lane * 8;
        nloads = 1;
    }

    f32x4 acc[MI][4];
#pragma unroll
    for (int i = 0; i < MI; ++i)
#pragma unroll
        for (int j = 0; j < 4; ++j) acc[i][j] = (f32x4){0.f, 0.f, 0.f, 0.f};

    // prologue: prefetch stages 0 and 1
    glds16(g0, Smem + lofs64);
    if (nloads == 2) glds16(g0 + gstride16, Smem + lofs64 + 512);
    glds16(g0 + 32, Smem + STG + lofs64);
    if (nloads == 2) glds16(g0 + 32 + gstride16, Smem + STG + lofs64 + 512);

    int rb = 0;
    for (int k0 = 0; k0 < K; k0 += 32) {
        if (k0 + 64 < K) {
            int wb = rb + 2; if (wb >= 3) wb -= 3;
            unsigned short* ld = Smem + wb * STG;
            glds16(g0 + k0 + 64, ld + lofs64);
            if (nloads == 2) {
                glds16(g0 + k0 + 64 + gstride16, ld + lofs64 + 512);
                WAIT_VM4();
            } else {
                WAIT_VM2();
            }
        } else if (k0 + 32 < K) {
            if (nloads == 2) WAIT_VM2(); else WAIT_VM1();
        } else {
            WAIT_VM0();
        }
        __builtin_amdgcn_s_barrier();
        const unsigned short* Ab = Smem + rb * STG;
        const unsigned short* Bb = Ab + BOFS;
        bf16x8 af[MI], bfr[4];
#pragma unroll
        for (int i = 0; i < MI; ++i)
            af[i] = *(const bf16x8*)(Ab + (wm + i * 16 + lrc) * LDP + rofs);
#pragma unroll
        for (int j = 0; j < 4; ++j)
            bfr[j] = *(const bf16x8*)(Bb + (wn + j * 16 + lrc) * LDP + rofs);
#pragma unroll
        for (int i = 0; i < MI; ++i)
#pragma unroll
            for (int j = 0; j < 4; ++j)
                acc[i][j] = __builtin_amdgcn_mfma_f32_16x16x32_bf16(af[i], bfr[j],
                                                                    acc[i][j], 0, 0, 0);
        __builtin_amdgcn_s_barrier();
        rb = (rb + 1 == 3) ? 0 : rb + 1;
    }
#pragma unroll
    for (int i = 0; i < MI; ++i) {
#pragma unroll
        for (int r = 0; r < 4; ++r) {
            int lrow = wm + i * 16 + koct * 4 + r;
            int grow = bm + lrow;
#pragma unroll
            for (int j = 0; j < 4; ++j) {
                int lcol = wn + j * 16 + lrc;
                int gcol = bn + lcol;
                float v = acc[i][j][r];
                if (bias) v += bias[gcol];
                if (relu_first) v = fmaxf(v, 0.f);
                if (resb) v += bf2f(resb[(size_t)grow * N + gcol]);
                if (inter) v += inter[(grow >> 8) * N + gcol];
                if (do_relu && !relu_first) v = fmaxf(v, 0.f);
                Cs[lrow * CP + lcol] = f2bf(v);
            }
        }
    }
    __syncthreads();
#pragma unroll
    for (int it = 0; it < MT / 32; ++it) {
        int row = it * 32 + (tid >> 4);
        int cc = (tid & 15) * 8;
        *(uint4*)(&Cb[(size_t)(bm + row) * N + bn + cc]) =
            *(const uint4*)(&Cs[row * CP + cc]);
    }
}

// ---------------------------------------------------------------------------
// 128x128 bf16 MFMA GEMM, 4 waves x 64x64 wave-tile (round-23, m97 shape).
// Round-5 diagnosis: the 8-wave 32x64 config pinned ff1 AND ff2 at 42 us
// (identical per-block-step cost, both pipes idle) -> per-step dependency
// chain bound: barrier -> ds_read (~120cy) -> only 8 MFMA -> barrier.
// Fix: 64x64 wave tile = 16 MFMA + 8 ds_read per step per wave (0.5
// reads/MFMA). Each wave stages 32 A-rows + 32 B-rows (4 glds/step);
// triple-buffered 16 KB stages (48 KB -> 3 blocks/CU = 12 waves/CU);
// steady-state vmcnt(8) keeps stages t+1,t+2 in flight. acc[4][4]=64 VGPR,
// launch_bounds(256,3) caps at 168 VGPR (no spill; round-4 lesson).
__global__ __launch_bounds__(256, 3) void gemm128w4_kernel(
    const unsigned short* __restrict__ A,
    const unsigned short* __restrict__ Bt,
    unsigned short* __restrict__ Cb,
    int M, int K, int N,
    const float* __restrict__ bias,
    const unsigned short* __restrict__ resb,
    const float* __restrict__ inter,
    int do_relu, int relu_first) {
    constexpr int LDP = 32;
    constexpr int CP = 136;
    constexpr int STG = 8192;                // shorts: A 8KB | B 8KB
    constexpr int BOFS = 4096;
    __shared__ unsigned short Smem[3 * STG]; // 48 KB (>= 34.8 KB C-tile union)
    unsigned short* Cs = Smem;
    int gx = gridDim.x, gyP = gridDim.y >> 3;
    int d = blockIdx.y * gx + blockIdx.x;
    int xcd = d & 7, j2 = d >> 3;
    int bm = (xcd * gyP + j2 / gx) * 128;
    int bn = (j2 % gx) * 128;
    int tid = threadIdx.x;
    int wave = tid >> 6, lane = tid & 63;
    int wm = (wave >> 1) * 64;               // 2 m-waves x 2 n-waves
    int wn = (wave & 1) * 64;
    int lrc = lane & 15;
    int koct = lane >> 4;
    int rsw = (lrc >> 1) & 3;
    int rofs = (koct ^ rsw) * 8;
    int cg = (lane & 3) ^ ((lane >> 3) & 3);
    int skk = cg * 8;

    // Each wave stages A rows [wave*32, +32) and B rows likewise:
    // two 16-row glds groups per operand (same per-16-row swizzle pattern
    // as the proven kernels; reader rofs math unchanged).
    int sr = wave * 32 + (lane >> 2);
    const unsigned short* gA0 = A + (size_t)(bm + sr) * K + skk;
    const unsigned short* gB0 = Bt + (size_t)(bn + sr) * K + skk;
    size_t g16 = (size_t)16 * K;
    int lofs = wave * 1024 + lane * 8;

    f32x4 acc[4][4];
#pragma unroll
    for (int i = 0; i < 4; ++i)
#pragma unroll
        for (int j = 0; j < 4; ++j) acc[i][j] = (f32x4){0.f, 0.f, 0.f, 0.f};

    // prologue: prefetch stages 0 and 1 (4 glds each)
#pragma unroll
    for (int st = 0; st < 2; ++st) {
        unsigned short* s = Smem + st * STG;
        glds16(gA0 + st * 32, s + lofs);
        glds16(gA0 + st * 32 + g16, s + lofs + 512);
        glds16(gB0 + st * 32, s + BOFS + lofs);
        glds16(gB0 + st * 32 + g16, s + BOFS + lofs + 512);
    }

    int rb = 0;
    for (int k0 = 0; k0 < K; k0 += 32) {
        if (k0 + 64 < K) {
            int wb = rb + 2; if (wb >= 3) wb -= 3;
            unsigned short* s = Smem + wb * STG;
            glds16(gA0 + k0 + 64, s + lofs);
            glds16(gA0 + k0 + 64 + g16, s + lofs + 512);
            glds16(gB0 + k0 + 64, s + BOFS + lofs);
            glds16(gB0 + k0 + 64 + g16, s + BOFS + lofs + 512);
            WAIT_VM8();                      // drain stage t; t+1,t+2 in flight
        } else if (k0 + 32 < K) {
            WAIT_VM4();
        } else {
            WAIT_VM0();
        }
        __builtin_amdgcn_s_barrier();
        const unsigned short* Ab = Smem + rb * STG;
        const unsigned short* Bb = Ab + BOFS;
        bf16x8 af[4], bfr[4];
#pragma unroll
        for (int i = 0; i < 4; ++i)
            af[i] = *(const bf16x8*)(Ab + (wm + i * 16 + lrc) * LDP + rofs);
#pragma unroll
        for (int j = 0; j < 4; ++j)
            bfr[j] = *(const bf16x8*)(Bb + (wn + j * 16 + lrc) * LDP + rofs);
#pragma unroll
        for (int i = 0; i < 4; ++i)
#pragma unroll
            for (int j = 0; j < 4; ++j)
                acc[i][j] = __builtin_amdgcn_mfma_f32_16x16x32_bf16(af[i], bfr[j],
                                                                    acc[i][j], 0, 0, 0);
        __builtin_amdgcn_s_barrier();
        rb = (rb + 1 == 3) ? 0 : rb + 1;
    }
    // Epilogue: bias/relu/res/inter in regs, bf16 stage into Cs, coalesced out.
#pragma unroll
    for (int i = 0; i < 4; ++i) {
#pragma unroll
        for (int r = 0; r < 4; ++r) {
            int lrow = wm + i * 16 + koct * 4 + r;
            int grow = bm + lrow;
#pragma unroll
            for (int j = 0; j < 4; ++j) {
                int lcol = wn + j * 16 + lrc;
                int gcol = bn + lcol;
                float v = acc[i][j][r];
                if (bias) v += bias[gcol];
                if (relu_first) v = fmaxf(v, 0.f);
                if (resb) v += bf2f(resb[(size_t)grow * N + gcol]);
                if (inter) v += inter[(grow >> 8) * N + gcol];
                if (do_relu && !relu_first) v = fmaxf(v, 0.f);
                Cs[lrow * CP + lcol] = f2bf(v);
            }
        }
    }
    __syncthreads();
    // Coalesced copy-out: 8 iters x 16 rows; one uint4 (16 B) per thread.
#pragma unroll
    for (int it = 0; it < 8; ++it) {
        int row = it * 16 + (tid >> 4);
        int cc = (tid & 15) * 8;
        *(uint4*)(&Cb[(size_t)(bm + row) * N + bn + cc]) =
            *(const uint4*)(&Cs[row * CP + cc]);
    }
}

// ---------------------------------------------------------------------------
// MFMA flash attention, transposed-score, no online softmax.
// P kept fully in-register: QK^T C-fragment -> v_cvt_pk_bf16_f32 ->
// permlane32_swap + permlane16_swap -> PV A-fragment. No Ps LDS buffer
// (34.3 KB LDS -> 4 blocks/CU, matching the 1024-block grid).
__global__ __launch_bounds__(256, 4) void attn_mfma_kernel(
    const unsigned short* __restrict__ QKV,
    unsigned short* __restrict__ Ob) {
    int b = blockIdx.x >> 3, h = blockIdx.x & 7;
    __shared__ unsigned short Ks[256 * 32];    // XOR-swizzled chunks
    __shared__ unsigned short Vt[32 * 264];    // [d][key 256 + pad]
    __shared__ float Lc[4 * 64];               // per-wave l broadcast
    const unsigned short* kg = QKV + (size_t)b * 256 * 768 + 256 + h * 32;
    const unsigned short* vg = QKV + (size_t)b * 256 * 768 + 512 + h * 32;
    int tid = threadIdx.x;
#pragma unroll
    for (int it = 0; it < 4; ++it) {
        int c = it * 256 + tid;
        int row = c >> 2, ch = c & 3;
        int slot = ch ^ ((row >> 1) & 3);
        *(uint4*)(Ks + row * 32 + slot * 8) =
            *(const uint4*)(kg + (size_t)row * 768 + ch * 8);
    }
#pragma unroll
    for (int it = 0; it < 4; ++it) {
        int c = it * 256 + tid;
        int key = c >> 2, d0 = (c & 3) * 8;
        unsigned short tmp[8];
        *(uint4*)tmp = *(const uint4*)(vg + (size_t)key * 768 + d0);
#pragma unroll
        for (int j = 0; j < 8; ++j) Vt[(d0 + j) * 264 + key] = tmp[j];
    }
    __syncthreads();

    int wave = tid >> 6, lane = tid & 63;
    int lr = lane & 15, koct = lane >> 4;
    int s4 = (lr >> 1) & 3;
    int qrow0 = b * 256 + wave * 64;
    bf16x8 qf[4];
#pragma unroll
    for (int j = 0; j < 4; ++j)
        qf[j] = *(const bf16x8*)(QKV + (size_t)(qrow0 + j * 16 + lr) * 768 + h * 32 + koct * 8);

    f32x4 Oa[4][2];
    float lp[4];
#pragma unroll
    for (int i = 0; i < 4; ++i) {
        Oa[i][0] = (f32x4){0.f, 0.f, 0.f, 0.f};
        Oa[i][1] = (f32x4){0.f, 0.f, 0.f, 0.f};
        lp[i] = 0.f;
    }
    float* Lw = Lc + wave * 64;

    for (int kc = 0; kc < 256; kc += 32) {
        bf16x8 kf0 = *(const bf16x8*)(Ks + (kc + lr) * 32 + (koct ^ s4) * 8);
        bf16x8 kf1 = *(const bf16x8*)(Ks + (kc + 16 + lr) * 32 + (koct ^ s4) * 8);
        bf16x8 pfr[4];
#pragma unroll
        for (int j = 0; j < 4; ++j) {
            f32x4 St0 = __builtin_amdgcn_mfma_f32_16x16x32_bf16(kf0, qf[j],
                            (f32x4){0.f, 0.f, 0.f, 0.f}, 0, 0, 0);
            f32x4 St1 = __builtin_amdgcn_mfma_f32_16x16x32_bf16(kf1, qf[j],
                            (f32x4){0.f, 0.f, 0.f, 0.f}, 0, 0, 0);
            float p0[4], p1[4], ps = 0.f;
#pragma unroll
            for (int r = 0; r < 4; ++r) {
                p0[r] = exp2f(St0[r]); p1[r] = exp2f(St1[r]);
                ps += p0[r] + p1[r];
            }
            lp[j] += ps;
            unsigned int w0a, w0b, w1a, w1b;
            asm("v_cvt_pk_bf16_f32 %0, %1, %2" : "=v"(w0a) : "v"(p0[0]), "v"(p0[1]));
            asm("v_cvt_pk_bf16_f32 %0, %1, %2" : "=v"(w0b) : "v"(p0[2]), "v"(p0[3]));
            asm("v_cvt_pk_bf16_f32 %0, %1, %2" : "=v"(w1a) : "v"(p1[0]), "v"(p1[1]));
            asm("v_cvt_pk_bf16_f32 %0, %1, %2" : "=v"(w1b) : "v"(p1[2]), "v"(p1[3]));
            u32x2 sa = __builtin_amdgcn_permlane32_swap(w0a, w1a, false, false);
            u32x2 da = __builtin_amdgcn_permlane16_swap(sa[0], sa[1], false, false);
            u32x2 sb = __builtin_amdgcn_permlane32_swap(w0b, w1b, false, false);
            u32x2 db = __builtin_amdgcn_permlane16_swap(sb[0], sb[1], false, false);
            u32x4 pw = {da[0], db[0], da[1], db[1]};
            pfr[j] = __builtin_bit_cast(bf16x8, pw);
        }
        bf16x8 vf0 = *(const bf16x8*)(Vt + lr * 264 + kc + koct * 8);
        bf16x8 vf1 = *(const bf16x8*)(Vt + (16 + lr) * 264 + kc + koct * 8);
#pragma unroll
        for (int i = 0; i < 4; ++i) {
            Oa[i][0] = __builtin_amdgcn_mfma_f32_16x16x32_bf16(pfr[i], vf0, Oa[i][0], 0, 0, 0);
            Oa[i][1] = __builtin_amdgcn_mfma_f32_16x16x32_bf16(pfr[i], vf1, Oa[i][1], 0, 0, 0);
        }
    }
#pragma unroll
    for (int j = 0; j < 4; ++j) {
        lp[j] += __shfl_xor(lp[j], 16);
        lp[j] += __shfl_xor(lp[j], 32);
    }
    if (koct == 0) {
#pragma unroll
        for (int j = 0; j < 4; ++j) Lw[j * 16 + lr] = lp[j];
    }
    __builtin_amdgcn_s_waitcnt(0);
#pragma unroll
    for (int i = 0; i < 4; ++i) {
        f32x4 l4 = *(const f32x4*)(Lw + i * 16 + koct * 4);
#pragma unroll
        for (int r = 0; r < 4; ++r) {
            float inv = 1.f / l4[r];
            int row = qrow0 + i * 16 + koct * 4 + r;
#pragma unroll
            for (int jn = 0; jn < 2; ++jn) {
                int col = h * 32 + jn * 16 + lr;
                Ob[(size_t)row * 256 + col] = f2bf(Oa[i][jn][r] * inv);
            }
        }
    }
}

// LayerNorm over last dim (256), bf16 in -> bf16 out. One wave per row.
// Vectorized 8 B loads/stores (lane owns cols lane*4..+3).
__global__ __launch_bounds__(256) void lnb_kernel(const unsigned short* __restrict__ Z,
                                                  unsigned short* __restrict__ Out,
                                                  const float* __restrict__ g,
                                                  const float* __restrict__ bt) {
    int row = blockIdx.x * 4 + (threadIdx.x >> 6);
    int lane = threadIdx.x & 63;
    unsigned short tv[4];
    *(uint2*)tv = *(const uint2*)(Z + (size_t)row * DH_ + lane * 4);
    float v[4];
    float sum = 0.f;
#pragma unroll
    for (int i = 0; i < 4; ++i) { v[i] = bf2f(tv[i]); sum += v[i]; }
#pragma unroll
    for (int off = 32; off; off >>= 1) sum += __shfl_xor(sum, off);
    float mu = sum * (1.f / (float)DH_);
    float vs = 0.f;
#pragma unroll
    for (int i = 0; i < 4; ++i) { float dd = v[i] - mu; vs += dd * dd; }
#pragma unroll
    for (int off = 32; off; off >>= 1) vs += __shfl_xor(vs, off);
    float rs = rsqrtf(vs * (1.f / (float)DH_) + EPS_);
    float4 gv = *(const float4*)(g + lane * 4);
    float4 bv = *(const float4*)(bt + lane * 4);
    unsigned short ov[4];
    ov[0] = f2bf((v[0] - mu) * rs * gv.x + bv.x);
    ov[1] = f2bf((v[1] - mu) * rs * gv.y + bv.y);
    ov[2] = f2bf((v[2] - mu) * rs * gv.z + bv.z);
    ov[3] = f2bf((v[3] - mu) * rs * gv.w + bv.w);
    *(uint2*)(Out + (size_t)row * DH_ + lane * 4) = *(uint2*)ov;
}

// Readout: per-graph column sum of t3 (bf16 in, fp32 out).
__global__ __launch_bounds__(256) void readout_kernel(const unsigned short* __restrict__ T3,
                                                      float* __restrict__ out) {
    int b = blockIdx.x, j = threadIdx.x;
    float s = 0.f;
    for (int r = 0; r < SG; ++r) s += bf2f(T3[(size_t)(b * SG + r) * DH_ + j]);
    out[b * DH_ + j] = s;
}

// ---------------------------------------------------------------------------
extern "C" void kernel_launch(void* const* d_in, const int* in_sizes, int n_in,
                              void* d_out, int out_size, void* d_ws, size_t ws_size,
                              hipStream_t stream) {
    const float* x       = (const float*)d_in[0];
    const int*   ei      = (const int*)d_in[1];
    const float* inter_f = (const float*)d_in[3];
    const float* bn1_g = (const float*)d_in[4],  *bn1_b = (const float*)d_in[5];
    const float* bn2_g = (const float*)d_in[6],  *bn2_b = (const float*)d_in[7];
    const float* w_conv1 = (const float*)d_in[8],  *b_conv1 = (const float*)d_in[9];
    const float* w_conv2 = (const float*)d_in[10], *b_conv2 = (const float*)d_in[11];
    const float* wq = (const float*)d_in[12], *bq = (const float*)d_in[13];
    const float* wk = (const float*)d_in[14], *bk = (const float*)d_in[15];
    const float* wv = (const float*)d_in[16], *bv = (const float*)d_in[17];
    const float* wo = (const float*)d_in[18], *bo = (const float*)d_in[19];
    const float* ln1_g = (const float*)d_in[20], *ln1_b = (const float*)d_in[21];
    const float* ln2_g = (const float*)d_in[22], *ln2_b = (const float*)d_in[23];
    const float* w_ff1 = (const float*)d_in[24], *b_ff1 = (const float*)d_in[25];
    const float* w_ff2 = (const float*)d_in[26], *b_ff2 = (const float*)d_in[27];
    float* out = (float*)d_out;

    char* base = (char*)d_ws;
    size_t o = 0;
    auto alloc = [&](size_t bytes) -> void* {
        void* p = base + o;
        o = (o + bytes + 255) & ~(size_t)255;
        return p;
    };
    int*   deg    = (int*)alloc(NN * 4);
    int*   off    = (int*)alloc((NN + 1) * 4);
    int*   cnt    = (int*)alloc(NN * 4);
    int*   srow   = (int*)alloc(EE * 4);
    float* dis    = (float*)alloc(NN * 4);
    float* csum   = (float*)alloc(256 * 4);
    float* csumsq = (float*)alloc(256 * 4);
    float* scl    = (float*)alloc(256 * 4);
    float* shf    = (float*)alloc(256 * 4);
    float* bqkv   = (float*)alloc(768 * 4);
    const size_t SLOT = (size_t)NN * DH_;  // 8M elements (16 MB bf16)
    unsigned short* Arena = (unsigned short*)alloc((size_t)NN * DFF_ * 2);
    unsigned short* TB = (unsigned short*)alloc(SLOT * 2);  // tb -> z2b
    unsigned short* B0 = (unsigned short*)alloc(SLOT * 2);  // Xb->h1b->Ob->t2b->t3b
    unsigned short* wc1t  = (unsigned short*)alloc((size_t)DIN_ * DH_ * 2);
    unsigned short* wc2t  = (unsigned short*)alloc((size_t)DH_ * DH_ * 2);
    unsigned short* wqkvt = (unsigned short*)alloc((size_t)DH_ * DH_ * 3 * 2);
    unsigned short* wot   = (unsigned short*)alloc((size_t)DH_ * DH_ * 2);
    unsigned short* wf1t  = (unsigned short*)alloc((size_t)DH_ * DFF_ * 2);
    unsigned short* wf2t  = (unsigned short*)alloc((size_t)DFF_ * DH_ * 2);
    unsigned short* Xa   = Arena;                            // NN*DIN (4M)
    unsigned short* X2a  = Arena + (size_t)NN * DIN_;        // [4M..12M)
    unsigned short* QKVb = Arena;                            // [0..24M)
    unsigned short* zb   = Arena + SLOT * 3;                 // [24M..32M)
    unsigned short* Fb   = Arena;                            // [0..32M)
    unsigned short* tb   = TB;
    unsigned short* z2b  = TB;

    hipMemsetAsync(deg, 0, NN * 4, stream);
    hipMemsetAsync(cnt, 0, NN * 4, stream);
    hipMemsetAsync(csum, 0, 2048, stream);

    // Weight transposes (bf16; wq pre-scaled by QSCALE) + QKV bias concat
    wtrans_kernel<<<(DIN_ * DH_ + 255) / 256, 256, 0, stream>>>(w_conv1, wc1t, DIN_, DH_, 1.f);
    wtrans_kernel<<<(DH_ * DH_ + 255) / 256, 256, 0, stream>>>(w_conv2, wc2t, DH_, DH_, 1.f);
    wtrans_kernel<<<(DH_ * DH_ + 255) / 256, 256, 0, stream>>>(wq, wqkvt, DH_, DH_, QSCALE);
    wtrans_kernel<<<(DH_ * DH_ + 255) / 256, 256, 0, stream>>>(wk, wqkvt + DH_ * DH_, DH_, DH_, 1.f);
    wtrans_kernel<<<(DH_ * DH_ + 255) / 256, 256, 0, stream>>>(wv, wqkvt + 2 * DH_ * DH_, DH_, DH_, 1.f);
    wtrans_kernel<<<(DH_ * DH_ + 255) / 256, 256, 0, stream>>>(wo, wot, DH_, DH_, 1.f);
    wtrans_kernel<<<(DH_ * DFF_ + 255) / 256, 256, 0, stream>>>(w_ff1, wf1t, DH_, DFF_, 1.f);
    wtrans_kernel<<<(DFF_ * DH_ + 255) / 256, 256, 0, stream>>>(w_ff2, wf2t, DFF_, DH_, 1.f);
    bcat_kernel<<<3, 256, 0, stream>>>(bq, bk, bv, bqkv);

    // init_avg_h -> out[B*DH ...]
    initavg_kernel<<<BG, 128, 0, stream>>>(x, out + BG * DH_);

    // BN1 -> Xb bf16 (B0)
    colstats_kernel<DIN_><<<NN / 256, DIN_, 0, stream>>>(x, csum, csumsq);
    bnfin_kernel<DIN_><<<1, DIN_, 0, stream>>>(csum, csumsq, bn1_g, bn1_b, scl, shf);
    bnapply_kernel<DIN_><<<NN * DIN_ / 256, 256, 0, stream>>>(x, scl, shf, B0);

    // CSR build
    deg_kernel<<<EE / 256, 256, 0, stream>>>(ei + EE, deg);
    scan_kernel<<<1, 1024, 0, stream>>>(deg, off, dis);
    scatter_kernel<<<EE / 256, 256, 0, stream>>>(ei, ei + EE, off, cnt, srow);

    // agg1 (A·X)·W == A·(X·W): Xa = Anorm @ Xb (bf16, 128 cols)
    aggb_kernel<DIN_, 0><<<NN / 4, 256, 0, stream>>>(B0, off, srow, dis,
                                                     nullptr, nullptr, Xa);
    // conv1 (N=256 -> MT=64): h1b = relu(Xa @ w_conv1 + b) -> B0 (Xb dead)
    gemm_bf16_kernel<64><<<dim3(DH_ / 128, NN / 64), 512, 0, stream>>>(
        Xa, wc1t, B0, NN, DIN_, DH_, b_conv1, nullptr, nullptr, 1, 0);

    // BN2 stats on h1b -> scale/shift (apply fused into agg2)
    hipMemsetAsync(csum, 0, 2048, stream);
    colstats_b_kernel<DH_><<<NN / 256, DH_, 0, stream>>>(B0, csum, csumsq);
    bnfin_kernel<DH_><<<1, DH_, 0, stream>>>(csum, csumsq, bn2_g, bn2_b, scl, shf);

    // agg2 with fused BN apply: X2a = Anorm @ (h1b*s + b) -> Arena[4M..12M)
    aggb_kernel<DH_, 1><<<NN / 4, 256, 0, stream>>>(B0, off, srow, dis,
                                                    scl, shf, X2a);
    // conv2 (MT=64): tb = h1b + relu(X2a @ w_conv2 + b) + inter[graph] -> TB
    gemm_bf16_kernel<64><<<dim3(DH_ / 128, NN / 64), 512, 0, stream>>>(
        X2a, wc2t, tb, NN, DH_, DH_, b_conv2, B0, inter_f, 1, 1);

    // Fused QKV (N=768, 4-wave 128x128): QKVb = tb @ [wq*s|wk|wv] + bqkv
    gemm128w4_kernel<<<dim3(768 / 128, NN / 128), 256, 0, stream>>>(
        tb, wqkvt, QKVb, NN, DH_, 768, bqkv, nullptr, nullptr, 0, 0);

    // MFMA flash attention -> Ob (B0; h1b dead)
    attn_mfma_kernel<<<BG * NH, 256, 0, stream>>>(QKVb, B0);

    // O-proj (MT=64): zb = Ob @ wo + bo + tb ; t2b = LN(zb) -> B0
    gemm_bf16_kernel<64><<<dim3(DH_ / 128, NN / 64), 512, 0, stream>>>(
        B0, wot, zb, NN, DH_, DH_, bo, tb, nullptr, 0, 0);
    lnb_kernel<<<NN / 4, 256, 0, stream>>>(zb, B0, ln1_g, ln1_b);

    // FFN (4-wave 128x128): ff1: Fb = relu(t2b @ w_ff1 + b1) ;
    //                       ff2: z2b = Fb @ w_ff2 + b2 + t2b -> TB
    gemm128w4_kernel<<<dim3(DFF_ / 128, NN / 128), 256, 0, stream>>>(
        B0, wf1t, Fb, NN, DH_, DFF_, b_ff1, nullptr, nullptr, 1, 0);
    gemm128w4_kernel<<<dim3(DH_ / 128, NN / 128), 256, 0, stream>>>(
        Fb, wf2t, z2b, NN, DFF_, DH_, b_ff2, B0, nullptr, 0, 0);

    // t3b = LN(z2b) -> B0 (t2b dead) ; readout -> out[0 .. B*DH)
    lnb_kernel<<<NN / 4, 256, 0, stream>>>(z2b, B0, ln2_g, ln2_b);
    readout_kernel<<<BG, 256, 0, stream>>>(B0, out);
}

// Round 7
// 533.115 us; speedup vs baseline: 1.0641x; 1.0641x over previous
//
#include <hip/hip_runtime.h>
#include <math.h>

// Problem constants (fixed by the reference)
#define NN   32768
#define BG   128
#define SG   256
#define EE   524288
#define DIN_ 128
#define DH_  256
#define NH   8
#define HD_  32
#define DFF_ 1024
#define EPS_ 1e-5f

typedef __attribute__((ext_vector_type(8))) short bf16x8;
typedef __attribute__((ext_vector_type(4))) float f32x4;
typedef __attribute__((ext_vector_type(2))) unsigned int u32x2;
typedef __attribute__((ext_vector_type(4))) unsigned int u32x4;

__device__ __forceinline__ unsigned short f2bf(float f) {
    unsigned int u = __builtin_bit_cast(unsigned int, f);
    unsigned int r = u + 0x7FFFu + ((u >> 16) & 1u);
    return (unsigned short)(r >> 16);
}
__device__ __forceinline__ float bf2f(unsigned short u) {
    return __builtin_bit_cast(float, (unsigned int)u << 16);
}
// Async global->LDS DMA, 16 B per lane (dest = wave-uniform base + lane*16).
__device__ __forceinline__ void glds16(const unsigned short* g, unsigned short* l) {
    __builtin_amdgcn_global_load_lds(
        (const __attribute__((address_space(1))) void*)g,
        (__attribute__((address_space(3))) void*)l, 16, 0, 0);
}
// s_waitcnt with vmcnt(N) only (exp/lgkm masked off).
#define WAIT_VM0() __builtin_amdgcn_s_waitcnt(0x0F70)
#define WAIT_VM1() __builtin_amdgcn_s_waitcnt(0x0F71)
#define WAIT_VM2() __builtin_amdgcn_s_waitcnt(0x0F72)
#define WAIT_VM3() __builtin_amdgcn_s_waitcnt(0x0F73)
#define WAIT_VM4() __builtin_amdgcn_s_waitcnt(0x0F74)

// Softmax pre-scale: 1/sqrt(32) * log2(e), folded into wq/bq at transpose time.
#define QSCALE (0.17677669529663689f * 1.4426950408889634f)

// ---------------------------------------------------------------------------
// Fused init_avg_h + BN1 column stats: one pass over x (was two 16 MB passes).
// Block b = graph b (rows [b*256, b*256+256)); thread j = column.
__global__ __launch_bounds__(128) void initstats_kernel(const float* __restrict__ X,
                                                        float* __restrict__ out2,
                                                        float* __restrict__ csum,
                                                        float* __restrict__ csumsq) {
    int b = blockIdx.x, j = threadIdx.x;
    float s = 0.f, sq = 0.f;
    for (int r = 0; r < SG; ++r) {
        float v = X[(size_t)(b * SG + r) * DIN_ + j];
        s += v; sq += v * v;
    }
    out2[b * DIN_ + j] = s * (1.f / (float)SG);
    atomicAdd(&csum[j], s);
    atomicAdd(&csumsq[j], sq);
}

template <int C>
__global__ __launch_bounds__(C) void bnfin_kernel(const float* __restrict__ csum,
                                                  const float* __restrict__ csumsq,
                                                  const float* __restrict__ g,
                                                  const float* __restrict__ b,
                                                  float* __restrict__ scale,
                                                  float* __restrict__ shift) {
    int j = threadIdx.x;
    float mu  = csum[j] * (1.f / (float)NN);
    float var = csumsq[j] * (1.f / (float)NN) - mu * mu;
    float s = g[j] * rsqrtf(var + EPS_);
    scale[j] = s;
    shift[j] = b[j] - mu * s;
}

// BN apply, fp32 in -> bf16 out (BN1).
template <int C>
__global__ __launch_bounds__(256) void bnapply_kernel(const float* __restrict__ X,
                                                      const float* __restrict__ sc,
                                                      const float* __restrict__ sh,
                                                      unsigned short* __restrict__ Y) {
    int i = blockIdx.x * 256 + threadIdx.x;
    int j = i & (C - 1);
    Y[i] = f2bf(X[i] * sc[j] + sh[j]);
}

// Weight cast+transpose: W[K,N] fp32 -> Wt[N,K] bf16, optional scalar scale.
__global__ __launch_bounds__(256) void wtrans_kernel(const float* __restrict__ W,
                                                     unsigned short* __restrict__ Wt,
                                                     int K, int N, float scale) {
    int idx = blockIdx.x * 256 + threadIdx.x;
    if (idx < K * N) {
        int n = idx / K, k = idx - n * K;
        Wt[idx] = f2bf(W[(size_t)k * N + n] * scale);
    }
}

// Concat Q/K/V biases into one fp32[768]; Q part pre-scaled by QSCALE.
__global__ __launch_bounds__(256) void bcat_kernel(const float* __restrict__ bq,
                                                   const float* __restrict__ bk,
                                                   const float* __restrict__ bv,
                                                   float* __restrict__ o) {
    int j = threadIdx.x;
    if (blockIdx.x == 0) o[j] = bq[j] * QSCALE;
    else if (blockIdx.x == 1) o[DH_ + j] = bk[j];
    else o[2 * DH_ + j] = bv[j];
}

// ---------------------------------------------------------------------------
// CSR build
__global__ __launch_bounds__(256) void deg_kernel(const int* __restrict__ col,
                                                  int* __restrict__ deg) {
    int e = blockIdx.x * 256 + threadIdx.x;
    if (e < EE) atomicAdd(&deg[col[e]], 1);
}

__global__ __launch_bounds__(1024) void scan_kernel(const int* __restrict__ deg,
                                                    int* __restrict__ off,
                                                    float* __restrict__ dis) {
    __shared__ int sums[1024];
    int t = threadIdx.x;
    int base = t * 32;
    int loc[32];
    int run = 0;
#pragma unroll
    for (int i = 0; i < 32; ++i) { loc[i] = run; run += deg[base + i]; }
    sums[t] = run;
    __syncthreads();
    for (int d = 1; d < 1024; d <<= 1) {
        int tmp = (t >= d) ? sums[t - d] : 0;
        __syncthreads();
        sums[t] += tmp;
        __syncthreads();
    }
    int excl = sums[t] - run;
#pragma unroll
    for (int i = 0; i < 32; ++i) {
        off[base + i] = excl + loc[i];
        dis[base + i] = rsqrtf((float)(deg[base + i] + 1));
    }
    if (t == 1023) off[NN] = sums[1023];
}

__global__ __launch_bounds__(256) void scatter_kernel(const int* __restrict__ row,
                                                      const int* __restrict__ col,
                                                      const int* __restrict__ off,
                                                      int* __restrict__ cnt,
                                                      int* __restrict__ srow) {
    int e = blockIdx.x * 256 + threadIdx.x;
    if (e < EE) {
        int c = col[e];
        int p = off[c] + atomicAdd(&cnt[c], 1);
        srow[p] = row[e];
    }
}

// ---------------------------------------------------------------------------
// bf16 GCN aggregation, 4x-unrolled edge loop for MLP.
template <int C, int FUSE_BN>
__global__ __launch_bounds__(256) void aggb_kernel(const unsigned short* __restrict__ X,
                                                   const int* __restrict__ off,
                                                   const int* __restrict__ srow,
                                                   const float* __restrict__ dis,
                                                   const float* __restrict__ scl,
                                                   const float* __restrict__ shf,
                                                   unsigned short* __restrict__ Y) {
    constexpr int EPL = C / 64;
    int lane = threadIdx.x & 63;
    int c = blockIdx.x * 4 + (threadIdx.x >> 6);
    float dc = dis[c];
    float acc[EPL];
    float wsum = dc;
    {
        unsigned short t[EPL];
        const unsigned short* xc = X + (size_t)c * C + lane * EPL;
        if constexpr (EPL == 4) *(uint2*)t = *(const uint2*)xc;
        else *(unsigned int*)t = *(const unsigned int*)xc;
#pragma unroll
        for (int e2 = 0; e2 < EPL; ++e2) acc[e2] = dc * bf2f(t[e2]);
    }
    int s = off[c], en = off[c + 1];
    int i = s;
    for (; i + 4 <= en; i += 4) {
        int r0 = srow[i], r1 = srow[i + 1], r2 = srow[i + 2], r3 = srow[i + 3];
        float d0 = dis[r0], d1 = dis[r1], d2 = dis[r2], d3 = dis[r3];
        unsigned short t0[EPL], t1[EPL], t2[EPL], t3[EPL];
        const unsigned short* p0 = X + (size_t)r0 * C + lane * EPL;
        const unsigned short* p1 = X + (size_t)r1 * C + lane * EPL;
        const unsigned short* p2 = X + (size_t)r2 * C + lane * EPL;
        const unsigned short* p3 = X + (size_t)r3 * C + lane * EPL;
        if constexpr (EPL == 4) {
            *(uint2*)t0 = *(const uint2*)p0;
            *(uint2*)t1 = *(const uint2*)p1;
            *(uint2*)t2 = *(const uint2*)p2;
            *(uint2*)t3 = *(const uint2*)p3;
        } else {
            *(unsigned int*)t0 = *(const unsigned int*)p0;
            *(unsigned int*)t1 = *(const unsigned int*)p1;
            *(unsigned int*)t2 = *(const unsigned int*)p2;
            *(unsigned int*)t3 = *(const unsigned int*)p3;
        }
        wsum += d0 + d1 + d2 + d3;
#pragma unroll
        for (int e2 = 0; e2 < EPL; ++e2) {
            acc[e2] += d0 * bf2f(t0[e2]) + d1 * bf2f(t1[e2]) +
                       d2 * bf2f(t2[e2]) + d3 * bf2f(t3[e2]);
        }
    }
    for (; i < en; ++i) {
        int r = srow[i];
        float dr = dis[r];
        unsigned short t[EPL];
        const unsigned short* xr = X + (size_t)r * C + lane * EPL;
        if constexpr (EPL == 4) *(uint2*)t = *(const uint2*)xr;
        else *(unsigned int*)t = *(const unsigned int*)xr;
        wsum += dr;
#pragma unroll
        for (int e2 = 0; e2 < EPL; ++e2) acc[e2] += dr * bf2f(t[e2]);
    }
    unsigned short t[EPL];
#pragma unroll
    for (int e2 = 0; e2 < EPL; ++e2) {
        float v;
        if constexpr (FUSE_BN) {
            int j = lane * EPL + e2;
            v = dc * (scl[j] * acc[e2] + shf[j] * wsum);
        } else {
            v = dc * acc[e2];
        }
        t[e2] = f2bf(v);
    }
    unsigned short* yc = Y + (size_t)c * C + lane * EPL;
    if constexpr (EPL == 4) *(uint2*)yc = *(const uint2*)t;
    else *(unsigned int*)yc = *(const unsigned int*)t;
}

// ---------------------------------------------------------------------------
// MT=128 bf16 MFMA GEMM (QKV / ff1), proven round-5 structure: triple-buffered
// glds staging (depth-2 in flight, counted vmcnt), raw s_barrier, XCD swizzle,
// XOR-swizzled staging, coalesced LDS C-tile epilogue. 48 KB -> 3 blocks/CU.
__global__ __launch_bounds__(512, 8) void gemm_bf16_kernel(
    const unsigned short* __restrict__ A,
    const unsigned short* __restrict__ Bt,
    unsigned short* __restrict__ Cb,
    int M, int K, int N,
    const float* __restrict__ bias,
    const unsigned short* __restrict__ resb,
    const float* __restrict__ inter,
    int do_relu, int relu_first) {
    constexpr int LDP = 32;
    constexpr int CP = 136;
    constexpr int MI = 2;
    constexpr int STG = 8192;                // per-stage shorts: A 8KB | B 8KB
    constexpr int BOFS = 4096;
    __shared__ unsigned short Smem[3 * STG];
    unsigned short* Cs = Smem;               // union: staging dead after K-loop
    int gx = gridDim.x, gyP = gridDim.y >> 3;
    int d = blockIdx.y * gx + blockIdx.x;
    int xcd = d & 7, j2 = d >> 3;
    int bm = (xcd * gyP + j2 / gx) * 128;
    int bn = (j2 % gx) * 128;
    int tid = threadIdx.x;
    int wave = tid >> 6, lane = tid & 63;
    int wm = (wave >> 1) * 32;               // 4 m-waves x 2 n-waves
    int wn = (wave & 1) * 64;
    int lrc = lane & 15;
    int koct = lane >> 4;
    int rsw = (lrc >> 1) & 3;
    int rofs = (koct ^ rsw) * 8;
    int cg = (lane & 3) ^ ((lane >> 3) & 3);
    int skk = cg * 8;

    int sr = wave * 16 + (lane >> 2);
    const unsigned short* gA0 = A + (size_t)(bm + sr) * K + skk;
    const unsigned short* gB0 = Bt + (size_t)(bn + sr) * K + skk;
    int lofs = wave * 512 + lane * 8;

    f32x4 acc[MI][4];
#pragma unroll
    for (int i = 0; i < MI; ++i)
#pragma unroll
        for (int j = 0; j < 4; ++j) acc[i][j] = (f32x4){0.f, 0.f, 0.f, 0.f};

    glds16(gA0, Smem + lofs);
    glds16(gB0, Smem + BOFS + lofs);
    glds16(gA0 + 32, Smem + STG + lofs);
    glds16(gB0 + 32, Smem + STG + BOFS + lofs);

    int rb = 0;
    for (int k0 = 0; k0 < K; k0 += 32) {
        if (k0 + 64 < K) {
            int wb = rb + 2; if (wb >= 3) wb -= 3;
            unsigned short* ld = Smem + wb * STG;
            glds16(gA0 + k0 + 64, ld + lofs);
            glds16(gB0 + k0 + 64, ld + BOFS + lofs);
            WAIT_VM4();                       // drain stage t; t+1,t+2 in flight
        } else if (k0 + 32 < K) {
            WAIT_VM2();
        } else {
            WAIT_VM0();
        }
        __builtin_amdgcn_s_barrier();
        const unsigned short* Ab = Smem + rb * STG;
        const unsigned short* Bb = Ab + BOFS;
        bf16x8 af[MI], bfr[4];
#pragma unroll
        for (int i = 0; i < MI; ++i)
            af[i] = *(const bf16x8*)(Ab + (wm + i * 16 + lrc) * LDP + rofs);
#pragma unroll
        for (int j = 0; j < 4; ++j)
            bfr[j] = *(const bf16x8*)(Bb + (wn + j * 16 + lrc) * LDP + rofs);
#pragma unroll
        for (int i = 0; i < MI; ++i)
#pragma unroll
            for (int j = 0; j < 4; ++j)
                acc[i][j] = __builtin_amdgcn_mfma_f32_16x16x32_bf16(af[i], bfr[j],
                                                                    acc[i][j], 0, 0, 0);
        __builtin_amdgcn_s_barrier();
        rb = (rb + 1 == 3) ? 0 : rb + 1;
    }
#pragma unroll
    for (int i = 0; i < MI; ++i) {
#pragma unroll
        for (int r = 0; r < 4; ++r) {
            int lrow = wm + i * 16 + koct * 4 + r;
            int grow = bm + lrow;
#pragma unroll
            for (int j = 0; j < 4; ++j) {
                int lcol = wn + j * 16 + lrc;
                int gcol = bn + lcol;
                float v = acc[i][j][r];
                if (bias) v += bias[gcol];
                if (relu_first) v = fmaxf(v, 0.f);
                if (resb) v += bf2f(resb[(size_t)grow * N + gcol]);
                if (inter) v += inter[(grow >> 8) * N + gcol];
                if (do_relu && !relu_first) v = fmaxf(v, 0.f);
                Cs[lrow * CP + lcol] = f2bf(v);
            }
        }
    }
    __syncthreads();
#pragma unroll
    for (int it = 0; it < 4; ++it) {
        int row = it * 32 + (tid >> 4);
        int cc = (tid & 15) * 8;
        *(uint4*)(&Cb[(size_t)(bm + row) * N + bn + cc]) =
            *(const uint4*)(&Cs[row * CP + cc]);
    }
}

// ---------------------------------------------------------------------------
// 32x256 full-row-tile bf16 GEMM for N=256 layers (round-24).
// Same wave shape as the proven MT=64 kernel (16x64 wave tile, 4 MFMA +
// 5 ds_read per step), 8 waves covering 32 rows x all 256 cols; grid NN/32 =
// 1024 blocks; double-buffered stages (A 2KB + B 16KB = 18 KB, x2 = 36 KB ->
// 4 blocks/CU, matching grid). Full-row tiles enable epilogue fusion:
//   MODE 0: plain copy-out                       (conv2)
//   MODE 1: copy-out + BN column-stats atomics   (conv1; kills colstats_b)
//   MODE 2: row LayerNorm -> write Cb            (oproj; kills zb + lnb1)
//   MODE 3: row LayerNorm -> column-sum atomics  (ff2; kills z2b/t3b/lnb2/
//            into outp (per-graph readout)        readout entirely)
// LN uses the exact two-pass mean/var of the old lnb kernel.
// In-place safety (oproj A==Cb): each block reads only rows [bm,bm+32) of A
// (all K, during the loop) and writes only those rows afterwards.
template <int MODE>
__global__ __launch_bounds__(512, 8) void gemm32n256_kernel(
    const unsigned short* __restrict__ A,
    const unsigned short* __restrict__ Bt,
    unsigned short* __restrict__ Cb,
    int K,
    const float* __restrict__ bias,
    const unsigned short* __restrict__ resb,
    const float* __restrict__ inter,
    int do_relu, int relu_first,
    float* __restrict__ stat0, float* __restrict__ stat1,
    const float* __restrict__ lng, const float* __restrict__ lnbt,
    float* __restrict__ outp) {
    constexpr int LDP = 32;
    constexpr int CP = 264;                  // 256 + 8 pad
    constexpr int STG = 9216;                // shorts: A 1024 | B 8192
    constexpr int BOFS = 1024;
    __shared__ unsigned short Smem[2 * STG]; // 36 KB
    unsigned short* Cs = Smem;               // union (32*264 = 8448 shorts)
    int bm = blockIdx.x * 32;
    int tid = threadIdx.x;
    int wave = tid >> 6, lane = tid & 63;
    int wm = (wave >> 2) * 16;               // 2 m-positions x 4 n-positions
    int wn = (wave & 3) * 64;
    int lrc = lane & 15;
    int koct = lane >> 4;
    int rsw = (lrc >> 1) & 3;
    int rofs = (koct ^ rsw) * 8;
    int cg = (lane & 3) ^ ((lane >> 3) & 3);
    int skk = cg * 8;

    // Staging: every wave stages B rows [wave*32, +32) (2 glds);
    // waves 0-1 additionally stage A rows [wave*16, +16) (1 glds).
    const unsigned short* gB0 = Bt + (size_t)(wave * 32 + (lane >> 2)) * K + skk;
    size_t g16 = (size_t)16 * K;
    int lofsB = BOFS + wave * 1024 + lane * 8;
    const unsigned short* gA0 = nullptr;
    int lofsA = 0;
    if (wave < 2) {
        gA0 = A + (size_t)(bm + wave * 16 + (lane >> 2)) * K + skk;
        lofsA = wave * 512 + lane * 8;
    }

    f32x4 acc[4];
#pragma unroll
    for (int j = 0; j < 4; ++j) acc[j] = (f32x4){0.f, 0.f, 0.f, 0.f};

    // prologue: stage 0 into buf0
    glds16(gB0, Smem + lofsB);
    glds16(gB0 + g16, Smem + lofsB + 512);
    if (wave < 2) glds16(gA0, Smem + lofsA);

    int cur = 0;
    for (int k0 = 0; k0 < K; k0 += 32) {
        int nk = k0 + 32;
        if (nk < K) {
            unsigned short* nb = Smem + (cur ^ 1) * STG;
            glds16(gB0 + nk, nb + lofsB);
            glds16(gB0 + nk + g16, nb + lofsB + 512);
            if (wave < 2) {
                glds16(gA0 + nk, nb + lofsA);
                WAIT_VM3();                  // next stage (3 loads) in flight
            } else {
                WAIT_VM2();
            }
        } else {
            WAIT_VM0();
        }
        __builtin_amdgcn_s_barrier();
        const unsigned short* Ab = Smem + cur * STG;
        const unsigned short* Bb = Ab + BOFS;
        bf16x8 af = *(const bf16x8*)(Ab + (wm + lrc) * LDP + rofs);
        bf16x8 bfr[4];
#pragma unroll
        for (int j = 0; j < 4; ++j)
            bfr[j] = *(const bf16x8*)(Bb + (wn + j * 16 + lrc) * LDP + rofs);
#pragma unroll
        for (int j = 0; j < 4; ++j)
            acc[j] = __builtin_amdgcn_mfma_f32_16x16x32_bf16(af, bfr[j], acc[j], 0, 0, 0);
        __builtin_amdgcn_s_barrier();
        cur ^= 1;
    }
    // Finalize into Cs (bias/relu/res/inter applied in regs).
#pragma unroll
    for (int r = 0; r < 4; ++r) {
        int lrow = wm + koct * 4 + r;
        int grow = bm + lrow;
#pragma unroll
        for (int j = 0; j < 4; ++j) {
            int lcol = wn + j * 16 + lrc;
            float v = acc[j][r];
            if (bias) v += bias[lcol];
            if (relu_first) v = fmaxf(v, 0.f);
            if (resb) v += bf2f(resb[(size_t)grow * 256 + lcol]);
            if (inter) v += inter[(grow >> 8) * 256 + lcol];
            if (do_relu && !relu_first) v = fmaxf(v, 0.f);
            Cs[lrow * CP + lcol] = f2bf(v);
        }
    }
    __syncthreads();

    if constexpr (MODE == 0 || MODE == 1) {
        // Coalesced copy-out: 2 iters x 16 rows; one uint4 per thread.
#pragma unroll
        for (int it = 0; it < 2; ++it) {
            int row = it * 16 + (tid >> 5);
            int cc = (tid & 31) * 8;
            *(uint4*)(&Cb[(size_t)(bm + row) * 256 + cc]) =
                *(const uint4*)(&Cs[row * CP + cc]);
        }
        if constexpr (MODE == 1) {
            if (tid < 256) {
                float s = 0.f, sq = 0.f;
                for (int r = 0; r < 32; ++r) {
                    float v = bf2f(Cs[r * CP + tid]);
                    s += v; sq += v * v;
                }
                atomicAdd(&stat0[tid], s);
                atomicAdd(&stat1[tid], sq);
            }
        }
    } else {
        // LN modes: wave handles rows [wave*4, wave*4+4), lane owns cols lane*4..+3.
        float4 g4 = *(const float4*)(lng + lane * 4);
        float4 b4 = *(const float4*)(lnbt + lane * 4);
#pragma unroll
        for (int q = 0; q < 4; ++q) {
            int row = wave * 4 + q;
            unsigned short tv[4];
            *(uint2*)tv = *(const uint2*)(Cs + row * CP + lane * 4);
            float v0 = bf2f(tv[0]), v1 = bf2f(tv[1]), v2 = bf2f(tv[2]), v3 = bf2f(tv[3]);
            float sum = v0 + v1 + v2 + v3;
#pragma unroll
            for (int off = 32; off; off >>= 1) sum += __shfl_xor(sum, off);
            float mu = sum * (1.f / (float)DH_);
            float d0 = v0 - mu, d1 = v1 - mu, d2 = v2 - mu, d3 = v3 - mu;
            float vs = d0 * d0 + d1 * d1 + d2 * d2 + d3 * d3;
#pragma unroll
            for (int off = 32; off; off >>= 1) vs += __shfl_xor(vs, off);
            float rs = rsqrtf(vs * (1.f / (float)DH_) + EPS_);
            unsigned short ov[4];
            ov[0] = f2bf(d0 * rs * g4.x + b4.x);
            ov[1] = f2bf(d1 * rs * g4.y + b4.y);
            ov[2] = f2bf(d2 * rs * g4.z + b4.z);
            ov[3] = f2bf(d3 * rs * g4.w + b4.w);
            if constexpr (MODE == 2) {
                *(uint2*)(&Cb[(size_t)(bm + row) * 256 + lane * 4]) = *(uint2*)ov;
            } else {
                *(uint2*)(Cs + row * CP + lane * 4) = *(uint2*)ov;
            }
        }
        if constexpr (MODE == 3) {
            __syncthreads();
            if (tid < 256) {
                float s = 0.f;
                for (int r = 0; r < 32; ++r) s += bf2f(Cs[r * CP + tid]);
                atomicAdd(&outp[(bm >> 8) * 256 + tid], s);
            }
        }
    }
}

// ---------------------------------------------------------------------------
// MFMA flash attention, transposed-score, no online softmax.
// P kept fully in-register: QK^T C-fragment -> v_cvt_pk_bf16_f32 ->
// permlane32_swap + permlane16_swap -> PV A-fragment. No Ps LDS buffer.
__global__ __launch_bounds__(256, 4) void attn_mfma_kernel(
    const unsigned short* __restrict__ QKV,
    unsigned short* __restrict__ Ob) {
    int b = blockIdx.x >> 3, h = blockIdx.x & 7;
    __shared__ unsigned short Ks[256 * 32];    // XOR-swizzled chunks
    __shared__ unsigned short Vt[32 * 264];    // [d][key 256 + pad]
    __shared__ float Lc[4 * 64];               // per-wave l broadcast
    const unsigned short* kg = QKV + (size_t)b * 256 * 768 + 256 + h * 32;
    const unsigned short* vg = QKV + (size_t)b * 256 * 768 + 512 + h * 32;
    int tid = threadIdx.x;
#pragma unroll
    for (int it = 0; it < 4; ++it) {
        int c = it * 256 + tid;
        int row = c >> 2, ch = c & 3;
        int slot = ch ^ ((row >> 1) & 3);
        *(uint4*)(Ks + row * 32 + slot * 8) =
            *(const uint4*)(kg + (size_t)row * 768 + ch * 8);
    }
#pragma unroll
    for (int it = 0; it < 4; ++it) {
        int c = it * 256 + tid;
        int key = c >> 2, d0 = (c & 3) * 8;
        unsigned short tmp[8];
        *(uint4*)tmp = *(const uint4*)(vg + (size_t)key * 768 + d0);
#pragma unroll
        for (int j = 0; j < 8; ++j) Vt[(d0 + j) * 264 + key] = tmp[j];
    }
    __syncthreads();

    int wave = tid >> 6, lane = tid & 63;
    int lr = lane & 15, koct = lane >> 4;
    int s4 = (lr >> 1) & 3;
    int qrow0 = b * 256 + wave * 64;
    bf16x8 qf[4];
#pragma unroll
    for (int j = 0; j < 4; ++j)
        qf[j] = *(const bf16x8*)(QKV + (size_t)(qrow0 + j * 16 + lr) * 768 + h * 32 + koct * 8);

    f32x4 Oa[4][2];
    float lp[4];
#pragma unroll
    for (int i = 0; i < 4; ++i) {
        Oa[i][0] = (f32x4){0.f, 0.f, 0.f, 0.f};
        Oa[i][1] = (f32x4){0.f, 0.f, 0.f, 0.f};
        lp[i] = 0.f;
    }
    float* Lw = Lc + wave * 64;

    for (int kc = 0; kc < 256; kc += 32) {
        bf16x8 kf0 = *(const bf16x8*)(Ks + (kc + lr) * 32 + (koct ^ s4) * 8);
        bf16x8 kf1 = *(const bf16x8*)(Ks + (kc + 16 + lr) * 32 + (koct ^ s4) * 8);
        bf16x8 pfr[4];
#pragma unroll
        for (int j = 0; j < 4; ++j) {
            f32x4 St0 = __builtin_amdgcn_mfma_f32_16x16x32_bf16(kf0, qf[j],
                            (f32x4){0.f, 0.f, 0.f, 0.f}, 0, 0, 0);
            f32x4 St1 = __builtin_amdgcn_mfma_f32_16x16x32_bf16(kf1, qf[j],
                            (f32x4){0.f, 0.f, 0.f, 0.f}, 0, 0, 0);
            float p0[4], p1[4], ps = 0.f;
#pragma unroll
            for (int r = 0; r < 4; ++r) {
                p0[r] = exp2f(St0[r]); p1[r] = exp2f(St1[r]);
                ps += p0[r] + p1[r];
            }
            lp[j] += ps;
            unsigned int w0a, w0b, w1a, w1b;
            asm("v_cvt_pk_bf16_f32 %0, %1, %2" : "=v"(w0a) : "v"(p0[0]), "v"(p0[1]));
            asm("v_cvt_pk_bf16_f32 %0, %1, %2" : "=v"(w0b) : "v"(p0[2]), "v"(p0[3]));
            asm("v_cvt_pk_bf16_f32 %0, %1, %2" : "=v"(w1a) : "v"(p1[0]), "v"(p1[1]));
            asm("v_cvt_pk_bf16_f32 %0, %1, %2" : "=v"(w1b) : "v"(p1[2]), "v"(p1[3]));
            u32x2 sa = __builtin_amdgcn_permlane32_swap(w0a, w1a, false, false);
            u32x2 da = __builtin_amdgcn_permlane16_swap(sa[0], sa[1], false, false);
            u32x2 sb = __builtin_amdgcn_permlane32_swap(w0b, w1b, false, false);
            u32x2 db = __builtin_amdgcn_permlane16_swap(sb[0], sb[1], false, false);
            u32x4 pw = {da[0], db[0], da[1], db[1]};
            pfr[j] = __builtin_bit_cast(bf16x8, pw);
        }
        bf16x8 vf0 = *(const bf16x8*)(Vt + lr * 264 + kc + koct * 8);
        bf16x8 vf1 = *(const bf16x8*)(Vt + (16 + lr) * 264 + kc + koct * 8);
#pragma unroll
        for (int i = 0; i < 4; ++i) {
            Oa[i][0] = __builtin_amdgcn_mfma_f32_16x16x32_bf16(pfr[i], vf0, Oa[i][0], 0, 0, 0);
            Oa[i][1] = __builtin_amdgcn_mfma_f32_16x16x32_bf16(pfr[i], vf1, Oa[i][1], 0, 0, 0);
        }
    }
#pragma unroll
    for (int j = 0; j < 4; ++j) {
        lp[j] += __shfl_xor(lp[j], 16);
        lp[j] += __shfl_xor(lp[j], 32);
    }
    if (koct == 0) {
#pragma unroll
        for (int j = 0; j < 4; ++j) Lw[j * 16 + lr] = lp[j];
    }
    __builtin_amdgcn_s_waitcnt(0);
#pragma unroll
    for (int i = 0; i < 4; ++i) {
        f32x4 l4 = *(const f32x4*)(Lw + i * 16 + koct * 4);
#pragma unroll
        for (int r = 0; r < 4; ++r) {
            float inv = 1.f / l4[r];
            int row = qrow0 + i * 16 + koct * 4 + r;
#pragma unroll
            for (int jn = 0; jn < 2; ++jn) {
                int col = h * 32 + jn * 16 + lr;
                Ob[(size_t)row * 256 + col] = f2bf(Oa[i][jn][r] * inv);
            }
        }
    }
}

// ---------------------------------------------------------------------------
extern "C" void kernel_launch(void* const* d_in, const int* in_sizes, int n_in,
                              void* d_out, int out_size, void* d_ws, size_t ws_size,
                              hipStream_t stream) {
    const float* x       = (const float*)d_in[0];
    const int*   ei      = (const int*)d_in[1];
    const float* inter_f = (const float*)d_in[3];
    const float* bn1_g = (const float*)d_in[4],  *bn1_b = (const float*)d_in[5];
    const float* bn2_g = (const float*)d_in[6],  *bn2_b = (const float*)d_in[7];
    const float* w_conv1 = (const float*)d_in[8],  *b_conv1 = (const float*)d_in[9];
    const float* w_conv2 = (const float*)d_in[10], *b_conv2 = (const float*)d_in[11];
    const float* wq = (const float*)d_in[12], *bq = (const float*)d_in[13];
    const float* wk = (const float*)d_in[14], *bk = (const float*)d_in[15];
    const float* wv = (const float*)d_in[16], *bv = (const float*)d_in[17];
    const float* wo = (const float*)d_in[18], *bo = (const float*)d_in[19];
    const float* ln1_g = (const float*)d_in[20], *ln1_b = (const float*)d_in[21];
    const float* ln2_g = (const float*)d_in[22], *ln2_b = (const float*)d_in[23];
    const float* w_ff1 = (const float*)d_in[24], *b_ff1 = (const float*)d_in[25];
    const float* w_ff2 = (const float*)d_in[26], *b_ff2 = (const float*)d_in[27];
    float* out = (float*)d_out;

    char* base = (char*)d_ws;
    size_t o = 0;
    auto alloc = [&](size_t bytes) -> void* {
        void* p = base + o;
        o = (o + bytes + 255) & ~(size_t)255;
        return p;
    };
    int*   deg    = (int*)alloc(NN * 4);
    int*   off    = (int*)alloc((NN + 1) * 4);
    int*   cnt    = (int*)alloc(NN * 4);
    int*   srow   = (int*)alloc(EE * 4);
    float* dis    = (float*)alloc(NN * 4);
    float* csum   = (float*)alloc(256 * 4);   // BN1 stats (contiguous 4 KB
    float* csumsq = (float*)alloc(256 * 4);   //  block with csum2/csumsq2,
    float* csum2  = (float*)alloc(256 * 4);   //  zeroed in one memset)
    float* csumsq2= (float*)alloc(256 * 4);
    float* scl    = (float*)alloc(256 * 4);
    float* shf    = (float*)alloc(256 * 4);
    float* bqkv   = (float*)alloc(768 * 4);
    const size_t SLOT = (size_t)NN * DH_;  // 8M elements (16 MB bf16)
    unsigned short* Arena = (unsigned short*)alloc((size_t)NN * DFF_ * 2);
    unsigned short* TB = (unsigned short*)alloc(SLOT * 2);  // tb
    unsigned short* B0 = (unsigned short*)alloc(SLOT * 2);  // Xb->h1b->Ob->t2b
    unsigned short* wc1t  = (unsigned short*)alloc((size_t)DIN_ * DH_ * 2);
    unsigned short* wc2t  = (unsigned short*)alloc((size_t)DH_ * DH_ * 2);
    unsigned short* wqkvt = (unsigned short*)alloc((size_t)DH_ * DH_ * 3 * 2);
    unsigned short* wot   = (unsigned short*)alloc((size_t)DH_ * DH_ * 2);
    unsigned short* wf1t  = (unsigned short*)alloc((size_t)DH_ * DFF_ * 2);
    unsigned short* wf2t  = (unsigned short*)alloc((size_t)DFF_ * DH_ * 2);
    unsigned short* Xa   = Arena;                            // NN*DIN (4M)
    unsigned short* X2a  = Arena + (size_t)NN * DIN_;        // [4M..12M)
    unsigned short* QKVb = Arena;                            // [0..24M)
    unsigned short* Fb   = Arena;                            // [0..32M)
    unsigned short* tb   = TB;

    hipMemsetAsync(deg, 0, NN * 4, stream);
    hipMemsetAsync(cnt, 0, NN * 4, stream);
    hipMemsetAsync(csum, 0, 4096, stream);                   // all 4 stat arrays
    hipMemsetAsync(out, 0, BG * DH_ * 4, stream);            // readout atomics target

    // Weight transposes (bf16; wq pre-scaled by QSCALE) + QKV bias concat
    wtrans_kernel<<<(DIN_ * DH_ + 255) / 256, 256, 0, stream>>>(w_conv1, wc1t, DIN_, DH_, 1.f);
    wtrans_kernel<<<(DH_ * DH_ + 255) / 256, 256, 0, stream>>>(w_conv2, wc2t, DH_, DH_, 1.f);
    wtrans_kernel<<<(DH_ * DH_ + 255) / 256, 256, 0, stream>>>(wq, wqkvt, DH_, DH_, QSCALE);
    wtrans_kernel<<<(DH_ * DH_ + 255) / 256, 256, 0, stream>>>(wk, wqkvt + DH_ * DH_, DH_, DH_, 1.f);
    wtrans_kernel<<<(DH_ * DH_ + 255) / 256, 256, 0, stream>>>(wv, wqkvt + 2 * DH_ * DH_, DH_, DH_, 1.f);
    wtrans_kernel<<<(DH_ * DH_ + 255) / 256, 256, 0, stream>>>(wo, wot, DH_, DH_, 1.f);
    wtrans_kernel<<<(DH_ * DFF_ + 255) / 256, 256, 0, stream>>>(w_ff1, wf1t, DH_, DFF_, 1.f);
    wtrans_kernel<<<(DFF_ * DH_ + 255) / 256, 256, 0, stream>>>(w_ff2, wf2t, DFF_, DH_, 1.f);
    bcat_kernel<<<3, 256, 0, stream>>>(bq, bk, bv, bqkv);

    // Fused init_avg_h + BN1 stats (one pass over x)
    initstats_kernel<<<BG, 128, 0, stream>>>(x, out + BG * DH_, csum, csumsq);
    bnfin_kernel<DIN_><<<1, DIN_, 0, stream>>>(csum, csumsq, bn1_g, bn1_b, scl, shf);
    bnapply_kernel<DIN_><<<NN * DIN_ / 256, 256, 0, stream>>>(x, scl, shf, B0);

    // CSR build
    deg_kernel<<<EE / 256, 256, 0, stream>>>(ei + EE, deg);
    scan_kernel<<<1, 1024, 0, stream>>>(deg, off, dis);
    scatter_kernel<<<EE / 256, 256, 0, stream>>>(ei, ei + EE, off, cnt, srow);

    // agg1 (A·X)·W == A·(X·W): Xa = Anorm @ Xb (bf16, 128 cols)
    aggb_kernel<DIN_, 0><<<NN / 4, 256, 0, stream>>>(B0, off, srow, dis,
                                                     nullptr, nullptr, Xa);
    // conv1 (MODE 1): h1b = relu(Xa @ w_conv1 + b) -> B0 ; fused BN2 stats
    gemm32n256_kernel<1><<<NN / 32, 512, 0, stream>>>(
        Xa, wc1t, B0, DIN_, b_conv1, nullptr, nullptr, 1, 0,
        csum2, csumsq2, nullptr, nullptr, nullptr);
    bnfin_kernel<DH_><<<1, DH_, 0, stream>>>(csum2, csumsq2, bn2_g, bn2_b, scl, shf);

    // agg2 with fused BN apply: X2a = Anorm @ (h1b*s + b)
    aggb_kernel<DH_, 1><<<NN / 4, 256, 0, stream>>>(B0, off, srow, dis,
                                                    scl, shf, X2a);
    // conv2 (MODE 0): tb = h1b + relu(X2a @ w_conv2 + b) + inter[graph] -> TB
    gemm32n256_kernel<0><<<NN / 32, 512, 0, stream>>>(
        X2a, wc2t, tb, DH_, b_conv2, B0, inter_f, 1, 1,
        nullptr, nullptr, nullptr, nullptr, nullptr);

    // Fused QKV (N=768, MT=128): QKVb = tb @ [wq*s|wk|wv] + bqkv
    gemm_bf16_kernel<<<dim3(768 / 128, NN / 128), 512, 0, stream>>>(
        tb, wqkvt, QKVb, NN, DH_, 768, bqkv, nullptr, nullptr, 0, 0);

    // MFMA flash attention -> Ob (B0; h1b dead)
    attn_mfma_kernel<<<BG * NH, 256, 0, stream>>>(QKVb, B0);

    // O-proj (MODE 2): t2b = LN1(Ob @ wo + bo + tb) -> B0 in-place
    gemm32n256_kernel<2><<<NN / 32, 512, 0, stream>>>(
        B0, wot, B0, DH_, bo, tb, nullptr, 0, 0,
        nullptr, nullptr, ln1_g, ln1_b, nullptr);

    // ff1 (N=1024, MT=128): Fb = relu(t2b @ w_ff1 + b1)
    gemm_bf16_kernel<<<dim3(DFF_ / 128, NN / 128), 512, 0, stream>>>(
        B0, wf1t, Fb, NN, DH_, DFF_, b_ff1, nullptr, nullptr, 1, 0);

    // ff2 (MODE 3): LN2(Fb @ w_ff2 + b2 + t2b) -> per-graph column sums -> out
    gemm32n256_kernel<3><<<NN / 32, 512, 0, stream>>>(
        Fb, wf2t, nullptr, DFF_, b_ff2, B0, nullptr, 0, 0,
        nullptr, nullptr, ln2_g, ln2_b, out);
}

// Round 8
// 521.726 us; speedup vs baseline: 1.0873x; 1.0218x over previous
//
#include <hip/hip_runtime.h>
#include <math.h>

// Problem constants (fixed by the reference)
#define NN   32768
#define BG   128
#define SG   256
#define EE   524288
#define DIN_ 128
#define DH_  256
#define NH   8
#define HD_  32
#define DFF_ 1024
#define EPS_ 1e-5f

typedef __attribute__((ext_vector_type(8))) short bf16x8;
typedef __attribute__((ext_vector_type(4))) float f32x4;
typedef __attribute__((ext_vector_type(2))) unsigned int u32x2;
typedef __attribute__((ext_vector_type(4))) unsigned int u32x4;

__device__ __forceinline__ unsigned short f2bf(float f) {
    unsigned int u = __builtin_bit_cast(unsigned int, f);
    unsigned int r = u + 0x7FFFu + ((u >> 16) & 1u);
    return (unsigned short)(r >> 16);
}
__device__ __forceinline__ float bf2f(unsigned short u) {
    return __builtin_bit_cast(float, (unsigned int)u << 16);
}
// Async global->LDS DMA, 16 B per lane (dest = wave-uniform base + lane*16).
__device__ __forceinline__ void glds16(const unsigned short* g, unsigned short* l) {
    __builtin_amdgcn_global_load_lds(
        (const __attribute__((address_space(1))) void*)g,
        (__attribute__((address_space(3))) void*)l, 16, 0, 0);
}
// s_waitcnt with vmcnt(N) only (exp/lgkm masked off).
#define WAIT_VM0() __builtin_amdgcn_s_waitcnt(0x0F70)
#define WAIT_VM1() __builtin_amdgcn_s_waitcnt(0x0F71)
#define WAIT_VM2() __builtin_amdgcn_s_waitcnt(0x0F72)
#define WAIT_VM3() __builtin_amdgcn_s_waitcnt(0x0F73)
#define WAIT_VM4() __builtin_amdgcn_s_waitcnt(0x0F74)
#define WAIT_VM6() __builtin_amdgcn_s_waitcnt(0x0F76)

// Softmax pre-scale: 1/sqrt(32) * log2(e), folded into wq/bq at transpose time.
#define QSCALE (0.17677669529663689f * 1.4426950408889634f)

// ---------------------------------------------------------------------------
// Fused init_avg_h + BN1 column stats: one pass over x.
__global__ __launch_bounds__(128) void initstats_kernel(const float* __restrict__ X,
                                                        float* __restrict__ out2,
                                                        float* __restrict__ csum,
                                                        float* __restrict__ csumsq) {
    int b = blockIdx.x, j = threadIdx.x;
    float s = 0.f, sq = 0.f;
    for (int r = 0; r < SG; ++r) {
        float v = X[(size_t)(b * SG + r) * DIN_ + j];
        s += v; sq += v * v;
    }
    out2[b * DIN_ + j] = s * (1.f / (float)SG);
    atomicAdd(&csum[j], s);
    atomicAdd(&csumsq[j], sq);
}

template <int C>
__global__ __launch_bounds__(C) void bnfin_kernel(const float* __restrict__ csum,
                                                  const float* __restrict__ csumsq,
                                                  const float* __restrict__ g,
                                                  const float* __restrict__ b,
                                                  float* __restrict__ scale,
                                                  float* __restrict__ shift) {
    int j = threadIdx.x;
    float mu  = csum[j] * (1.f / (float)NN);
    float var = csumsq[j] * (1.f / (float)NN) - mu * mu;
    float s = g[j] * rsqrtf(var + EPS_);
    scale[j] = s;
    shift[j] = b[j] - mu * s;
}

// BN apply, fp32 in -> bf16 out (BN1).
template <int C>
__global__ __launch_bounds__(256) void bnapply_kernel(const float* __restrict__ X,
                                                      const float* __restrict__ sc,
                                                      const float* __restrict__ sh,
                                                      unsigned short* __restrict__ Y) {
    int i = blockIdx.x * 256 + threadIdx.x;
    int j = i & (C - 1);
    Y[i] = f2bf(X[i] * sc[j] + sh[j]);
}

// Weight cast+transpose: W[K,N] fp32 -> Wt[N,K] bf16, optional scalar scale.
__global__ __launch_bounds__(256) void wtrans_kernel(const float* __restrict__ W,
                                                     unsigned short* __restrict__ Wt,
                                                     int K, int N, float scale) {
    int idx = blockIdx.x * 256 + threadIdx.x;
    if (idx < K * N) {
        int n = idx / K, k = idx - n * K;
        Wt[idx] = f2bf(W[(size_t)k * N + n] * scale);
    }
}

// Concat Q/K/V biases into one fp32[768]; Q part pre-scaled by QSCALE.
__global__ __launch_bounds__(256) void bcat_kernel(const float* __restrict__ bq,
                                                   const float* __restrict__ bk,
                                                   const float* __restrict__ bv,
                                                   float* __restrict__ o) {
    int j = threadIdx.x;
    if (blockIdx.x == 0) o[j] = bq[j] * QSCALE;
    else if (blockIdx.x == 1) o[DH_ + j] = bk[j];
    else o[2 * DH_ + j] = bv[j];
}

// ---------------------------------------------------------------------------
// CSR build
__global__ __launch_bounds__(256) void deg_kernel(const int* __restrict__ col,
                                                  int* __restrict__ deg) {
    int e = blockIdx.x * 256 + threadIdx.x;
    if (e < EE) atomicAdd(&deg[col[e]], 1);
}

__global__ __launch_bounds__(1024) void scan_kernel(const int* __restrict__ deg,
                                                    int* __restrict__ off,
                                                    float* __restrict__ dis) {
    __shared__ int sums[1024];
    int t = threadIdx.x;
    int base = t * 32;
    int loc[32];
    int run = 0;
#pragma unroll
    for (int i = 0; i < 32; ++i) { loc[i] = run; run += deg[base + i]; }
    sums[t] = run;
    __syncthreads();
    for (int d = 1; d < 1024; d <<= 1) {
        int tmp = (t >= d) ? sums[t - d] : 0;
        __syncthreads();
        sums[t] += tmp;
        __syncthreads();
    }
    int excl = sums[t] - run;
#pragma unroll
    for (int i = 0; i < 32; ++i) {
        off[base + i] = excl + loc[i];
        dis[base + i] = rsqrtf((float)(deg[base + i] + 1));
    }
    if (t == 1023) off[NN] = sums[1023];
}

__global__ __launch_bounds__(256) void scatter_kernel(const int* __restrict__ row,
                                                      const int* __restrict__ col,
                                                      const int* __restrict__ off,
                                                      int* __restrict__ cnt,
                                                      int* __restrict__ srow) {
    int e = blockIdx.x * 256 + threadIdx.x;
    if (e < EE) {
        int c = col[e];
        int p = off[c] + atomicAdd(&cnt[c], 1);
        srow[p] = row[e];
    }
}

// ---------------------------------------------------------------------------
// bf16 GCN aggregation, 4x-unrolled edge loop for MLP.
template <int C, int FUSE_BN>
__global__ __launch_bounds__(256) void aggb_kernel(const unsigned short* __restrict__ X,
                                                   const int* __restrict__ off,
                                                   const int* __restrict__ srow,
                                                   const float* __restrict__ dis,
                                                   const float* __restrict__ scl,
                                                   const float* __restrict__ shf,
                                                   unsigned short* __restrict__ Y) {
    constexpr int EPL = C / 64;
    int lane = threadIdx.x & 63;
    int c = blockIdx.x * 4 + (threadIdx.x >> 6);
    float dc = dis[c];
    float acc[EPL];
    float wsum = dc;
    {
        unsigned short t[EPL];
        const unsigned short* xc = X + (size_t)c * C + lane * EPL;
        if constexpr (EPL == 4) *(uint2*)t = *(const uint2*)xc;
        else *(unsigned int*)t = *(const unsigned int*)xc;
#pragma unroll
        for (int e2 = 0; e2 < EPL; ++e2) acc[e2] = dc * bf2f(t[e2]);
    }
    int s = off[c], en = off[c + 1];
    int i = s;
    for (; i + 4 <= en; i += 4) {
        int r0 = srow[i], r1 = srow[i + 1], r2 = srow[i + 2], r3 = srow[i + 3];
        float d0 = dis[r0], d1 = dis[r1], d2 = dis[r2], d3 = dis[r3];
        unsigned short t0[EPL], t1[EPL], t2[EPL], t3[EPL];
        const unsigned short* p0 = X + (size_t)r0 * C + lane * EPL;
        const unsigned short* p1 = X + (size_t)r1 * C + lane * EPL;
        const unsigned short* p2 = X + (size_t)r2 * C + lane * EPL;
        const unsigned short* p3 = X + (size_t)r3 * C + lane * EPL;
        if constexpr (EPL == 4) {
            *(uint2*)t0 = *(const uint2*)p0;
            *(uint2*)t1 = *(const uint2*)p1;
            *(uint2*)t2 = *(const uint2*)p2;
            *(uint2*)t3 = *(const uint2*)p3;
        } else {
            *(unsigned int*)t0 = *(const unsigned int*)p0;
            *(unsigned int*)t1 = *(const unsigned int*)p1;
            *(unsigned int*)t2 = *(const unsigned int*)p2;
            *(unsigned int*)t3 = *(const unsigned int*)p3;
        }
        wsum += d0 + d1 + d2 + d3;
#pragma unroll
        for (int e2 = 0; e2 < EPL; ++e2) {
            acc[e2] += d0 * bf2f(t0[e2]) + d1 * bf2f(t1[e2]) +
                       d2 * bf2f(t2[e2]) + d3 * bf2f(t3[e2]);
        }
    }
    for (; i < en; ++i) {
        int r = srow[i];
        float dr = dis[r];
        unsigned short t[EPL];
        const unsigned short* xr = X + (size_t)r * C + lane * EPL;
        if constexpr (EPL == 4) *(uint2*)t = *(const uint2*)xr;
        else *(unsigned int*)t = *(const unsigned int*)xr;
        wsum += dr;
#pragma unroll
        for (int e2 = 0; e2 < EPL; ++e2) acc[e2] += dr * bf2f(t[e2]);
    }
    unsigned short t[EPL];
#pragma unroll
    for (int e2 = 0; e2 < EPL; ++e2) {
        float v;
        if constexpr (FUSE_BN) {
            int j = lane * EPL + e2;
            v = dc * (scl[j] * acc[e2] + shf[j] * wsum);
        } else {
            v = dc * acc[e2];
        }
        t[e2] = f2bf(v);
    }
    unsigned short* yc = Y + (size_t)c * C + lane * EPL;
    if constexpr (EPL == 4) *(uint2*)yc = *(const uint2*)t;
    else *(unsigned int*)yc = *(const unsigned int*)t;
}

// ---------------------------------------------------------------------------
// MT=128 bf16 MFMA GEMM (QKV / ff1), proven round-5 structure: triple-buffered
// glds staging (depth-2 in flight, counted vmcnt), raw s_barrier, XCD swizzle,
// XOR-swizzled staging, coalesced LDS C-tile epilogue. 48 KB -> 3 blocks/CU.
__global__ __launch_bounds__(512, 8) void gemm_bf16_kernel(
    const unsigned short* __restrict__ A,
    const unsigned short* __restrict__ Bt,
    unsigned short* __restrict__ Cb,
    int M, int K, int N,
    const float* __restrict__ bias,
    const unsigned short* __restrict__ resb,
    const float* __restrict__ inter,
    int do_relu, int relu_first) {
    constexpr int LDP = 32;
    constexpr int CP = 136;
    constexpr int MI = 2;
    constexpr int STG = 8192;                // per-stage shorts: A 8KB | B 8KB
    constexpr int BOFS = 4096;
    __shared__ unsigned short Smem[3 * STG];
    unsigned short* Cs = Smem;               // union: staging dead after K-loop
    int gx = gridDim.x, gyP = gridDim.y >> 3;
    int d = blockIdx.y * gx + blockIdx.x;
    int xcd = d & 7, j2 = d >> 3;
    int bm = (xcd * gyP + j2 / gx) * 128;
    int bn = (j2 % gx) * 128;
    int tid = threadIdx.x;
    int wave = tid >> 6, lane = tid & 63;
    int wm = (wave >> 1) * 32;               // 4 m-waves x 2 n-waves
    int wn = (wave & 1) * 64;
    int lrc = lane & 15;
    int koct = lane >> 4;
    int rsw = (lrc >> 1) & 3;
    int rofs = (koct ^ rsw) * 8;
    int cg = (lane & 3) ^ ((lane >> 3) & 3);
    int skk = cg * 8;

    int sr = wave * 16 + (lane >> 2);
    const unsigned short* gA0 = A + (size_t)(bm + sr) * K + skk;
    const unsigned short* gB0 = Bt + (size_t)(bn + sr) * K + skk;
    int lofs = wave * 512 + lane * 8;

    f32x4 acc[MI][4];
#pragma unroll
    for (int i = 0; i < MI; ++i)
#pragma unroll
        for (int j = 0; j < 4; ++j) acc[i][j] = (f32x4){0.f, 0.f, 0.f, 0.f};

    glds16(gA0, Smem + lofs);
    glds16(gB0, Smem + BOFS + lofs);
    glds16(gA0 + 32, Smem + STG + lofs);
    glds16(gB0 + 32, Smem + STG + BOFS + lofs);

    int rb = 0;
    for (int k0 = 0; k0 < K; k0 += 32) {
        if (k0 + 64 < K) {
            int wb = rb + 2; if (wb >= 3) wb -= 3;
            unsigned short* ld = Smem + wb * STG;
            glds16(gA0 + k0 + 64, ld + lofs);
            glds16(gB0 + k0 + 64, ld + BOFS + lofs);
            WAIT_VM4();                       // drain stage t; t+1,t+2 in flight
        } else if (k0 + 32 < K) {
            WAIT_VM2();
        } else {
            WAIT_VM0();
        }
        __builtin_amdgcn_s_barrier();
        const unsigned short* Ab = Smem + rb * STG;
        const unsigned short* Bb = Ab + BOFS;
        bf16x8 af[MI], bfr[4];
#pragma unroll
        for (int i = 0; i < MI; ++i)
            af[i] = *(const bf16x8*)(Ab + (wm + i * 16 + lrc) * LDP + rofs);
#pragma unroll
        for (int j = 0; j < 4; ++j)
            bfr[j] = *(const bf16x8*)(Bb + (wn + j * 16 + lrc) * LDP + rofs);
#pragma unroll
        for (int i = 0; i < MI; ++i)
#pragma unroll
            for (int j = 0; j < 4; ++j)
                acc[i][j] = __builtin_amdgcn_mfma_f32_16x16x32_bf16(af[i], bfr[j],
                                                                    acc[i][j], 0, 0, 0);
        __builtin_amdgcn_s_barrier();
        rb = (rb + 1 == 3) ? 0 : rb + 1;
    }
#pragma unroll
    for (int i = 0; i < MI; ++i) {
#pragma unroll
        for (int r = 0; r < 4; ++r) {
            int lrow = wm + i * 16 + koct * 4 + r;
            int grow = bm + lrow;
#pragma unroll
            for (int j = 0; j < 4; ++j) {
                int lcol = wn + j * 16 + lrc;
                int gcol = bn + lcol;
                float v = acc[i][j][r];
                if (bias) v += bias[gcol];
                if (relu_first) v = fmaxf(v, 0.f);
                if (resb) v += bf2f(resb[(size_t)grow * N + gcol]);
                if (inter) v += inter[(grow >> 8) * N + gcol];
                if (do_relu && !relu_first) v = fmaxf(v, 0.f);
                Cs[lrow * CP + lcol] = f2bf(v);
            }
        }
    }
    __syncthreads();
#pragma unroll
    for (int it = 0; it < 4; ++it) {
        int row = it * 32 + (tid >> 4);
        int cc = (tid & 15) * 8;
        *(uint4*)(&Cb[(size_t)(bm + row) * N + bn + cc]) =
            *(const uint4*)(&Cs[row * CP + cc]);
    }
}

// ---------------------------------------------------------------------------
// 64x256 full-row-tile bf16 GEMM for N=256 layers (round-25).
// Round-7 post-mortem: the 32-row version regressed ff2 (42->56 us) because
// it doubled staging per MFMA (18 KB/32 MFMA) and dropped to depth-1.
// This shape: 8 waves x 32x64 wave-tile (2m x 4n): 8 MFMA per 6 ds_read
// (0.75 reads/MFMA), staging 20 KB per 64 MFMAs (half of 32-row), triple-
// buffered (depth-2, 60 KB LDS -> 2 blocks/CU = exactly the 512-block grid).
// Fusion modes unchanged:
//   MODE 0: plain copy-out                       (conv2)
//   MODE 1: copy-out + BN column-stats atomics   (conv1)
//   MODE 2: row LayerNorm -> write Cb            (oproj, in-place safe)
//   MODE 3: row LayerNorm -> column-sum atomics into outp (ff2+readout)
// vmcnt (in-order retirement, per staging role): waves 0-3 stage 3 loads
// (2 B + 1 A) -> VM6 steady / VM3 / VM0; waves 4-7 stage 2 -> VM4/VM2/VM0.
template <int MODE>
__global__ __launch_bounds__(512, 4) void gemm64n256_kernel(
    const unsigned short* __restrict__ A,
    const unsigned short* __restrict__ Bt,
    unsigned short* __restrict__ Cb,
    int K,
    const float* __restrict__ bias,
    const unsigned short* __restrict__ resb,
    const float* __restrict__ inter,
    int do_relu, int relu_first,
    float* __restrict__ stat0, float* __restrict__ stat1,
    const float* __restrict__ lng, const float* __restrict__ lnbt,
    float* __restrict__ outp) {
    constexpr int LDP = 32;
    constexpr int CP = 264;                  // 256 + 8 pad
    constexpr int STG = 10240;               // shorts: A 2048 | B 8192
    constexpr int BOFS = 2048;
    __shared__ unsigned short Smem[3 * STG]; // 60 KB
    unsigned short* Cs = Smem;               // union (64*264 = 16896 shorts)
    int bm = blockIdx.x * 64;
    int tid = threadIdx.x;
    int wave = tid >> 6, lane = tid & 63;
    int wm = (wave >> 2) * 32;               // 2 m-waves x 4 n-waves
    int wn = (wave & 3) * 64;
    int lrc = lane & 15;
    int koct = lane >> 4;
    int rsw = (lrc >> 1) & 3;
    int rofs = (koct ^ rsw) * 8;
    int cg = (lane & 3) ^ ((lane >> 3) & 3);
    int skk = cg * 8;

    // Staging: every wave stages B rows [wave*32, +32) (2 glds);
    // waves 0-3 additionally stage A rows [bm + wave*16, +16) (1 glds).
    const unsigned short* gB0 = Bt + (size_t)(wave * 32 + (lane >> 2)) * K + skk;
    size_t g16 = (size_t)16 * K;
    int lofsB = BOFS + wave * 1024 + lane * 8;
    const unsigned short* gA0 = nullptr;
    int lofsA = 0;
    if (wave < 4) {
        gA0 = A + (size_t)(bm + wave * 16 + (lane >> 2)) * K + skk;
        lofsA = wave * 512 + lane * 8;
    }

    f32x4 acc[2][4];
#pragma unroll
    for (int i = 0; i < 2; ++i)
#pragma unroll
        for (int j = 0; j < 4; ++j) acc[i][j] = (f32x4){0.f, 0.f, 0.f, 0.f};

    // prologue: stages 0 and 1
#pragma unroll
    for (int st = 0; st < 2; ++st) {
        unsigned short* s = Smem + st * STG;
        glds16(gB0 + st * 32, s + lofsB);
        glds16(gB0 + st * 32 + g16, s + lofsB + 512);
        if (wave < 4) glds16(gA0 + st * 32, s + lofsA);
    }

    int rb = 0;
    for (int k0 = 0; k0 < K; k0 += 32) {
        if (k0 + 64 < K) {
            int wb = rb + 2; if (wb >= 3) wb -= 3;
            unsigned short* s = Smem + wb * STG;
            glds16(gB0 + k0 + 64, s + lofsB);
            glds16(gB0 + k0 + 64 + g16, s + lofsB + 512);
            if (wave < 4) {
                glds16(gA0 + k0 + 64, s + lofsA);
                WAIT_VM6();                  // stage t done; t+1,t+2 in flight
            } else {
                WAIT_VM4();
            }
        } else if (k0 + 32 < K) {
            if (wave < 4) WAIT_VM3(); else WAIT_VM2();
        } else {
            WAIT_VM0();
        }
        __builtin_amdgcn_s_barrier();
        const unsigned short* Ab = Smem + rb * STG;
        const unsigned short* Bb = Ab + BOFS;
        bf16x8 af[2], bfr[4];
#pragma unroll
        for (int i = 0; i < 2; ++i)
            af[i] = *(const bf16x8*)(Ab + (wm + i * 16 + lrc) * LDP + rofs);
#pragma unroll
        for (int j = 0; j < 4; ++j)
            bfr[j] = *(const bf16x8*)(Bb + (wn + j * 16 + lrc) * LDP + rofs);
#pragma unroll
        for (int i = 0; i < 2; ++i)
#pragma unroll
            for (int j = 0; j < 4; ++j)
                acc[i][j] = __builtin_amdgcn_mfma_f32_16x16x32_bf16(af[i], bfr[j],
                                                                    acc[i][j], 0, 0, 0);
        __builtin_amdgcn_s_barrier();
        rb = (rb + 1 == 3) ? 0 : rb + 1;
    }
    // Finalize into Cs (bias/relu/res/inter applied in regs).
#pragma unroll
    for (int i = 0; i < 2; ++i) {
#pragma unroll
        for (int r = 0; r < 4; ++r) {
            int lrow = wm + i * 16 + koct * 4 + r;
            int grow = bm + lrow;
#pragma unroll
            for (int j = 0; j < 4; ++j) {
                int lcol = wn + j * 16 + lrc;
                float v = acc[i][j][r];
                if (bias) v += bias[lcol];
                if (relu_first) v = fmaxf(v, 0.f);
                if (resb) v += bf2f(resb[(size_t)grow * 256 + lcol]);
                if (inter) v += inter[(grow >> 8) * 256 + lcol];
                if (do_relu && !relu_first) v = fmaxf(v, 0.f);
                Cs[lrow * CP + lcol] = f2bf(v);
            }
        }
    }
    __syncthreads();

    if constexpr (MODE == 0 || MODE == 1) {
        // Coalesced copy-out: 4 iters x 16 rows; one uint4 per thread.
#pragma unroll
        for (int it = 0; it < 4; ++it) {
            int row = it * 16 + (tid >> 5);
            int cc = (tid & 31) * 8;
            *(uint4*)(&Cb[(size_t)(bm + row) * 256 + cc]) =
                *(const uint4*)(&Cs[row * CP + cc]);
        }
        if constexpr (MODE == 1) {
            if (tid < 256) {
                float s = 0.f, sq = 0.f;
                for (int r = 0; r < 64; ++r) {
                    float v = bf2f(Cs[r * CP + tid]);
                    s += v; sq += v * v;
                }
                atomicAdd(&stat0[tid], s);
                atomicAdd(&stat1[tid], sq);
            }
        }
    } else {
        // LN modes: wave handles rows [wave*8, wave*8+8), lane owns cols lane*4..+3.
        float4 g4 = *(const float4*)(lng + lane * 4);
        float4 b4 = *(const float4*)(lnbt + lane * 4);
#pragma unroll
        for (int q = 0; q < 8; ++q) {
            int row = wave * 8 + q;
            unsigned short tv[4];
            *(uint2*)tv = *(const uint2*)(Cs + row * CP + lane * 4);
            float v0 = bf2f(tv[0]), v1 = bf2f(tv[1]), v2 = bf2f(tv[2]), v3 = bf2f(tv[3]);
            float sum = v0 + v1 + v2 + v3;
#pragma unroll
            for (int off = 32; off; off >>= 1) sum += __shfl_xor(sum, off);
            float mu = sum * (1.f / (float)DH_);
            float d0 = v0 - mu, d1 = v1 - mu, d2 = v2 - mu, d3 = v3 - mu;
            float vs = d0 * d0 + d1 * d1 + d2 * d2 + d3 * d3;
#pragma unroll
            for (int off = 32; off; off >>= 1) vs += __shfl_xor(vs, off);
            float rs = rsqrtf(vs * (1.f / (float)DH_) + EPS_);
            unsigned short ov[4];
            ov[0] = f2bf(d0 * rs * g4.x + b4.x);
            ov[1] = f2bf(d1 * rs * g4.y + b4.y);
            ov[2] = f2bf(d2 * rs * g4.z + b4.z);
            ov[3] = f2bf(d3 * rs * g4.w + b4.w);
            if constexpr (MODE == 2) {
                *(uint2*)(&Cb[(size_t)(bm + row) * 256 + lane * 4]) = *(uint2*)ov;
            } else {
                *(uint2*)(Cs + row * CP + lane * 4) = *(uint2*)ov;
            }
        }
        if constexpr (MODE == 3) {
            __syncthreads();
            if (tid < 256) {
                float s = 0.f;
                for (int r = 0; r < 64; ++r) s += bf2f(Cs[r * CP + tid]);
                atomicAdd(&outp[(bm >> 8) * 256 + tid], s);
            }
        }
    }
}

// ---------------------------------------------------------------------------
// MFMA flash attention, transposed-score, no online softmax.
// P kept fully in-register: QK^T C-fragment -> v_cvt_pk_bf16_f32 ->
// permlane32_swap + permlane16_swap -> PV A-fragment. No Ps LDS buffer.
__global__ __launch_bounds__(256, 4) void attn_mfma_kernel(
    const unsigned short* __restrict__ QKV,
    unsigned short* __restrict__ Ob) {
    int b = blockIdx.x >> 3, h = blockIdx.x & 7;
    __shared__ unsigned short Ks[256 * 32];    // XOR-swizzled chunks
    __shared__ unsigned short Vt[32 * 264];    // [d][key 256 + pad]
    __shared__ float Lc[4 * 64];               // per-wave l broadcast
    const unsigned short* kg = QKV + (size_t)b * 256 * 768 + 256 + h * 32;
    const unsigned short* vg = QKV + (size_t)b * 256 * 768 + 512 + h * 32;
    int tid = threadIdx.x;
#pragma unroll
    for (int it = 0; it < 4; ++it) {
        int c = it * 256 + tid;
        int row = c >> 2, ch = c & 3;
        int slot = ch ^ ((row >> 1) & 3);
        *(uint4*)(Ks + row * 32 + slot * 8) =
            *(const uint4*)(kg + (size_t)row * 768 + ch * 8);
    }
#pragma unroll
    for (int it = 0; it < 4; ++it) {
        int c = it * 256 + tid;
        int key = c >> 2, d0 = (c & 3) * 8;
        unsigned short tmp[8];
        *(uint4*)tmp = *(const uint4*)(vg + (size_t)key * 768 + d0);
#pragma unroll
        for (int j = 0; j < 8; ++j) Vt[(d0 + j) * 264 + key] = tmp[j];
    }
    __syncthreads();

    int wave = tid >> 6, lane = tid & 63;
    int lr = lane & 15, koct = lane >> 4;
    int s4 = (lr >> 1) & 3;
    int qrow0 = b * 256 + wave * 64;
    bf16x8 qf[4];
#pragma unroll
    for (int j = 0; j < 4; ++j)
        qf[j] = *(const bf16x8*)(QKV + (size_t)(qrow0 + j * 16 + lr) * 768 + h * 32 + koct * 8);

    f32x4 Oa[4][2];
    float lp[4];
#pragma unroll
    for (int i = 0; i < 4; ++i) {
        Oa[i][0] = (f32x4){0.f, 0.f, 0.f, 0.f};
        Oa[i][1] = (f32x4){0.f, 0.f, 0.f, 0.f};
        lp[i] = 0.f;
    }
    float* Lw = Lc + wave * 64;

    for (int kc = 0; kc < 256; kc += 32) {
        bf16x8 kf0 = *(const bf16x8*)(Ks + (kc + lr) * 32 + (koct ^ s4) * 8);
        bf16x8 kf1 = *(const bf16x8*)(Ks + (kc + 16 + lr) * 32 + (koct ^ s4) * 8);
        bf16x8 pfr[4];
#pragma unroll
        for (int j = 0; j < 4; ++j) {
            f32x4 St0 = __builtin_amdgcn_mfma_f32_16x16x32_bf16(kf0, qf[j],
                            (f32x4){0.f, 0.f, 0.f, 0.f}, 0, 0, 0);
            f32x4 St1 = __builtin_amdgcn_mfma_f32_16x16x32_bf16(kf1, qf[j],
                            (f32x4){0.f, 0.f, 0.f, 0.f}, 0, 0, 0);
            float p0[4], p1[4], ps = 0.f;
#pragma unroll
            for (int r = 0; r < 4; ++r) {
                p0[r] = exp2f(St0[r]); p1[r] = exp2f(St1[r]);
                ps += p0[r] + p1[r];
            }
            lp[j] += ps;
            unsigned int w0a, w0b, w1a, w1b;
            asm("v_cvt_pk_bf16_f32 %0, %1, %2" : "=v"(w0a) : "v"(p0[0]), "v"(p0[1]));
            asm("v_cvt_pk_bf16_f32 %0, %1, %2" : "=v"(w0b) : "v"(p0[2]), "v"(p0[3]));
            asm("v_cvt_pk_bf16_f32 %0, %1, %2" : "=v"(w1a) : "v"(p1[0]), "v"(p1[1]));
            asm("v_cvt_pk_bf16_f32 %0, %1, %2" : "=v"(w1b) : "v"(p1[2]), "v"(p1[3]));
            u32x2 sa = __builtin_amdgcn_permlane32_swap(w0a, w1a, false, false);
            u32x2 da = __builtin_amdgcn_permlane16_swap(sa[0], sa[1], false, false);
            u32x2 sb = __builtin_amdgcn_permlane32_swap(w0b, w1b, false, false);
            u32x2 db = __builtin_amdgcn_permlane16_swap(sb[0], sb[1], false, false);
            u32x4 pw = {da[0], db[0], da[1], db[1]};
            pfr[j] = __builtin_bit_cast(bf16x8, pw);
        }
        bf16x8 vf0 = *(const bf16x8*)(Vt + lr * 264 + kc + koct * 8);
        bf16x8 vf1 = *(const bf16x8*)(Vt + (16 + lr) * 264 + kc + koct * 8);
#pragma unroll
        for (int i = 0; i < 4; ++i) {
            Oa[i][0] = __builtin_amdgcn_mfma_f32_16x16x32_bf16(pfr[i], vf0, Oa[i][0], 0, 0, 0);
            Oa[i][1] = __builtin_amdgcn_mfma_f32_16x16x32_bf16(pfr[i], vf1, Oa[i][1], 0, 0, 0);
        }
    }
#pragma unroll
    for (int j = 0; j < 4; ++j) {
        lp[j] += __shfl_xor(lp[j], 16);
        lp[j] += __shfl_xor(lp[j], 32);
    }
    if (koct == 0) {
#pragma unroll
        for (int j = 0; j < 4; ++j) Lw[j * 16 + lr] = lp[j];
    }
    __builtin_amdgcn_s_waitcnt(0);
#pragma unroll
    for (int i = 0; i < 4; ++i) {
        f32x4 l4 = *(const f32x4*)(Lw + i * 16 + koct * 4);
#pragma unroll
        for (int r = 0; r < 4; ++r) {
            float inv = 1.f / l4[r];
            int row = qrow0 + i * 16 + koct * 4 + r;
#pragma unroll
            for (int jn = 0; jn < 2; ++jn) {
                int col = h * 32 + jn * 16 + lr;
                Ob[(size_t)row * 256 + col] = f2bf(Oa[i][jn][r] * inv);
            }
        }
    }
}

// ---------------------------------------------------------------------------
extern "C" void kernel_launch(void* const* d_in, const int* in_sizes, int n_in,
                              void* d_out, int out_size, void* d_ws, size_t ws_size,
                              hipStream_t stream) {
    const float* x       = (const float*)d_in[0];
    const int*   ei      = (const int*)d_in[1];
    const float* inter_f = (const float*)d_in[3];
    const float* bn1_g = (const float*)d_in[4],  *bn1_b = (const float*)d_in[5];
    const float* bn2_g = (const float*)d_in[6],  *bn2_b = (const float*)d_in[7];
    const float* w_conv1 = (const float*)d_in[8],  *b_conv1 = (const float*)d_in[9];
    const float* w_conv2 = (const float*)d_in[10], *b_conv2 = (const float*)d_in[11];
    const float* wq = (const float*)d_in[12], *bq = (const float*)d_in[13];
    const float* wk = (const float*)d_in[14], *bk = (const float*)d_in[15];
    const float* wv = (const float*)d_in[16], *bv = (const float*)d_in[17];
    const float* wo = (const float*)d_in[18], *bo = (const float*)d_in[19];
    const float* ln1_g = (const float*)d_in[20], *ln1_b = (const float*)d_in[21];
    const float* ln2_g = (const float*)d_in[22], *ln2_b = (const float*)d_in[23];
    const float* w_ff1 = (const float*)d_in[24], *b_ff1 = (const float*)d_in[25];
    const float* w_ff2 = (const float*)d_in[26], *b_ff2 = (const float*)d_in[27];
    float* out = (float*)d_out;

    char* base = (char*)d_ws;
    size_t o = 0;
    auto alloc = [&](size_t bytes) -> void* {
        void* p = base + o;
        o = (o + bytes + 255) & ~(size_t)255;
        return p;
    };
    int*   deg    = (int*)alloc(NN * 4);
    int*   off    = (int*)alloc((NN + 1) * 4);
    int*   cnt    = (int*)alloc(NN * 4);
    int*   srow   = (int*)alloc(EE * 4);
    float* dis    = (float*)alloc(NN * 4);
    float* csum   = (float*)alloc(256 * 4);   // BN1 stats (contiguous 4 KB
    float* csumsq = (float*)alloc(256 * 4);   //  block with csum2/csumsq2,
    float* csum2  = (float*)alloc(256 * 4);   //  zeroed in one memset)
    float* csumsq2= (float*)alloc(256 * 4);
    float* scl    = (float*)alloc(256 * 4);
    float* shf    = (float*)alloc(256 * 4);
    float* bqkv   = (float*)alloc(768 * 4);
    const size_t SLOT = (size_t)NN * DH_;  // 8M elements (16 MB bf16)
    unsigned short* Arena = (unsigned short*)alloc((size_t)NN * DFF_ * 2);
    unsigned short* TB = (unsigned short*)alloc(SLOT * 2);  // tb
    unsigned short* B0 = (unsigned short*)alloc(SLOT * 2);  // Xb->h1b->Ob->t2b
    unsigned short* wc1t  = (unsigned short*)alloc((size_t)DIN_ * DH_ * 2);
    unsigned short* wc2t  = (unsigned short*)alloc((size_t)DH_ * DH_ * 2);
    unsigned short* wqkvt = (unsigned short*)alloc((size_t)DH_ * DH_ * 3 * 2);
    unsigned short* wot   = (unsigned short*)alloc((size_t)DH_ * DH_ * 2);
    unsigned short* wf1t  = (unsigned short*)alloc((size_t)DH_ * DFF_ * 2);
    unsigned short* wf2t  = (unsigned short*)alloc((size_t)DFF_ * DH_ * 2);
    unsigned short* Xa   = Arena;                            // NN*DIN (4M)
    unsigned short* X2a  = Arena + (size_t)NN * DIN_;        // [4M..12M)
    unsigned short* QKVb = Arena;                            // [0..24M)
    unsigned short* Fb   = Arena;                            // [0..32M)
    unsigned short* tb   = TB;

    hipMemsetAsync(deg, 0, NN * 4, stream);
    hipMemsetAsync(cnt, 0, NN * 4, stream);
    hipMemsetAsync(csum, 0, 4096, stream);                   // all 4 stat arrays
    hipMemsetAsync(out, 0, BG * DH_ * 4, stream);            // readout atomics target

    // Weight transposes (bf16; wq pre-scaled by QSCALE) + QKV bias concat
    wtrans_kernel<<<(DIN_ * DH_ + 255) / 256, 256, 0, stream>>>(w_conv1, wc1t, DIN_, DH_, 1.f);
    wtrans_kernel<<<(DH_ * DH_ + 255) / 256, 256, 0, stream>>>(w_conv2, wc2t, DH_, DH_, 1.f);
    wtrans_kernel<<<(DH_ * DH_ + 255) / 256, 256, 0, stream>>>(wq, wqkvt, DH_, DH_, QSCALE);
    wtrans_kernel<<<(DH_ * DH_ + 255) / 256, 256, 0, stream>>>(wk, wqkvt + DH_ * DH_, DH_, DH_, 1.f);
    wtrans_kernel<<<(DH_ * DH_ + 255) / 256, 256, 0, stream>>>(wv, wqkvt + 2 * DH_ * DH_, DH_, DH_, 1.f);
    wtrans_kernel<<<(DH_ * DH_ + 255) / 256, 256, 0, stream>>>(wo, wot, DH_, DH_, 1.f);
    wtrans_kernel<<<(DH_ * DFF_ + 255) / 256, 256, 0, stream>>>(w_ff1, wf1t, DH_, DFF_, 1.f);
    wtrans_kernel<<<(DFF_ * DH_ + 255) / 256, 256, 0, stream>>>(w_ff2, wf2t, DFF_, DH_, 1.f);
    bcat_kernel<<<3, 256, 0, stream>>>(bq, bk, bv, bqkv);

    // Fused init_avg_h + BN1 stats (one pass over x)
    initstats_kernel<<<BG, 128, 0, stream>>>(x, out + BG * DH_, csum, csumsq);
    bnfin_kernel<DIN_><<<1, DIN_, 0, stream>>>(csum, csumsq, bn1_g, bn1_b, scl, shf);
    bnapply_kernel<DIN_><<<NN * DIN_ / 256, 256, 0, stream>>>(x, scl, shf, B0);

    // CSR build
    deg_kernel<<<EE / 256, 256, 0, stream>>>(ei + EE, deg);
    scan_kernel<<<1, 1024, 0, stream>>>(deg, off, dis);
    scatter_kernel<<<EE / 256, 256, 0, stream>>>(ei, ei + EE, off, cnt, srow);

    // agg1 (A·X)·W == A·(X·W): Xa = Anorm @ Xb (bf16, 128 cols)
    aggb_kernel<DIN_, 0><<<NN / 4, 256, 0, stream>>>(B0, off, srow, dis,
                                                     nullptr, nullptr, Xa);
    // conv1 (MODE 1): h1b = relu(Xa @ w_conv1 + b) -> B0 ; fused BN2 stats
    gemm64n256_kernel<1><<<NN / 64, 512, 0, stream>>>(
        Xa, wc1t, B0, DIN_, b_conv1, nullptr, nullptr, 1, 0,
        csum2, csumsq2, nullptr, nullptr, nullptr);
    bnfin_kernel<DH_><<<1, DH_, 0, stream>>>(csum2, csumsq2, bn2_g, bn2_b, scl, shf);

    // agg2 with fused BN apply: X2a = Anorm @ (h1b*s + b)
    aggb_kernel<DH_, 1><<<NN / 4, 256, 0, stream>>>(B0, off, srow, dis,
                                                    scl, shf, X2a);
    // conv2 (MODE 0): tb = h1b + relu(X2a @ w_conv2 + b) + inter[graph] -> TB
    gemm64n256_kernel<0><<<NN / 64, 512, 0, stream>>>(
        X2a, wc2t, tb, DH_, b_conv2, B0, inter_f, 1, 1,
        nullptr, nullptr, nullptr, nullptr, nullptr);

    // Fused QKV (N=768, MT=128): QKVb = tb @ [wq*s|wk|wv] + bqkv
    gemm_bf16_kernel<<<dim3(768 / 128, NN / 128), 512, 0, stream>>>(
        tb, wqkvt, QKVb, NN, DH_, 768, bqkv, nullptr, nullptr, 0, 0);

    // MFMA flash attention -> Ob (B0; h1b dead)
    attn_mfma_kernel<<<BG * NH, 256, 0, stream>>>(QKVb, B0);

    // O-proj (MODE 2): t2b = LN1(Ob @ wo + bo + tb) -> B0 in-place
    gemm64n256_kernel<2><<<NN / 64, 512, 0, stream>>>(
        B0, wot, B0, DH_, bo, tb, nullptr, 0, 0,
        nullptr, nullptr, ln1_g, ln1_b, nullptr);

    // ff1 (N=1024, MT=128): Fb = relu(t2b @ w_ff1 + b1)
    gemm_bf16_kernel<<<dim3(DFF_ / 128, NN / 128), 512, 0, stream>>>(
        B0, wf1t, Fb, NN, DH_, DFF_, b_ff1, nullptr, nullptr, 1, 0);

    // ff2 (MODE 3): LN2(Fb @ w_ff2 + b2 + t2b) -> per-graph column sums -> out
    gemm64n256_kernel<3><<<NN / 64, 512, 0, stream>>>(
        Fb, wf2t, nullptr, DFF_, b_ff2, B0, nullptr, 0, 0,
        nullptr, nullptr, ln2_g, ln2_b, out);
}

// Round 9
// 517.116 us; speedup vs baseline: 1.0970x; 1.0089x over previous
//
#include <hip/hip_runtime.h>
#include <math.h>

// Problem constants (fixed by the reference)
#define NN   32768
#define BG   128
#define SG   256
#define EE   524288
#define DIN_ 128
#define DH_  256
#define NH   8
#define HD_  32
#define DFF_ 1024
#define EPS_ 1e-5f

typedef __attribute__((ext_vector_type(8))) short bf16x8;
typedef __attribute__((ext_vector_type(4))) float f32x4;
typedef __attribute__((ext_vector_type(2))) unsigned int u32x2;
typedef __attribute__((ext_vector_type(4))) unsigned int u32x4;

__device__ __forceinline__ unsigned short f2bf(float f) {
    unsigned int u = __builtin_bit_cast(unsigned int, f);
    unsigned int r = u + 0x7FFFu + ((u >> 16) & 1u);
    return (unsigned short)(r >> 16);
}
__device__ __forceinline__ float bf2f(unsigned short u) {
    return __builtin_bit_cast(float, (unsigned int)u << 16);
}
// Async global->LDS DMA, 16 B per lane (dest = wave-uniform base + lane*16).
__device__ __forceinline__ void glds16(const unsigned short* g, unsigned short* l) {
    __builtin_amdgcn_global_load_lds(
        (const __attribute__((address_space(1))) void*)g,
        (__attribute__((address_space(3))) void*)l, 16, 0, 0);
}
// s_waitcnt with vmcnt(N) only (exp/lgkm masked off).
#define WAIT_VM0() __builtin_amdgcn_s_waitcnt(0x0F70)
#define WAIT_VM1() __builtin_amdgcn_s_waitcnt(0x0F71)
#define WAIT_VM2() __builtin_amdgcn_s_waitcnt(0x0F72)
#define WAIT_VM3() __builtin_amdgcn_s_waitcnt(0x0F73)
#define WAIT_VM4() __builtin_amdgcn_s_waitcnt(0x0F74)

// Softmax pre-scale: 1/sqrt(32) * log2(e), folded into wq/bq at transpose time.
#define QSCALE (0.17677669529663689f * 1.4426950408889634f)

// ---------------------------------------------------------------------------
// Fused init_avg_h + BN1 column stats: one pass over x.
__global__ __launch_bounds__(128) void initstats_kernel(const float* __restrict__ X,
                                                        float* __restrict__ out2,
                                                        float* __restrict__ csum,
                                                        float* __restrict__ csumsq) {
    int b = blockIdx.x, j = threadIdx.x;
    float s = 0.f, sq = 0.f;
    for (int r = 0; r < SG; ++r) {
        float v = X[(size_t)(b * SG + r) * DIN_ + j];
        s += v; sq += v * v;
    }
    out2[b * DIN_ + j] = s * (1.f / (float)SG);
    atomicAdd(&csum[j], s);
    atomicAdd(&csumsq[j], sq);
}

template <int C>
__global__ __launch_bounds__(C) void bnfin_kernel(const float* __restrict__ csum,
                                                  const float* __restrict__ csumsq,
                                                  const float* __restrict__ g,
                                                  const float* __restrict__ b,
                                                  float* __restrict__ scale,
                                                  float* __restrict__ shift) {
    int j = threadIdx.x;
    float mu  = csum[j] * (1.f / (float)NN);
    float var = csumsq[j] * (1.f / (float)NN) - mu * mu;
    float s = g[j] * rsqrtf(var + EPS_);
    scale[j] = s;
    shift[j] = b[j] - mu * s;
}

// BN apply, fp32 in -> bf16 out (BN1).
template <int C>
__global__ __launch_bounds__(256) void bnapply_kernel(const float* __restrict__ X,
                                                      const float* __restrict__ sc,
                                                      const float* __restrict__ sh,
                                                      unsigned short* __restrict__ Y) {
    int i = blockIdx.x * 256 + threadIdx.x;
    int j = i & (C - 1);
    Y[i] = f2bf(X[i] * sc[j] + sh[j]);
}

// Weight cast+transpose: W[K,N] fp32 -> Wt[N,K] bf16, optional scalar scale.
__global__ __launch_bounds__(256) void wtrans_kernel(const float* __restrict__ W,
                                                     unsigned short* __restrict__ Wt,
                                                     int K, int N, float scale) {
    int idx = blockIdx.x * 256 + threadIdx.x;
    if (idx < K * N) {
        int n = idx / K, k = idx - n * K;
        Wt[idx] = f2bf(W[(size_t)k * N + n] * scale);
    }
}

// Concat Q/K/V biases into one fp32[768]; Q part pre-scaled by QSCALE.
__global__ __launch_bounds__(256) void bcat_kernel(const float* __restrict__ bq,
                                                   const float* __restrict__ bk,
                                                   const float* __restrict__ bv,
                                                   float* __restrict__ o) {
    int j = threadIdx.x;
    if (blockIdx.x == 0) o[j] = bq[j] * QSCALE;
    else if (blockIdx.x == 1) o[DH_ + j] = bk[j];
    else o[2 * DH_ + j] = bv[j];
}

// ---------------------------------------------------------------------------
// CSR build
__global__ __launch_bounds__(256) void deg_kernel(const int* __restrict__ col,
                                                  int* __restrict__ deg) {
    int e = blockIdx.x * 256 + threadIdx.x;
    if (e < EE) atomicAdd(&deg[col[e]], 1);
}

__global__ __launch_bounds__(1024) void scan_kernel(const int* __restrict__ deg,
                                                    int* __restrict__ off,
                                                    float* __restrict__ dis) {
    __shared__ int sums[1024];
    int t = threadIdx.x;
    int base = t * 32;
    int loc[32];
    int run = 0;
#pragma unroll
    for (int i = 0; i < 32; ++i) { loc[i] = run; run += deg[base + i]; }
    sums[t] = run;
    __syncthreads();
    for (int d = 1; d < 1024; d <<= 1) {
        int tmp = (t >= d) ? sums[t - d] : 0;
        __syncthreads();
        sums[t] += tmp;
        __syncthreads();
    }
    int excl = sums[t] - run;
#pragma unroll
    for (int i = 0; i < 32; ++i) {
        off[base + i] = excl + loc[i];
        dis[base + i] = rsqrtf((float)(deg[base + i] + 1));
    }
    if (t == 1023) off[NN] = sums[1023];
}

__global__ __launch_bounds__(256) void scatter_kernel(const int* __restrict__ row,
                                                      const int* __restrict__ col,
                                                      const int* __restrict__ off,
                                                      int* __restrict__ cnt,
                                                      int* __restrict__ srow) {
    int e = blockIdx.x * 256 + threadIdx.x;
    if (e < EE) {
        int c = col[e];
        int p = off[c] + atomicAdd(&cnt[c], 1);
        srow[p] = row[e];
    }
}

// ---------------------------------------------------------------------------
// bf16 GCN aggregation, 4x-unrolled edge loop for MLP.
template <int C, int FUSE_BN>
__global__ __launch_bounds__(256) void aggb_kernel(const unsigned short* __restrict__ X,
                                                   const int* __restrict__ off,
                                                   const int* __restrict__ srow,
                                                   const float* __restrict__ dis,
                                                   const float* __restrict__ scl,
                                                   const float* __restrict__ shf,
                                                   unsigned short* __restrict__ Y) {
    constexpr int EPL = C / 64;
    int lane = threadIdx.x & 63;
    int c = blockIdx.x * 4 + (threadIdx.x >> 6);
    float dc = dis[c];
    float acc[EPL];
    float wsum = dc;
    {
        unsigned short t[EPL];
        const unsigned short* xc = X + (size_t)c * C + lane * EPL;
        if constexpr (EPL == 4) *(uint2*)t = *(const uint2*)xc;
        else *(unsigned int*)t = *(const unsigned int*)xc;
#pragma unroll
        for (int e2 = 0; e2 < EPL; ++e2) acc[e2] = dc * bf2f(t[e2]);
    }
    int s = off[c], en = off[c + 1];
    int i = s;
    for (; i + 4 <= en; i += 4) {
        int r0 = srow[i], r1 = srow[i + 1], r2 = srow[i + 2], r3 = srow[i + 3];
        float d0 = dis[r0], d1 = dis[r1], d2 = dis[r2], d3 = dis[r3];
        unsigned short t0[EPL], t1[EPL], t2[EPL], t3[EPL];
        const unsigned short* p0 = X + (size_t)r0 * C + lane * EPL;
        const unsigned short* p1 = X + (size_t)r1 * C + lane * EPL;
        const unsigned short* p2 = X + (size_t)r2 * C + lane * EPL;
        const unsigned short* p3 = X + (size_t)r3 * C + lane * EPL;
        if constexpr (EPL == 4) {
            *(uint2*)t0 = *(const uint2*)p0;
            *(uint2*)t1 = *(const uint2*)p1;
            *(uint2*)t2 = *(const uint2*)p2;
            *(uint2*)t3 = *(const uint2*)p3;
        } else {
            *(unsigned int*)t0 = *(const unsigned int*)p0;
            *(unsigned int*)t1 = *(const unsigned int*)p1;
            *(unsigned int*)t2 = *(const unsigned int*)p2;
            *(unsigned int*)t3 = *(const unsigned int*)p3;
        }
        wsum += d0 + d1 + d2 + d3;
#pragma unroll
        for (int e2 = 0; e2 < EPL; ++e2) {
            acc[e2] += d0 * bf2f(t0[e2]) + d1 * bf2f(t1[e2]) +
                       d2 * bf2f(t2[e2]) + d3 * bf2f(t3[e2]);
        }
    }
    for (; i < en; ++i) {
        int r = srow[i];
        float dr = dis[r];
        unsigned short t[EPL];
        const unsigned short* xr = X + (size_t)r * C + lane * EPL;
        if constexpr (EPL == 4) *(uint2*)t = *(const uint2*)xr;
        else *(unsigned int*)t = *(const unsigned int*)xr;
        wsum += dr;
#pragma unroll
        for (int e2 = 0; e2 < EPL; ++e2) acc[e2] += dr * bf2f(t[e2]);
    }
    unsigned short t[EPL];
#pragma unroll
    for (int e2 = 0; e2 < EPL; ++e2) {
        float v;
        if constexpr (FUSE_BN) {
            int j = lane * EPL + e2;
            v = dc * (scl[j] * acc[e2] + shf[j] * wsum);
        } else {
            v = dc * acc[e2];
        }
        t[e2] = f2bf(v);
    }
    unsigned short* yc = Y + (size_t)c * C + lane * EPL;
    if constexpr (EPL == 4) *(uint2*)yc = *(const uint2*)t;
    else *(unsigned int*)yc = *(const unsigned int*)t;
}

// ---------------------------------------------------------------------------
// MT=128 bf16 MFMA GEMM (QKV / ff1), proven round-5 structure: triple-buffered
// glds staging (depth-2 in flight, counted vmcnt), raw s_barrier, XCD swizzle,
// XOR-swizzled staging, coalesced LDS C-tile epilogue. 48 KB -> 3 blocks/CU.
__global__ __launch_bounds__(512, 8) void gemm_bf16_kernel(
    const unsigned short* __restrict__ A,
    const unsigned short* __restrict__ Bt,
    unsigned short* __restrict__ Cb,
    int M, int K, int N,
    const float* __restrict__ bias,
    const unsigned short* __restrict__ resb,
    const float* __restrict__ inter,
    int do_relu, int relu_first) {
    constexpr int LDP = 32;
    constexpr int CP = 136;
    constexpr int MI = 2;
    constexpr int STG = 8192;                // per-stage shorts: A 8KB | B 8KB
    constexpr int BOFS = 4096;
    __shared__ unsigned short Smem[3 * STG];
    unsigned short* Cs = Smem;               // union: staging dead after K-loop
    int gx = gridDim.x, gyP = gridDim.y >> 3;
    int d = blockIdx.y * gx + blockIdx.x;
    int xcd = d & 7, j2 = d >> 3;
    int bm = (xcd * gyP + j2 / gx) * 128;
    int bn = (j2 % gx) * 128;
    int tid = threadIdx.x;
    int wave = tid >> 6, lane = tid & 63;
    int wm = (wave >> 1) * 32;               // 4 m-waves x 2 n-waves
    int wn = (wave & 1) * 64;
    int lrc = lane & 15;
    int koct = lane >> 4;
    int rsw = (lrc >> 1) & 3;
    int rofs = (koct ^ rsw) * 8;
    int cg = (lane & 3) ^ ((lane >> 3) & 3);
    int skk = cg * 8;

    int sr = wave * 16 + (lane >> 2);
    const unsigned short* gA0 = A + (size_t)(bm + sr) * K + skk;
    const unsigned short* gB0 = Bt + (size_t)(bn + sr) * K + skk;
    int lofs = wave * 512 + lane * 8;

    f32x4 acc[MI][4];
#pragma unroll
    for (int i = 0; i < MI; ++i)
#pragma unroll
        for (int j = 0; j < 4; ++j) acc[i][j] = (f32x4){0.f, 0.f, 0.f, 0.f};

    glds16(gA0, Smem + lofs);
    glds16(gB0, Smem + BOFS + lofs);
    glds16(gA0 + 32, Smem + STG + lofs);
    glds16(gB0 + 32, Smem + STG + BOFS + lofs);

    int rb = 0;
    for (int k0 = 0; k0 < K; k0 += 32) {
        if (k0 + 64 < K) {
            int wb = rb + 2; if (wb >= 3) wb -= 3;
            unsigned short* ld = Smem + wb * STG;
            glds16(gA0 + k0 + 64, ld + lofs);
            glds16(gB0 + k0 + 64, ld + BOFS + lofs);
            WAIT_VM4();                       // drain stage t; t+1,t+2 in flight
        } else if (k0 + 32 < K) {
            WAIT_VM2();
        } else {
            WAIT_VM0();
        }
        __builtin_amdgcn_s_barrier();
        const unsigned short* Ab = Smem + rb * STG;
        const unsigned short* Bb = Ab + BOFS;
        bf16x8 af[MI], bfr[4];
#pragma unroll
        for (int i = 0; i < MI; ++i)
            af[i] = *(const bf16x8*)(Ab + (wm + i * 16 + lrc) * LDP + rofs);
#pragma unroll
        for (int j = 0; j < 4; ++j)
            bfr[j] = *(const bf16x8*)(Bb + (wn + j * 16 + lrc) * LDP + rofs);
#pragma unroll
        for (int i = 0; i < MI; ++i)
#pragma unroll
            for (int j = 0; j < 4; ++j)
                acc[i][j] = __builtin_amdgcn_mfma_f32_16x16x32_bf16(af[i], bfr[j],
                                                                    acc[i][j], 0, 0, 0);
        __builtin_amdgcn_s_barrier();
        rb = (rb + 1 == 3) ? 0 : rb + 1;
    }
#pragma unroll
    for (int i = 0; i < MI; ++i) {
#pragma unroll
        for (int r = 0; r < 4; ++r) {
            int lrow = wm + i * 16 + koct * 4 + r;
            int grow = bm + lrow;
#pragma unroll
            for (int j = 0; j < 4; ++j) {
                int lcol = wn + j * 16 + lrc;
                int gcol = bn + lcol;
                float v = acc[i][j][r];
                if (bias) v += bias[gcol];
                if (relu_first) v = fmaxf(v, 0.f);
                if (resb) v += bf2f(resb[(size_t)grow * N + gcol]);
                if (inter) v += inter[(grow >> 8) * N + gcol];
                if (do_relu && !relu_first) v = fmaxf(v, 0.f);
                Cs[lrow * CP + lcol] = f2bf(v);
            }
        }
    }
    __syncthreads();
#pragma unroll
    for (int it = 0; it < 4; ++it) {
        int row = it * 32 + (tid >> 4);
        int cc = (tid & 15) * 8;
        *(uint4*)(&Cb[(size_t)(bm + row) * N + bn + cc]) =
            *(const uint4*)(&Cs[row * CP + cc]);
    }
}

// ---------------------------------------------------------------------------
// 64x256 full-row-tile bf16 GEMM for N=256 layers (round-26).
// Round-8 post-mortem: triple-buffer (60 KB) halved occupancy to 2 blocks/CU
// (35%); every 42-us config had 4 blocks/CU. Rounds 1 vs 3 showed depth-1 ==
// depth-2 when 4 blocks are resident (TLP hides latency). So: DOUBLE-buffer,
// 2 x 20 KB = 40 KB -> exactly 4 blocks/CU; C-union (64x264x2 = 33.8 KB) fits.
// 8 waves x 32x64 wave-tile (2m x 4n): 8 MFMA per 6 ds_read (0.75/MFMA).
// Fusion modes:
//   MODE 0: plain copy-out                       (conv2)
//   MODE 1: copy-out + BN column-stats atomics   (conv1)
//   MODE 2: row LayerNorm -> write Cb            (oproj, in-place safe)
//   MODE 3: row LayerNorm -> column-sum atomics into outp (ff2+readout)
// vmcnt (in-order, per staging role): waves 0-3 stage 3 loads (2 B + 1 A)
// -> VM3 steady / VM0 last; waves 4-7 stage 2 -> VM2 / VM0.
// Buffer-reuse invariant: stage t+1 writes buf^1, whose readers all passed
// the trailing barrier of step t-1 (same as the proven round-1/2 kernel).
template <int MODE>
__global__ __launch_bounds__(512, 4) void gemm64n256_kernel(
    const unsigned short* __restrict__ A,
    const unsigned short* __restrict__ Bt,
    unsigned short* __restrict__ Cb,
    int K,
    const float* __restrict__ bias,
    const unsigned short* __restrict__ resb,
    const float* __restrict__ inter,
    int do_relu, int relu_first,
    float* __restrict__ stat0, float* __restrict__ stat1,
    const float* __restrict__ lng, const float* __restrict__ lnbt,
    float* __restrict__ outp) {
    constexpr int LDP = 32;
    constexpr int CP = 264;                  // 256 + 8 pad
    constexpr int STG = 10240;               // shorts: A 2048 | B 8192
    constexpr int BOFS = 2048;
    __shared__ unsigned short Smem[2 * STG]; // 40 KB -> 4 blocks/CU
    unsigned short* Cs = Smem;               // union (64*264 = 16896 shorts)
    int bm = blockIdx.x * 64;
    int tid = threadIdx.x;
    int wave = tid >> 6, lane = tid & 63;
    int wm = (wave >> 2) * 32;               // 2 m-waves x 4 n-waves
    int wn = (wave & 3) * 64;
    int lrc = lane & 15;
    int koct = lane >> 4;
    int rsw = (lrc >> 1) & 3;
    int rofs = (koct ^ rsw) * 8;
    int cg = (lane & 3) ^ ((lane >> 3) & 3);
    int skk = cg * 8;

    // Staging: every wave stages B rows [wave*32, +32) (2 glds);
    // waves 0-3 additionally stage A rows [bm + wave*16, +16) (1 glds).
    const unsigned short* gB0 = Bt + (size_t)(wave * 32 + (lane >> 2)) * K + skk;
    size_t g16 = (size_t)16 * K;
    int lofsB = BOFS + wave * 1024 + lane * 8;
    const unsigned short* gA0 = nullptr;
    int lofsA = 0;
    if (wave < 4) {
        gA0 = A + (size_t)(bm + wave * 16 + (lane >> 2)) * K + skk;
        lofsA = wave * 512 + lane * 8;
    }

    f32x4 acc[2][4];
#pragma unroll
    for (int i = 0; i < 2; ++i)
#pragma unroll
        for (int j = 0; j < 4; ++j) acc[i][j] = (f32x4){0.f, 0.f, 0.f, 0.f};

    // prologue: stage 0 into buf 0
    glds16(gB0, Smem + lofsB);
    glds16(gB0 + g16, Smem + lofsB + 512);
    if (wave < 4) glds16(gA0, Smem + lofsA);

    int cur = 0;
    for (int k0 = 0; k0 < K; k0 += 32) {
        int nk = k0 + 32;
        if (nk < K) {
            unsigned short* nb = Smem + (cur ^ 1) * STG;
            glds16(gB0 + nk, nb + lofsB);
            glds16(gB0 + nk + g16, nb + lofsB + 512);
            if (wave < 4) {
                glds16(gA0 + nk, nb + lofsA);
                WAIT_VM3();                  // stage t done; t+1 in flight
            } else {
                WAIT_VM2();
            }
        } else {
            WAIT_VM0();
        }
        __builtin_amdgcn_s_barrier();
        const unsigned short* Ab = Smem + cur * STG;
        const unsigned short* Bb = Ab + BOFS;
        bf16x8 af[2], bfr[4];
#pragma unroll
        for (int i = 0; i < 2; ++i)
            af[i] = *(const bf16x8*)(Ab + (wm + i * 16 + lrc) * LDP + rofs);
#pragma unroll
        for (int j = 0; j < 4; ++j)
            bfr[j] = *(const bf16x8*)(Bb + (wn + j * 16 + lrc) * LDP + rofs);
#pragma unroll
        for (int i = 0; i < 2; ++i)
#pragma unroll
            for (int j = 0; j < 4; ++j)
                acc[i][j] = __builtin_amdgcn_mfma_f32_16x16x32_bf16(af[i], bfr[j],
                                                                    acc[i][j], 0, 0, 0);
        __builtin_amdgcn_s_barrier();
        cur ^= 1;
    }
    // Finalize into Cs (bias/relu/res/inter applied in regs).
#pragma unroll
    for (int i = 0; i < 2; ++i) {
#pragma unroll
        for (int r = 0; r < 4; ++r) {
            int lrow = wm + i * 16 + koct * 4 + r;
            int grow = bm + lrow;
#pragma unroll
            for (int j = 0; j < 4; ++j) {
                int lcol = wn + j * 16 + lrc;
                float v = acc[i][j][r];
                if (bias) v += bias[lcol];
                if (relu_first) v = fmaxf(v, 0.f);
                if (resb) v += bf2f(resb[(size_t)grow * 256 + lcol]);
                if (inter) v += inter[(grow >> 8) * 256 + lcol];
                if (do_relu && !relu_first) v = fmaxf(v, 0.f);
                Cs[lrow * CP + lcol] = f2bf(v);
            }
        }
    }
    __syncthreads();

    if constexpr (MODE == 0 || MODE == 1) {
        // Coalesced copy-out: 4 iters x 16 rows; one uint4 per thread.
#pragma unroll
        for (int it = 0; it < 4; ++it) {
            int row = it * 16 + (tid >> 5);
            int cc = (tid & 31) * 8;
            *(uint4*)(&Cb[(size_t)(bm + row) * 256 + cc]) =
                *(const uint4*)(&Cs[row * CP + cc]);
        }
        if constexpr (MODE == 1) {
            if (tid < 256) {
                float s = 0.f, sq = 0.f;
                for (int r = 0; r < 64; ++r) {
                    float v = bf2f(Cs[r * CP + tid]);
                    s += v; sq += v * v;
                }
                atomicAdd(&stat0[tid], s);
                atomicAdd(&stat1[tid], sq);
            }
        }
    } else {
        // LN modes: wave handles rows [wave*8, wave*8+8), lane owns cols lane*4..+3.
        float4 g4 = *(const float4*)(lng + lane * 4);
        float4 b4 = *(const float4*)(lnbt + lane * 4);
#pragma unroll
        for (int q = 0; q < 8; ++q) {
            int row = wave * 8 + q;
            unsigned short tv[4];
            *(uint2*)tv = *(const uint2*)(Cs + row * CP + lane * 4);
            float v0 = bf2f(tv[0]), v1 = bf2f(tv[1]), v2 = bf2f(tv[2]), v3 = bf2f(tv[3]);
            float sum = v0 + v1 + v2 + v3;
#pragma unroll
            for (int off = 32; off; off >>= 1) sum += __shfl_xor(sum, off);
            float mu = sum * (1.f / (float)DH_);
            float d0 = v0 - mu, d1 = v1 - mu, d2 = v2 - mu, d3 = v3 - mu;
            float vs = d0 * d0 + d1 * d1 + d2 * d2 + d3 * d3;
#pragma unroll
            for (int off = 32; off; off >>= 1) vs += __shfl_xor(vs, off);
            float rs = rsqrtf(vs * (1.f / (float)DH_) + EPS_);
            unsigned short ov[4];
            ov[0] = f2bf(d0 * rs * g4.x + b4.x);
            ov[1] = f2bf(d1 * rs * g4.y + b4.y);
            ov[2] = f2bf(d2 * rs * g4.z + b4.z);
            ov[3] = f2bf(d3 * rs * g4.w + b4.w);
            if constexpr (MODE == 2) {
                *(uint2*)(&Cb[(size_t)(bm + row) * 256 + lane * 4]) = *(uint2*)ov;
            } else {
                *(uint2*)(Cs + row * CP + lane * 4) = *(uint2*)ov;
            }
        }
        if constexpr (MODE == 3) {
            __syncthreads();
            if (tid < 256) {
                float s = 0.f;
                for (int r = 0; r < 64; ++r) s += bf2f(Cs[r * CP + tid]);
                atomicAdd(&outp[(bm >> 8) * 256 + tid], s);
            }
        }
    }
}

// ---------------------------------------------------------------------------
// MFMA flash attention, transposed-score, no online softmax.
// P kept fully in-register: QK^T C-fragment -> v_cvt_pk_bf16_f32 ->
// permlane32_swap + permlane16_swap -> PV A-fragment. No Ps LDS buffer.
__global__ __launch_bounds__(256, 4) void attn_mfma_kernel(
    const unsigned short* __restrict__ QKV,
    unsigned short* __restrict__ Ob) {
    int b = blockIdx.x >> 3, h = blockIdx.x & 7;
    __shared__ unsigned short Ks[256 * 32];    // XOR-swizzled chunks
    __shared__ unsigned short Vt[32 * 264];    // [d][key 256 + pad]
    __shared__ float Lc[4 * 64];               // per-wave l broadcast
    const unsigned short* kg = QKV + (size_t)b * 256 * 768 + 256 + h * 32;
    const unsigned short* vg = QKV + (size_t)b * 256 * 768 + 512 + h * 32;
    int tid = threadIdx.x;
#pragma unroll
    for (int it = 0; it < 4; ++it) {
        int c = it * 256 + tid;
        int row = c >> 2, ch = c & 3;
        int slot = ch ^ ((row >> 1) & 3);
        *(uint4*)(Ks + row * 32 + slot * 8) =
            *(const uint4*)(kg + (size_t)row * 768 + ch * 8);
    }
#pragma unroll
    for (int it = 0; it < 4; ++it) {
        int c = it * 256 + tid;
        int key = c >> 2, d0 = (c & 3) * 8;
        unsigned short tmp[8];
        *(uint4*)tmp = *(const uint4*)(vg + (size_t)key * 768 + d0);
#pragma unroll
        for (int j = 0; j < 8; ++j) Vt[(d0 + j) * 264 + key] = tmp[j];
    }
    __syncthreads();

    int wave = tid >> 6, lane = tid & 63;
    int lr = lane & 15, koct = lane >> 4;
    int s4 = (lr >> 1) & 3;
    int qrow0 = b * 256 + wave * 64;
    bf16x8 qf[4];
#pragma unroll
    for (int j = 0; j < 4; ++j)
        qf[j] = *(const bf16x8*)(QKV + (size_t)(qrow0 + j * 16 + lr) * 768 + h * 32 + koct * 8);

    f32x4 Oa[4][2];
    float lp[4];
#pragma unroll
    for (int i = 0; i < 4; ++i) {
        Oa[i][0] = (f32x4){0.f, 0.f, 0.f, 0.f};
        Oa[i][1] = (f32x4){0.f, 0.f, 0.f, 0.f};
        lp[i] = 0.f;
    }
    float* Lw = Lc + wave * 64;

    for (int kc = 0; kc < 256; kc += 32) {
        bf16x8 kf0 = *(const bf16x8*)(Ks + (kc + lr) * 32 + (koct ^ s4) * 8);
        bf16x8 kf1 = *(const bf16x8*)(Ks + (kc + 16 + lr) * 32 + (koct ^ s4) * 8);
        bf16x8 pfr[4];
#pragma unroll
        for (int j = 0; j < 4; ++j) {
            f32x4 St0 = __builtin_amdgcn_mfma_f32_16x16x32_bf16(kf0, qf[j],
                            (f32x4){0.f, 0.f, 0.f, 0.f}, 0, 0, 0);
            f32x4 St1 = __builtin_amdgcn_mfma_f32_16x16x32_bf16(kf1, qf[j],
                            (f32x4){0.f, 0.f, 0.f, 0.f}, 0, 0, 0);
            float p0[4], p1[4], ps = 0.f;
#pragma unroll
            for (int r = 0; r < 4; ++r) {
                p0[r] = exp2f(St0[r]); p1[r] = exp2f(St1[r]);
                ps += p0[r] + p1[r];
            }
            lp[j] += ps;
            unsigned int w0a, w0b, w1a, w1b;
            asm("v_cvt_pk_bf16_f32 %0, %1, %2" : "=v"(w0a) : "v"(p0[0]), "v"(p0[1]));
            asm("v_cvt_pk_bf16_f32 %0, %1, %2" : "=v"(w0b) : "v"(p0[2]), "v"(p0[3]));
            asm("v_cvt_pk_bf16_f32 %0, %1, %2" : "=v"(w1a) : "v"(p1[0]), "v"(p1[1]));
            asm("v_cvt_pk_bf16_f32 %0, %1, %2" : "=v"(w1b) : "v"(p1[2]), "v"(p1[3]));
            u32x2 sa = __builtin_amdgcn_permlane32_swap(w0a, w1a, false, false);
            u32x2 da = __builtin_amdgcn_permlane16_swap(sa[0], sa[1], false, false);
            u32x2 sb = __builtin_amdgcn_permlane32_swap(w0b, w1b, false, false);
            u32x2 db = __builtin_amdgcn_permlane16_swap(sb[0], sb[1], false, false);
            u32x4 pw = {da[0], db[0], da[1], db[1]};
            pfr[j] = __builtin_bit_cast(bf16x8, pw);
        }
        bf16x8 vf0 = *(const bf16x8*)(Vt + lr * 264 + kc + koct * 8);
        bf16x8 vf1 = *(const bf16x8*)(Vt + (16 + lr) * 264 + kc + koct * 8);
#pragma unroll
        for (int i = 0; i < 4; ++i) {
            Oa[i][0] = __builtin_amdgcn_mfma_f32_16x16x32_bf16(pfr[i], vf0, Oa[i][0], 0, 0, 0);
            Oa[i][1] = __builtin_amdgcn_mfma_f32_16x16x32_bf16(pfr[i], vf1, Oa[i][1], 0, 0, 0);
        }
    }
#pragma unroll
    for (int j = 0; j < 4; ++j) {
        lp[j] += __shfl_xor(lp[j], 16);
        lp[j] += __shfl_xor(lp[j], 32);
    }
    if (koct == 0) {
#pragma unroll
        for (int j = 0; j < 4; ++j) Lw[j * 16 + lr] = lp[j];
    }
    __builtin_amdgcn_s_waitcnt(0);
#pragma unroll
    for (int i = 0; i < 4; ++i) {
        f32x4 l4 = *(const f32x4*)(Lw + i * 16 + koct * 4);
#pragma unroll
        for (int r = 0; r < 4; ++r) {
            float inv = 1.f / l4[r];
            int row = qrow0 + i * 16 + koct * 4 + r;
#pragma unroll
            for (int jn = 0; jn < 2; ++jn) {
                int col = h * 32 + jn * 16 + lr;
                Ob[(size_t)row * 256 + col] = f2bf(Oa[i][jn][r] * inv);
            }
        }
    }
}

// ---------------------------------------------------------------------------
extern "C" void kernel_launch(void* const* d_in, const int* in_sizes, int n_in,
                              void* d_out, int out_size, void* d_ws, size_t ws_size,
                              hipStream_t stream) {
    const float* x       = (const float*)d_in[0];
    const int*   ei      = (const int*)d_in[1];
    const float* inter_f = (const float*)d_in[3];
    const float* bn1_g = (const float*)d_in[4],  *bn1_b = (const float*)d_in[5];
    const float* bn2_g = (const float*)d_in[6],  *bn2_b = (const float*)d_in[7];
    const float* w_conv1 = (const float*)d_in[8],  *b_conv1 = (const float*)d_in[9];
    const float* w_conv2 = (const float*)d_in[10], *b_conv2 = (const float*)d_in[11];
    const float* wq = (const float*)d_in[12], *bq = (const float*)d_in[13];
    const float* wk = (const float*)d_in[14], *bk = (const float*)d_in[15];
    const float* wv = (const float*)d_in[16], *bv = (const float*)d_in[17];
    const float* wo = (const float*)d_in[18], *bo = (const float*)d_in[19];
    const float* ln1_g = (const float*)d_in[20], *ln1_b = (const float*)d_in[21];
    const float* ln2_g = (const float*)d_in[22], *ln2_b = (const float*)d_in[23];
    const float* w_ff1 = (const float*)d_in[24], *b_ff1 = (const float*)d_in[25];
    const float* w_ff2 = (const float*)d_in[26], *b_ff2 = (const float*)d_in[27];
    float* out = (float*)d_out;

    char* base = (char*)d_ws;
    size_t o = 0;
    auto alloc = [&](size_t bytes) -> void* {
        void* p = base + o;
        o = (o + bytes + 255) & ~(size_t)255;
        return p;
    };
    int*   deg    = (int*)alloc(NN * 4);
    int*   off    = (int*)alloc((NN + 1) * 4);
    int*   cnt    = (int*)alloc(NN * 4);
    int*   srow   = (int*)alloc(EE * 4);
    float* dis    = (float*)alloc(NN * 4);
    float* csum   = (float*)alloc(256 * 4);   // BN1 stats (contiguous 4 KB
    float* csumsq = (float*)alloc(256 * 4);   //  block with csum2/csumsq2,
    float* csum2  = (float*)alloc(256 * 4);   //  zeroed in one memset)
    float* csumsq2= (float*)alloc(256 * 4);
    float* scl    = (float*)alloc(256 * 4);
    float* shf    = (float*)alloc(256 * 4);
    float* bqkv   = (float*)alloc(768 * 4);
    const size_t SLOT = (size_t)NN * DH_;  // 8M elements (16 MB bf16)
    unsigned short* Arena = (unsigned short*)alloc((size_t)NN * DFF_ * 2);
    unsigned short* TB = (unsigned short*)alloc(SLOT * 2);  // tb
    unsigned short* B0 = (unsigned short*)alloc(SLOT * 2);  // Xb->h1b->Ob->t2b
    unsigned short* wc1t  = (unsigned short*)alloc((size_t)DIN_ * DH_ * 2);
    unsigned short* wc2t  = (unsigned short*)alloc((size_t)DH_ * DH_ * 2);
    unsigned short* wqkvt = (unsigned short*)alloc((size_t)DH_ * DH_ * 3 * 2);
    unsigned short* wot   = (unsigned short*)alloc((size_t)DH_ * DH_ * 2);
    unsigned short* wf1t  = (unsigned short*)alloc((size_t)DH_ * DFF_ * 2);
    unsigned short* wf2t  = (unsigned short*)alloc((size_t)DFF_ * DH_ * 2);
    unsigned short* Xa   = Arena;                            // NN*DIN (4M)
    unsigned short* X2a  = Arena + (size_t)NN * DIN_;        // [4M..12M)
    unsigned short* QKVb = Arena;                            // [0..24M)
    unsigned short* Fb   = Arena;                            // [0..32M)
    unsigned short* tb   = TB;

    hipMemsetAsync(deg, 0, NN * 4, stream);
    hipMemsetAsync(cnt, 0, NN * 4, stream);
    hipMemsetAsync(csum, 0, 4096, stream);                   // all 4 stat arrays
    hipMemsetAsync(out, 0, BG * DH_ * 4, stream);            // readout atomics target

    // Weight transposes (bf16; wq pre-scaled by QSCALE) + QKV bias concat
    wtrans_kernel<<<(DIN_ * DH_ + 255) / 256, 256, 0, stream>>>(w_conv1, wc1t, DIN_, DH_, 1.f);
    wtrans_kernel<<<(DH_ * DH_ + 255) / 256, 256, 0, stream>>>(w_conv2, wc2t, DH_, DH_, 1.f);
    wtrans_kernel<<<(DH_ * DH_ + 255) / 256, 256, 0, stream>>>(wq, wqkvt, DH_, DH_, QSCALE);
    wtrans_kernel<<<(DH_ * DH_ + 255) / 256, 256, 0, stream>>>(wk, wqkvt + DH_ * DH_, DH_, DH_, 1.f);
    wtrans_kernel<<<(DH_ * DH_ + 255) / 256, 256, 0, stream>>>(wv, wqkvt + 2 * DH_ * DH_, DH_, DH_, 1.f);
    wtrans_kernel<<<(DH_ * DH_ + 255) / 256, 256, 0, stream>>>(wo, wot, DH_, DH_, 1.f);
    wtrans_kernel<<<(DH_ * DFF_ + 255) / 256, 256, 0, stream>>>(w_ff1, wf1t, DH_, DFF_, 1.f);
    wtrans_kernel<<<(DFF_ * DH_ + 255) / 256, 256, 0, stream>>>(w_ff2, wf2t, DFF_, DH_, 1.f);
    bcat_kernel<<<3, 256, 0, stream>>>(bq, bk, bv, bqkv);

    // Fused init_avg_h + BN1 stats (one pass over x)
    initstats_kernel<<<BG, 128, 0, stream>>>(x, out + BG * DH_, csum, csumsq);
    bnfin_kernel<DIN_><<<1, DIN_, 0, stream>>>(csum, csumsq, bn1_g, bn1_b, scl, shf);
    bnapply_kernel<DIN_><<<NN * DIN_ / 256, 256, 0, stream>>>(x, scl, shf, B0);

    // CSR build
    deg_kernel<<<EE / 256, 256, 0, stream>>>(ei + EE, deg);
    scan_kernel<<<1, 1024, 0, stream>>>(deg, off, dis);
    scatter_kernel<<<EE / 256, 256, 0, stream>>>(ei, ei + EE, off, cnt, srow);

    // agg1 (A·X)·W == A·(X·W): Xa = Anorm @ Xb (bf16, 128 cols)
    aggb_kernel<DIN_, 0><<<NN / 4, 256, 0, stream>>>(B0, off, srow, dis,
                                                     nullptr, nullptr, Xa);
    // conv1 (MODE 1): h1b = relu(Xa @ w_conv1 + b) -> B0 ; fused BN2 stats
    gemm64n256_kernel<1><<<NN / 64, 512, 0, stream>>>(
        Xa, wc1t, B0, DIN_, b_conv1, nullptr, nullptr, 1, 0,
        csum2, csumsq2, nullptr, nullptr, nullptr);
    bnfin_kernel<DH_><<<1, DH_, 0, stream>>>(csum2, csumsq2, bn2_g, bn2_b, scl, shf);

    // agg2 with fused BN apply: X2a = Anorm @ (h1b*s + b)
    aggb_kernel<DH_, 1><<<NN / 4, 256, 0, stream>>>(B0, off, srow, dis,
                                                    scl, shf, X2a);
    // conv2 (MODE 0): tb = h1b + relu(X2a @ w_conv2 + b) + inter[graph] -> TB
    gemm64n256_kernel<0><<<NN / 64, 512, 0, stream>>>(
        X2a, wc2t, tb, DH_, b_conv2, B0, inter_f, 1, 1,
        nullptr, nullptr, nullptr, nullptr, nullptr);

    // Fused QKV (N=768, MT=128): QKVb = tb @ [wq*s|wk|wv] + bqkv
    gemm_bf16_kernel<<<dim3(768 / 128, NN / 128), 512, 0, stream>>>(
        tb, wqkvt, QKVb, NN, DH_, 768, bqkv, nullptr, nullptr, 0, 0);

    // MFMA flash attention -> Ob (B0; h1b dead)
    attn_mfma_kernel<<<BG * NH, 256, 0, stream>>>(QKVb, B0);

    // O-proj (MODE 2): t2b = LN1(Ob @ wo + bo + tb) -> B0 in-place
    gemm64n256_kernel<2><<<NN / 64, 512, 0, stream>>>(
        B0, wot, B0, DH_, bo, tb, nullptr, 0, 0,
        nullptr, nullptr, ln1_g, ln1_b, nullptr);

    // ff1 (N=1024, MT=128): Fb = relu(t2b @ w_ff1 + b1)
    gemm_bf16_kernel<<<dim3(DFF_ / 128, NN / 128), 512, 0, stream>>>(
        B0, wf1t, Fb, NN, DH_, DFF_, b_ff1, nullptr, nullptr, 1, 0);

    // ff2 (MODE 3): LN2(Fb @ w_ff2 + b2 + t2b) -> per-graph column sums -> out
    gemm64n256_kernel<3><<<NN / 64, 512, 0, stream>>>(
        Fb, wf2t, nullptr, DFF_, b_ff2, B0, nullptr, 0, 0,
        nullptr, nullptr, ln2_g, ln2_b, out);
}

// Round 10
// 512.281 us; speedup vs baseline: 1.1074x; 1.0094x over previous
//
#include <hip/hip_runtime.h>
#include <math.h>

// Problem constants (fixed by the reference)
#define NN   32768
#define BG   128
#define SG   256
#define EE   524288
#define DIN_ 128
#define DH_  256
#define NH   8
#define HD_  32
#define DFF_ 1024
#define EPS_ 1e-5f

typedef __attribute__((ext_vector_type(8))) short bf16x8;
typedef __attribute__((ext_vector_type(4))) float f32x4;
typedef __attribute__((ext_vector_type(2))) unsigned int u32x2;
typedef __attribute__((ext_vector_type(4))) unsigned int u32x4;

__device__ __forceinline__ unsigned short f2bf(float f) {
    unsigned int u = __builtin_bit_cast(unsigned int, f);
    unsigned int r = u + 0x7FFFu + ((u >> 16) & 1u);
    return (unsigned short)(r >> 16);
}
__device__ __forceinline__ float bf2f(unsigned short u) {
    return __builtin_bit_cast(float, (unsigned int)u << 16);
}
// Async global->LDS DMA, 16 B per lane (dest = wave-uniform base + lane*16).
__device__ __forceinline__ void glds16(const unsigned short* g, unsigned short* l) {
    __builtin_amdgcn_global_load_lds(
        (const __attribute__((address_space(1))) void*)g,
        (__attribute__((address_space(3))) void*)l, 16, 0, 0);
}
// s_waitcnt with vmcnt(N) only (exp/lgkm masked off).
#define WAIT_VM0() __builtin_amdgcn_s_waitcnt(0x0F70)
#define WAIT_VM2() __builtin_amdgcn_s_waitcnt(0x0F72)
#define WAIT_VM4() __builtin_amdgcn_s_waitcnt(0x0F74)
#define WAIT_VM6() __builtin_amdgcn_s_waitcnt(0x0F76)

// Softmax pre-scale: 1/sqrt(32) * log2(e), folded into wq/bq at transpose time.
#define QSCALE (0.17677669529663689f * 1.4426950408889634f)

// ---------------------------------------------------------------------------
// Fused init_avg_h + BN1 column stats: one pass over x.
__global__ __launch_bounds__(128) void initstats_kernel(const float* __restrict__ X,
                                                        float* __restrict__ out2,
                                                        float* __restrict__ csum,
                                                        float* __restrict__ csumsq) {
    int b = blockIdx.x, j = threadIdx.x;
    float s = 0.f, sq = 0.f;
    for (int r = 0; r < SG; ++r) {
        float v = X[(size_t)(b * SG + r) * DIN_ + j];
        s += v; sq += v * v;
    }
    out2[b * DIN_ + j] = s * (1.f / (float)SG);
    atomicAdd(&csum[j], s);
    atomicAdd(&csumsq[j], sq);
}

template <int C>
__global__ __launch_bounds__(C) void bnfin_kernel(const float* __restrict__ csum,
                                                  const float* __restrict__ csumsq,
                                                  const float* __restrict__ g,
                                                  const float* __restrict__ b,
                                                  float* __restrict__ scale,
                                                  float* __restrict__ shift) {
    int j = threadIdx.x;
    float mu  = csum[j] * (1.f / (float)NN);
    float var = csumsq[j] * (1.f / (float)NN) - mu * mu;
    float s = g[j] * rsqrtf(var + EPS_);
    scale[j] = s;
    shift[j] = b[j] - mu * s;
}

// BN apply, fp32 in -> bf16 out (BN1).
template <int C>
__global__ __launch_bounds__(256) void bnapply_kernel(const float* __restrict__ X,
                                                      const float* __restrict__ sc,
                                                      const float* __restrict__ sh,
                                                      unsigned short* __restrict__ Y) {
    int i = blockIdx.x * 256 + threadIdx.x;
    int j = i & (C - 1);
    Y[i] = f2bf(X[i] * sc[j] + sh[j]);
}

// Weight cast+transpose: W[K,N] fp32 -> Wt[N,K] bf16, optional scalar scale.
__global__ __launch_bounds__(256) void wtrans_kernel(const float* __restrict__ W,
                                                     unsigned short* __restrict__ Wt,
                                                     int K, int N, float scale) {
    int idx = blockIdx.x * 256 + threadIdx.x;
    if (idx < K * N) {
        int n = idx / K, k = idx - n * K;
        Wt[idx] = f2bf(W[(size_t)k * N + n] * scale);
    }
}

// Concat Q/K/V biases into one fp32[768]; Q part pre-scaled by QSCALE.
__global__ __launch_bounds__(256) void bcat_kernel(const float* __restrict__ bq,
                                                   const float* __restrict__ bk,
                                                   const float* __restrict__ bv,
                                                   float* __restrict__ o) {
    int j = threadIdx.x;
    if (blockIdx.x == 0) o[j] = bq[j] * QSCALE;
    else if (blockIdx.x == 1) o[DH_ + j] = bk[j];
    else o[2 * DH_ + j] = bv[j];
}

// ---------------------------------------------------------------------------
// CSR build
__global__ __launch_bounds__(256) void deg_kernel(const int* __restrict__ col,
                                                  int* __restrict__ deg) {
    int e = blockIdx.x * 256 + threadIdx.x;
    if (e < EE) atomicAdd(&deg[col[e]], 1);
}

__global__ __launch_bounds__(1024) void scan_kernel(const int* __restrict__ deg,
                                                    int* __restrict__ off,
                                                    float* __restrict__ dis) {
    __shared__ int sums[1024];
    int t = threadIdx.x;
    int base = t * 32;
    int loc[32];
    int run = 0;
#pragma unroll
    for (int i = 0; i < 32; ++i) { loc[i] = run; run += deg[base + i]; }
    sums[t] = run;
    __syncthreads();
    for (int d = 1; d < 1024; d <<= 1) {
        int tmp = (t >= d) ? sums[t - d] : 0;
        __syncthreads();
        sums[t] += tmp;
        __syncthreads();
    }
    int excl = sums[t] - run;
#pragma unroll
    for (int i = 0; i < 32; ++i) {
        off[base + i] = excl + loc[i];
        dis[base + i] = rsqrtf((float)(deg[base + i] + 1));
    }
    if (t == 1023) off[NN] = sums[1023];
}

__global__ __launch_bounds__(256) void scatter_kernel(const int* __restrict__ row,
                                                      const int* __restrict__ col,
                                                      const int* __restrict__ off,
                                                      int* __restrict__ cnt,
                                                      int* __restrict__ srow) {
    int e = blockIdx.x * 256 + threadIdx.x;
    if (e < EE) {
        int c = col[e];
        int p = off[c] + atomicAdd(&cnt[c], 1);
        srow[p] = row[e];
    }
}

// ---------------------------------------------------------------------------
// bf16 GCN aggregation, 4x-unrolled edge loop for MLP.
template <int C, int FUSE_BN>
__global__ __launch_bounds__(256) void aggb_kernel(const unsigned short* __restrict__ X,
                                                   const int* __restrict__ off,
                                                   const int* __restrict__ srow,
                                                   const float* __restrict__ dis,
                                                   const float* __restrict__ scl,
                                                   const float* __restrict__ shf,
                                                   unsigned short* __restrict__ Y) {
    constexpr int EPL = C / 64;
    int lane = threadIdx.x & 63;
    int c = blockIdx.x * 4 + (threadIdx.x >> 6);
    float dc = dis[c];
    float acc[EPL];
    float wsum = dc;
    {
        unsigned short t[EPL];
        const unsigned short* xc = X + (size_t)c * C + lane * EPL;
        if constexpr (EPL == 4) *(uint2*)t = *(const uint2*)xc;
        else *(unsigned int*)t = *(const unsigned int*)xc;
#pragma unroll
        for (int e2 = 0; e2 < EPL; ++e2) acc[e2] = dc * bf2f(t[e2]);
    }
    int s = off[c], en = off[c + 1];
    int i = s;
    for (; i + 4 <= en; i += 4) {
        int r0 = srow[i], r1 = srow[i + 1], r2 = srow[i + 2], r3 = srow[i + 3];
        float d0 = dis[r0], d1 = dis[r1], d2 = dis[r2], d3 = dis[r3];
        unsigned short t0[EPL], t1[EPL], t2[EPL], t3[EPL];
        const unsigned short* p0 = X + (size_t)r0 * C + lane * EPL;
        const unsigned short* p1 = X + (size_t)r1 * C + lane * EPL;
        const unsigned short* p2 = X + (size_t)r2 * C + lane * EPL;
        const unsigned short* p3 = X + (size_t)r3 * C + lane * EPL;
        if constexpr (EPL == 4) {
            *(uint2*)t0 = *(const uint2*)p0;
            *(uint2*)t1 = *(const uint2*)p1;
            *(uint2*)t2 = *(const uint2*)p2;
            *(uint2*)t3 = *(const uint2*)p3;
        } else {
            *(unsigned int*)t0 = *(const unsigned int*)p0;
            *(unsigned int*)t1 = *(const unsigned int*)p1;
            *(unsigned int*)t2 = *(const unsigned int*)p2;
            *(unsigned int*)t3 = *(const unsigned int*)p3;
        }
        wsum += d0 + d1 + d2 + d3;
#pragma unroll
        for (int e2 = 0; e2 < EPL; ++e2) {
            acc[e2] += d0 * bf2f(t0[e2]) + d1 * bf2f(t1[e2]) +
                       d2 * bf2f(t2[e2]) + d3 * bf2f(t3[e2]);
        }
    }
    for (; i < en; ++i) {
        int r = srow[i];
        float dr = dis[r];
        unsigned short t[EPL];
        const unsigned short* xr = X + (size_t)r * C + lane * EPL;
        if constexpr (EPL == 4) *(uint2*)t = *(const uint2*)xr;
        else *(unsigned int*)t = *(const unsigned int*)xr;
        wsum += dr;
#pragma unroll
        for (int e2 = 0; e2 < EPL; ++e2) acc[e2] += dr * bf2f(t[e2]);
    }
    unsigned short t[EPL];
#pragma unroll
    for (int e2 = 0; e2 < EPL; ++e2) {
        float v;
        if constexpr (FUSE_BN) {
            int j = lane * EPL + e2;
            v = dc * (scl[j] * acc[e2] + shf[j] * wsum);
        } else {
            v = dc * acc[e2];
        }
        t[e2] = f2bf(v);
    }
    unsigned short* yc = Y + (size_t)c * C + lane * EPL;
    if constexpr (EPL == 4) *(uint2*)yc = *(const uint2*)t;
    else *(unsigned int*)yc = *(const unsigned int*)t;
}

// ---------------------------------------------------------------------------
// MT=128 bf16 MFMA GEMM (QKV / ff1), proven round-5 structure: triple-buffered
// glds staging (depth-2 in flight, counted vmcnt), raw s_barrier, XCD swizzle,
// XOR-swizzled staging, coalesced LDS C-tile epilogue. 48 KB -> 3 blocks/CU.
__global__ __launch_bounds__(512, 8) void gemm_bf16_kernel(
    const unsigned short* __restrict__ A,
    const unsigned short* __restrict__ Bt,
    unsigned short* __restrict__ Cb,
    int M, int K, int N,
    const float* __restrict__ bias,
    const unsigned short* __restrict__ resb,
    const float* __restrict__ inter,
    int do_relu, int relu_first) {
    constexpr int LDP = 32;
    constexpr int CP = 136;
    constexpr int MI = 2;
    constexpr int STG = 8192;                // per-stage shorts: A 8KB | B 8KB
    constexpr int BOFS = 4096;
    __shared__ unsigned short Smem[3 * STG];
    unsigned short* Cs = Smem;               // union: staging dead after K-loop
    int gx = gridDim.x, gyP = gridDim.y >> 3;
    int d = blockIdx.y * gx + blockIdx.x;
    int xcd = d & 7, j2 = d >> 3;
    int bm = (xcd * gyP + j2 / gx) * 128;
    int bn = (j2 % gx) * 128;
    int tid = threadIdx.x;
    int wave = tid >> 6, lane = tid & 63;
    int wm = (wave >> 1) * 32;               // 4 m-waves x 2 n-waves
    int wn = (wave & 1) * 64;
    int lrc = lane & 15;
    int koct = lane >> 4;
    int rsw = (lrc >> 1) & 3;
    int rofs = (koct ^ rsw) * 8;
    int cg = (lane & 3) ^ ((lane >> 3) & 3);
    int skk = cg * 8;

    int sr = wave * 16 + (lane >> 2);
    const unsigned short* gA0 = A + (size_t)(bm + sr) * K + skk;
    const unsigned short* gB0 = Bt + (size_t)(bn + sr) * K + skk;
    int lofs = wave * 512 + lane * 8;

    f32x4 acc[MI][4];
#pragma unroll
    for (int i = 0; i < MI; ++i)
#pragma unroll
        for (int j = 0; j < 4; ++j) acc[i][j] = (f32x4){0.f, 0.f, 0.f, 0.f};

    glds16(gA0, Smem + lofs);
    glds16(gB0, Smem + BOFS + lofs);
    glds16(gA0 + 32, Smem + STG + lofs);
    glds16(gB0 + 32, Smem + STG + BOFS + lofs);

    int rb = 0;
    for (int k0 = 0; k0 < K; k0 += 32) {
        if (k0 + 64 < K) {
            int wb = rb + 2; if (wb >= 3) wb -= 3;
            unsigned short* ld = Smem + wb * STG;
            glds16(gA0 + k0 + 64, ld + lofs);
            glds16(gB0 + k0 + 64, ld + BOFS + lofs);
            WAIT_VM4();                       // drain stage t; t+1,t+2 in flight
        } else if (k0 + 32 < K) {
            WAIT_VM2();
        } else {
            WAIT_VM0();
        }
        __builtin_amdgcn_s_barrier();
        const unsigned short* Ab = Smem + rb * STG;
        const unsigned short* Bb = Ab + BOFS;
        bf16x8 af[MI], bfr[4];
#pragma unroll
        for (int i = 0; i < MI; ++i)
            af[i] = *(const bf16x8*)(Ab + (wm + i * 16 + lrc) * LDP + rofs);
#pragma unroll
        for (int j = 0; j < 4; ++j)
            bfr[j] = *(const bf16x8*)(Bb + (wn + j * 16 + lrc) * LDP + rofs);
#pragma unroll
        for (int i = 0; i < MI; ++i)
#pragma unroll
            for (int j = 0; j < 4; ++j)
                acc[i][j] = __builtin_amdgcn_mfma_f32_16x16x32_bf16(af[i], bfr[j],
                                                                    acc[i][j], 0, 0, 0);
        __builtin_amdgcn_s_barrier();
        rb = (rb + 1 == 3) ? 0 : rb + 1;
    }
#pragma unroll
    for (int i = 0; i < MI; ++i) {
#pragma unroll
        for (int r = 0; r < 4; ++r) {
            int lrow = wm + i * 16 + koct * 4 + r;
            int grow = bm + lrow;
#pragma unroll
            for (int j = 0; j < 4; ++j) {
                int lcol = wn + j * 16 + lrc;
                int gcol = bn + lcol;
                float v = acc[i][j][r];
                if (bias) v += bias[gcol];
                if (relu_first) v = fmaxf(v, 0.f);
                if (resb) v += bf2f(resb[(size_t)grow * N + gcol]);
                if (inter) v += inter[(grow >> 8) * N + gcol];
                if (do_relu && !relu_first) v = fmaxf(v, 0.f);
                Cs[lrow * CP + lcol] = f2bf(v);
            }
        }
    }
    __syncthreads();
#pragma unroll
    for (int it = 0; it < 4; ++it) {
        int row = it * 32 + (tid >> 4);
        int cc = (tid & 15) * 8;
        *(uint4*)(&Cb[(size_t)(bm + row) * N + bn + cc]) =
            *(const uint4*)(&Cs[row * CP + cc]);
    }
}

// ---------------------------------------------------------------------------
// 64x256 full-row-tile bf16 GEMM for N=256 layers (round-27).
// Round-9 post-mortem: occupancy is GRID-capped (NN/64 = 512 blocks = 2
// blocks/CU) -- LDS shrinking couldn't help. So spend the free LDS instead:
// K-STEP = 64 with double buffer (2 x 40 KB = 80 KB = exactly the 2-block
// budget). Per step each wave runs 16 MFMA + 12 ds_read between one barrier
// pair (vs 8+6), and the barrier/chain count halves (16 steps for K=1024).
// Stage layout (shorts): A chunk0 [0,2048) chunk1 [2048,4096);
//                        B chunk0 [4096,12288) chunk1 [12288,20480).
// Staging: every wave stages B rows [wave*32,+32) for both 32-k chunks
// (4 glds); waves 0-3 additionally stage A rows [bm+wave*16,+16) for both
// chunks (2 glds). vmcnt (in-order): waves 0-3 VM6 steady / VM0 last;
// waves 4-7 VM4 / VM0.
// Fusion modes:
//   MODE 0: plain copy-out                       (conv2)
//   MODE 1: copy-out + BN column-stats atomics   (conv1)
//   MODE 2: row LayerNorm -> write Cb            (oproj, in-place safe)
//   MODE 3: row LayerNorm -> column-sum atomics into outp (ff2+readout)
template <int MODE>
__global__ __launch_bounds__(512, 2) void gemm64n256_kernel(
    const unsigned short* __restrict__ A,
    const unsigned short* __restrict__ Bt,
    unsigned short* __restrict__ Cb,
    int K,
    const float* __restrict__ bias,
    const unsigned short* __restrict__ resb,
    const float* __restrict__ inter,
    int do_relu, int relu_first,
    float* __restrict__ stat0, float* __restrict__ stat1,
    const float* __restrict__ lng, const float* __restrict__ lnbt,
    float* __restrict__ outp) {
    constexpr int LDP = 32;
    constexpr int CP = 264;                  // 256 + 8 pad
    constexpr int STG = 20480;               // shorts per 64-k stage (40 KB)
    constexpr int AOFS1 = 2048;              // A chunk1
    constexpr int BOFS = 4096;               // B chunk0
    constexpr int BOFS1 = 12288;             // B chunk1
    __shared__ unsigned short Smem[2 * STG]; // 80 KB -> 2 blocks/CU (= grid cap)
    unsigned short* Cs = Smem;               // union (64*264 = 16896 shorts)
    int bm = blockIdx.x * 64;
    int tid = threadIdx.x;
    int wave = tid >> 6, lane = tid & 63;
    int wm = (wave >> 2) * 32;               // 2 m-waves x 4 n-waves
    int wn = (wave & 3) * 64;
    int lrc = lane & 15;
    int koct = lane >> 4;
    int rsw = (lrc >> 1) & 3;
    int rofs = (koct ^ rsw) * 8;
    int cg = (lane & 3) ^ ((lane >> 3) & 3);
    int skk = cg * 8;

    const unsigned short* gB0 = Bt + (size_t)(wave * 32 + (lane >> 2)) * K + skk;
    size_t g16 = (size_t)16 * K;
    int lofsB = BOFS + wave * 1024 + lane * 8;
    const unsigned short* gA0 = nullptr;
    int lofsA = 0;
    if (wave < 4) {
        gA0 = A + (size_t)(bm + wave * 16 + (lane >> 2)) * K + skk;
        lofsA = wave * 512 + lane * 8;
    }

    f32x4 acc[2][4];
#pragma unroll
    for (int i = 0; i < 2; ++i)
#pragma unroll
        for (int j = 0; j < 4; ++j) acc[i][j] = (f32x4){0.f, 0.f, 0.f, 0.f};

    // prologue: stage 0 (k 0..63) into buf 0
    glds16(gB0, Smem + lofsB);
    glds16(gB0 + g16, Smem + lofsB + 512);
    glds16(gB0 + 32, Smem + (BOFS1 - BOFS) + lofsB);
    glds16(gB0 + 32 + g16, Smem + (BOFS1 - BOFS) + lofsB + 512);
    if (wave < 4) {
        glds16(gA0, Smem + lofsA);
        glds16(gA0 + 32, Smem + AOFS1 + lofsA);
    }

    int cur = 0;
    for (int k0 = 0; k0 < K; k0 += 64) {
        int nk = k0 + 64;
        if (nk < K) {
            unsigned short* nb = Smem + (cur ^ 1) * STG;
            glds16(gB0 + nk, nb + lofsB);
            glds16(gB0 + nk + g16, nb + lofsB + 512);
            glds16(gB0 + nk + 32, nb + (BOFS1 - BOFS) + lofsB);
            glds16(gB0 + nk + 32 + g16, nb + (BOFS1 - BOFS) + lofsB + 512);
            if (wave < 4) {
                glds16(gA0 + nk, nb + lofsA);
                glds16(gA0 + nk + 32, nb + AOFS1 + lofsA);
                WAIT_VM6();                  // stage t done; t+1 (6) in flight
            } else {
                WAIT_VM4();
            }
        } else {
            WAIT_VM0();
        }
        __builtin_amdgcn_s_barrier();
        const unsigned short* Sb = Smem + cur * STG;
#pragma unroll
        for (int kk = 0; kk < 2; ++kk) {
            const unsigned short* Ab = Sb + kk * AOFS1;
            const unsigned short* Bb = Sb + BOFS + kk * (BOFS1 - BOFS);
            bf16x8 af[2], bfr[4];
#pragma unroll
            for (int i = 0; i < 2; ++i)
                af[i] = *(const bf16x8*)(Ab + (wm + i * 16 + lrc) * LDP + rofs);
#pragma unroll
            for (int j = 0; j < 4; ++j)
                bfr[j] = *(const bf16x8*)(Bb + (wn + j * 16 + lrc) * LDP + rofs);
#pragma unroll
            for (int i = 0; i < 2; ++i)
#pragma unroll
                for (int j = 0; j < 4; ++j)
                    acc[i][j] = __builtin_amdgcn_mfma_f32_16x16x32_bf16(af[i], bfr[j],
                                                                        acc[i][j], 0, 0, 0);
        }
        __builtin_amdgcn_s_barrier();
        cur ^= 1;
    }
    // Finalize into Cs (bias/relu/res/inter applied in regs).
#pragma unroll
    for (int i = 0; i < 2; ++i) {
#pragma unroll
        for (int r = 0; r < 4; ++r) {
            int lrow = wm + i * 16 + koct * 4 + r;
            int grow = bm + lrow;
#pragma unroll
            for (int j = 0; j < 4; ++j) {
                int lcol = wn + j * 16 + lrc;
                float v = acc[i][j][r];
                if (bias) v += bias[lcol];
                if (relu_first) v = fmaxf(v, 0.f);
                if (resb) v += bf2f(resb[(size_t)grow * 256 + lcol]);
                if (inter) v += inter[(grow >> 8) * 256 + lcol];
                if (do_relu && !relu_first) v = fmaxf(v, 0.f);
                Cs[lrow * CP + lcol] = f2bf(v);
            }
        }
    }
    __syncthreads();

    if constexpr (MODE == 0 || MODE == 1) {
        // Coalesced copy-out: 4 iters x 16 rows; one uint4 per thread.
#pragma unroll
        for (int it = 0; it < 4; ++it) {
            int row = it * 16 + (tid >> 5);
            int cc = (tid & 31) * 8;
            *(uint4*)(&Cb[(size_t)(bm + row) * 256 + cc]) =
                *(const uint4*)(&Cs[row * CP + cc]);
        }
        if constexpr (MODE == 1) {
            if (tid < 256) {
                float s = 0.f, sq = 0.f;
                for (int r = 0; r < 64; ++r) {
                    float v = bf2f(Cs[r * CP + tid]);
                    s += v; sq += v * v;
                }
                atomicAdd(&stat0[tid], s);
                atomicAdd(&stat1[tid], sq);
            }
        }
    } else {
        // LN modes: wave handles rows [wave*8, wave*8+8), lane owns cols lane*4..+3.
        float4 g4 = *(const float4*)(lng + lane * 4);
        float4 b4 = *(const float4*)(lnbt + lane * 4);
#pragma unroll
        for (int q = 0; q < 8; ++q) {
            int row = wave * 8 + q;
            unsigned short tv[4];
            *(uint2*)tv = *(const uint2*)(Cs + row * CP + lane * 4);
            float v0 = bf2f(tv[0]), v1 = bf2f(tv[1]), v2 = bf2f(tv[2]), v3 = bf2f(tv[3]);
            float sum = v0 + v1 + v2 + v3;
#pragma unroll
            for (int off = 32; off; off >>= 1) sum += __shfl_xor(sum, off);
            float mu = sum * (1.f / (float)DH_);
            float d0 = v0 - mu, d1 = v1 - mu, d2 = v2 - mu, d3 = v3 - mu;
            float vs = d0 * d0 + d1 * d1 + d2 * d2 + d3 * d3;
#pragma unroll
            for (int off = 32; off; off >>= 1) vs += __shfl_xor(vs, off);
            float rs = rsqrtf(vs * (1.f / (float)DH_) + EPS_);
            unsigned short ov[4];
            ov[0] = f2bf(d0 * rs * g4.x + b4.x);
            ov[1] = f2bf(d1 * rs * g4.y + b4.y);
            ov[2] = f2bf(d2 * rs * g4.z + b4.z);
            ov[3] = f2bf(d3 * rs * g4.w + b4.w);
            if constexpr (MODE == 2) {
                *(uint2*)(&Cb[(size_t)(bm + row) * 256 + lane * 4]) = *(uint2*)ov;
            } else {
                *(uint2*)(Cs + row * CP + lane * 4) = *(uint2*)ov;
            }
        }
        if constexpr (MODE == 3) {
            __syncthreads();
            if (tid < 256) {
                float s = 0.f;
                for (int r = 0; r < 64; ++r) s += bf2f(Cs[r * CP + tid]);
                atomicAdd(&outp[(bm >> 8) * 256 + tid], s);
            }
        }
    }
}

// ---------------------------------------------------------------------------
// MFMA flash attention, transposed-score, no online softmax.
// P kept fully in-register: QK^T C-fragment -> v_cvt_pk_bf16_f32 ->
// permlane32_swap + permlane16_swap -> PV A-fragment. No Ps LDS buffer.
__global__ __launch_bounds__(256, 4) void attn_mfma_kernel(
    const unsigned short* __restrict__ QKV,
    unsigned short* __restrict__ Ob) {
    int b = blockIdx.x >> 3, h = blockIdx.x & 7;
    __shared__ unsigned short Ks[256 * 32];    // XOR-swizzled chunks
    __shared__ unsigned short Vt[32 * 264];    // [d][key 256 + pad]
    __shared__ float Lc[4 * 64];               // per-wave l broadcast
    const unsigned short* kg = QKV + (size_t)b * 256 * 768 + 256 + h * 32;
    const unsigned short* vg = QKV + (size_t)b * 256 * 768 + 512 + h * 32;
    int tid = threadIdx.x;
#pragma unroll
    for (int it = 0; it < 4; ++it) {
        int c = it * 256 + tid;
        int row = c >> 2, ch = c & 3;
        int slot = ch ^ ((row >> 1) & 3);
        *(uint4*)(Ks + row * 32 + slot * 8) =
            *(const uint4*)(kg + (size_t)row * 768 + ch * 8);
    }
#pragma unroll
    for (int it = 0; it < 4; ++it) {
        int c = it * 256 + tid;
        int key = c >> 2, d0 = (c & 3) * 8;
        unsigned short tmp[8];
        *(uint4*)tmp = *(const uint4*)(vg + (size_t)key * 768 + d0);
#pragma unroll
        for (int j = 0; j < 8; ++j) Vt[(d0 + j) * 264 + key] = tmp[j];
    }
    __syncthreads();

    int wave = tid >> 6, lane = tid & 63;
    int lr = lane & 15, koct = lane >> 4;
    int s4 = (lr >> 1) & 3;
    int qrow0 = b * 256 + wave * 64;
    bf16x8 qf[4];
#pragma unroll
    for (int j = 0; j < 4; ++j)
        qf[j] = *(const bf16x8*)(QKV + (size_t)(qrow0 + j * 16 + lr) * 768 + h * 32 + koct * 8);

    f32x4 Oa[4][2];
    float lp[4];
#pragma unroll
    for (int i = 0; i < 4; ++i) {
        Oa[i][0] = (f32x4){0.f, 0.f, 0.f, 0.f};
        Oa[i][1] = (f32x4){0.f, 0.f, 0.f, 0.f};
        lp[i] = 0.f;
    }
    float* Lw = Lc + wave * 64;

    for (int kc = 0; kc < 256; kc += 32) {
        bf16x8 kf0 = *(const bf16x8*)(Ks + (kc + lr) * 32 + (koct ^ s4) * 8);
        bf16x8 kf1 = *(const bf16x8*)(Ks + (kc + 16 + lr) * 32 + (koct ^ s4) * 8);
        bf16x8 pfr[4];
#pragma unroll
        for (int j = 0; j < 4; ++j) {
            f32x4 St0 = __builtin_amdgcn_mfma_f32_16x16x32_bf16(kf0, qf[j],
                            (f32x4){0.f, 0.f, 0.f, 0.f}, 0, 0, 0);
            f32x4 St1 = __builtin_amdgcn_mfma_f32_16x16x32_bf16(kf1, qf[j],
                            (f32x4){0.f, 0.f, 0.f, 0.f}, 0, 0, 0);
            float p0[4], p1[4], ps = 0.f;
#pragma unroll
            for (int r = 0; r < 4; ++r) {
                p0[r] = exp2f(St0[r]); p1[r] = exp2f(St1[r]);
                ps += p0[r] + p1[r];
            }
            lp[j] += ps;
            unsigned int w0a, w0b, w1a, w1b;
            asm("v_cvt_pk_bf16_f32 %0, %1, %2" : "=v"(w0a) : "v"(p0[0]), "v"(p0[1]));
            asm("v_cvt_pk_bf16_f32 %0, %1, %2" : "=v"(w0b) : "v"(p0[2]), "v"(p0[3]));
            asm("v_cvt_pk_bf16_f32 %0, %1, %2" : "=v"(w1a) : "v"(p1[0]), "v"(p1[1]));
            asm("v_cvt_pk_bf16_f32 %0, %1, %2" : "=v"(w1b) : "v"(p1[2]), "v"(p1[3]));
            u32x2 sa = __builtin_amdgcn_permlane32_swap(w0a, w1a, false, false);
            u32x2 da = __builtin_amdgcn_permlane16_swap(sa[0], sa[1], false, false);
            u32x2 sb = __builtin_amdgcn_permlane32_swap(w0b, w1b, false, false);
            u32x2 db = __builtin_amdgcn_permlane16_swap(sb[0], sb[1], false, false);
            u32x4 pw = {da[0], db[0], da[1], db[1]};
            pfr[j] = __builtin_bit_cast(bf16x8, pw);
        }
        bf16x8 vf0 = *(const bf16x8*)(Vt + lr * 264 + kc + koct * 8);
        bf16x8 vf1 = *(const bf16x8*)(Vt + (16 + lr) * 264 + kc + koct * 8);
#pragma unroll
        for (int i = 0; i < 4; ++i) {
            Oa[i][0] = __builtin_amdgcn_mfma_f32_16x16x32_bf16(pfr[i], vf0, Oa[i][0], 0, 0, 0);
            Oa[i][1] = __builtin_amdgcn_mfma_f32_16x16x32_bf16(pfr[i], vf1, Oa[i][1], 0, 0, 0);
        }
    }
#pragma unroll
    for (int j = 0; j < 4; ++j) {
        lp[j] += __shfl_xor(lp[j], 16);
        lp[j] += __shfl_xor(lp[j], 32);
    }
    if (koct == 0) {
#pragma unroll
        for (int j = 0; j < 4; ++j) Lw[j * 16 + lr] = lp[j];
    }
    __builtin_amdgcn_s_waitcnt(0);
#pragma unroll
    for (int i = 0; i < 4; ++i) {
        f32x4 l4 = *(const f32x4*)(Lw + i * 16 + koct * 4);
#pragma unroll
        for (int r = 0; r < 4; ++r) {
            float inv = 1.f / l4[r];
            int row = qrow0 + i * 16 + koct * 4 + r;
#pragma unroll
            for (int jn = 0; jn < 2; ++jn) {
                int col = h * 32 + jn * 16 + lr;
                Ob[(size_t)row * 256 + col] = f2bf(Oa[i][jn][r] * inv);
            }
        }
    }
}

// ---------------------------------------------------------------------------
extern "C" void kernel_launch(void* const* d_in, const int* in_sizes, int n_in,
                              void* d_out, int out_size, void* d_ws, size_t ws_size,
                              hipStream_t stream) {
    const float* x       = (const float*)d_in[0];
    const int*   ei      = (const int*)d_in[1];
    const float* inter_f = (const float*)d_in[3];
    const float* bn1_g = (const float*)d_in[4],  *bn1_b = (const float*)d_in[5];
    const float* bn2_g = (const float*)d_in[6],  *bn2_b = (const float*)d_in[7];
    const float* w_conv1 = (const float*)d_in[8],  *b_conv1 = (const float*)d_in[9];
    const float* w_conv2 = (const float*)d_in[10], *b_conv2 = (const float*)d_in[11];
    const float* wq = (const float*)d_in[12], *bq = (const float*)d_in[13];
    const float* wk = (const float*)d_in[14], *bk = (const float*)d_in[15];
    const float* wv = (const float*)d_in[16], *bv = (const float*)d_in[17];
    const float* wo = (const float*)d_in[18], *bo = (const float*)d_in[19];
    const float* ln1_g = (const float*)d_in[20], *ln1_b = (const float*)d_in[21];
    const float* ln2_g = (const float*)d_in[22], *ln2_b = (const float*)d_in[23];
    const float* w_ff1 = (const float*)d_in[24], *b_ff1 = (const float*)d_in[25];
    const float* w_ff2 = (const float*)d_in[26], *b_ff2 = (const float*)d_in[27];
    float* out = (float*)d_out;

    char* base = (char*)d_ws;
    size_t o = 0;
    auto alloc = [&](size_t bytes) -> void* {
        void* p = base + o;
        o = (o + bytes + 255) & ~(size_t)255;
        return p;
    };
    int*   deg    = (int*)alloc(NN * 4);
    int*   off    = (int*)alloc((NN + 1) * 4);
    int*   cnt    = (int*)alloc(NN * 4);
    int*   srow   = (int*)alloc(EE * 4);
    float* dis    = (float*)alloc(NN * 4);
    float* csum   = (float*)alloc(256 * 4);   // BN1 stats (contiguous 4 KB
    float* csumsq = (float*)alloc(256 * 4);   //  block with csum2/csumsq2,
    float* csum2  = (float*)alloc(256 * 4);   //  zeroed in one memset)
    float* csumsq2= (float*)alloc(256 * 4);
    float* scl    = (float*)alloc(256 * 4);
    float* shf    = (float*)alloc(256 * 4);
    float* bqkv   = (float*)alloc(768 * 4);
    const size_t SLOT = (size_t)NN * DH_;  // 8M elements (16 MB bf16)
    unsigned short* Arena = (unsigned short*)alloc((size_t)NN * DFF_ * 2);
    unsigned short* TB = (unsigned short*)alloc(SLOT * 2);  // tb
    unsigned short* B0 = (unsigned short*)alloc(SLOT * 2);  // Xb->h1b->Ob->t2b
    unsigned short* wc1t  = (unsigned short*)alloc((size_t)DIN_ * DH_ * 2);
    unsigned short* wc2t  = (unsigned short*)alloc((size_t)DH_ * DH_ * 2);
    unsigned short* wqkvt = (unsigned short*)alloc((size_t)DH_ * DH_ * 3 * 2);
    unsigned short* wot   = (unsigned short*)alloc((size_t)DH_ * DH_ * 2);
    unsigned short* wf1t  = (unsigned short*)alloc((size_t)DH_ * DFF_ * 2);
    unsigned short* wf2t  = (unsigned short*)alloc((size_t)DFF_ * DH_ * 2);
    unsigned short* Xa   = Arena;                            // NN*DIN (4M)
    unsigned short* X2a  = Arena + (size_t)NN * DIN_;        // [4M..12M)
    unsigned short* QKVb = Arena;                            // [0..24M)
    unsigned short* Fb   = Arena;                            // [0..32M)
    unsigned short* tb   = TB;

    hipMemsetAsync(deg, 0, NN * 4, stream);
    hipMemsetAsync(cnt, 0, NN * 4, stream);
    hipMemsetAsync(csum, 0, 4096, stream);                   // all 4 stat arrays
    hipMemsetAsync(out, 0, BG * DH_ * 4, stream);            // readout atomics target

    // Weight transposes (bf16; wq pre-scaled by QSCALE) + QKV bias concat
    wtrans_kernel<<<(DIN_ * DH_ + 255) / 256, 256, 0, stream>>>(w_conv1, wc1t, DIN_, DH_, 1.f);
    wtrans_kernel<<<(DH_ * DH_ + 255) / 256, 256, 0, stream>>>(w_conv2, wc2t, DH_, DH_, 1.f);
    wtrans_kernel<<<(DH_ * DH_ + 255) / 256, 256, 0, stream>>>(wq, wqkvt, DH_, DH_, QSCALE);
    wtrans_kernel<<<(DH_ * DH_ + 255) / 256, 256, 0, stream>>>(wk, wqkvt + DH_ * DH_, DH_, DH_, 1.f);
    wtrans_kernel<<<(DH_ * DH_ + 255) / 256, 256, 0, stream>>>(wv, wqkvt + 2 * DH_ * DH_, DH_, DH_, 1.f);
    wtrans_kernel<<<(DH_ * DH_ + 255) / 256, 256, 0, stream>>>(wo, wot, DH_, DH_, 1.f);
    wtrans_kernel<<<(DH_ * DFF_ + 255) / 256, 256, 0, stream>>>(w_ff1, wf1t, DH_, DFF_, 1.f);
    wtrans_kernel<<<(DFF_ * DH_ + 255) / 256, 256, 0, stream>>>(w_ff2, wf2t, DFF_, DH_, 1.f);
    bcat_kernel<<<3, 256, 0, stream>>>(bq, bk, bv, bqkv);

    // Fused init_avg_h + BN1 stats (one pass over x)
    initstats_kernel<<<BG, 128, 0, stream>>>(x, out + BG * DH_, csum, csumsq);
    bnfin_kernel<DIN_><<<1, DIN_, 0, stream>>>(csum, csumsq, bn1_g, bn1_b, scl, shf);
    bnapply_kernel<DIN_><<<NN * DIN_ / 256, 256, 0, stream>>>(x, scl, shf, B0);

    // CSR build
    deg_kernel<<<EE / 256, 256, 0, stream>>>(ei + EE, deg);
    scan_kernel<<<1, 1024, 0, stream>>>(deg, off, dis);
    scatter_kernel<<<EE / 256, 256, 0, stream>>>(ei, ei + EE, off, cnt, srow);

    // agg1 (A·X)·W == A·(X·W): Xa = Anorm @ Xb (bf16, 128 cols)
    aggb_kernel<DIN_, 0><<<NN / 4, 256, 0, stream>>>(B0, off, srow, dis,
                                                     nullptr, nullptr, Xa);
    // conv1 (MODE 1): h1b = relu(Xa @ w_conv1 + b) -> B0 ; fused BN2 stats
    gemm64n256_kernel<1><<<NN / 64, 512, 0, stream>>>(
        Xa, wc1t, B0, DIN_, b_conv1, nullptr, nullptr, 1, 0,
        csum2, csumsq2, nullptr, nullptr, nullptr);
    bnfin_kernel<DH_><<<1, DH_, 0, stream>>>(csum2, csumsq2, bn2_g, bn2_b, scl, shf);

    // agg2 with fused BN apply: X2a = Anorm @ (h1b*s + b)
    aggb_kernel<DH_, 1><<<NN / 4, 256, 0, stream>>>(B0, off, srow, dis,
                                                    scl, shf, X2a);
    // conv2 (MODE 0): tb = h1b + relu(X2a @ w_conv2 + b) + inter[graph] -> TB
    gemm64n256_kernel<0><<<NN / 64, 512, 0, stream>>>(
        X2a, wc2t, tb, DH_, b_conv2, B0, inter_f, 1, 1,
        nullptr, nullptr, nullptr, nullptr, nullptr);

    // Fused QKV (N=768, MT=128): QKVb = tb @ [wq*s|wk|wv] + bqkv
    gemm_bf16_kernel<<<dim3(768 / 128, NN / 128), 512, 0, stream>>>(
        tb, wqkvt, QKVb, NN, DH_, 768, bqkv, nullptr, nullptr, 0, 0);

    // MFMA flash attention -> Ob (B0; h1b dead)
    attn_mfma_kernel<<<BG * NH, 256, 0, stream>>>(QKVb, B0);

    // O-proj (MODE 2): t2b = LN1(Ob @ wo + bo + tb) -> B0 in-place
    gemm64n256_kernel<2><<<NN / 64, 512, 0, stream>>>(
        B0, wot, B0, DH_, bo, tb, nullptr, 0, 0,
        nullptr, nullptr, ln1_g, ln1_b, nullptr);

    // ff1 (N=1024, MT=128): Fb = relu(t2b @ w_ff1 + b1)
    gemm_bf16_kernel<<<dim3(DFF_ / 128, NN / 128), 512, 0, stream>>>(
        B0, wf1t, Fb, NN, DH_, DFF_, b_ff1, nullptr, nullptr, 1, 0);

    // ff2 (MODE 3): LN2(Fb @ w_ff2 + b2 + t2b) -> per-graph column sums -> out
    gemm64n256_kernel<3><<<NN / 64, 512, 0, stream>>>(
        Fb, wf2t, nullptr, DFF_, b_ff2, B0, nullptr, 0, 0,
        nullptr, nullptr, ln2_g, ln2_b, out);
}

// Round 11
// 498.402 us; speedup vs baseline: 1.1382x; 1.0278x over previous
//
#include <hip/hip_runtime.h>
#include <math.h>

// Problem constants (fixed by the reference)
#define NN   32768
#define BG   128
#define SG   256
#define EE   524288
#define DIN_ 128
#define DH_  256
#define NH   8
#define HD_  32
#define DFF_ 1024
#define EPS_ 1e-5f

typedef __attribute__((ext_vector_type(8))) short bf16x8;
typedef __attribute__((ext_vector_type(4))) float f32x4;
typedef __attribute__((ext_vector_type(2))) unsigned int u32x2;
typedef __attribute__((ext_vector_type(4))) unsigned int u32x4;

__device__ __forceinline__ unsigned short f2bf(float f) {
    unsigned int u = __builtin_bit_cast(unsigned int, f);
    unsigned int r = u + 0x7FFFu + ((u >> 16) & 1u);
    return (unsigned short)(r >> 16);
}
__device__ __forceinline__ float bf2f(unsigned short u) {
    return __builtin_bit_cast(float, (unsigned int)u << 16);
}
// Async global->LDS DMA, 16 B per lane (dest = wave-uniform base + lane*16).
__device__ __forceinline__ void glds16(const unsigned short* g, unsigned short* l) {
    __builtin_amdgcn_global_load_lds(
        (const __attribute__((address_space(1))) void*)g,
        (__attribute__((address_space(3))) void*)l, 16, 0, 0);
}
// s_waitcnt with vmcnt(N) only (exp/lgkm masked off).
#define WAIT_VM0() __builtin_amdgcn_s_waitcnt(0x0F70)
#define WAIT_VM2() __builtin_amdgcn_s_waitcnt(0x0F72)
#define WAIT_VM4() __builtin_amdgcn_s_waitcnt(0x0F74)
#define WAIT_VM6() __builtin_amdgcn_s_waitcnt(0x0F76)

// Softmax pre-scale: 1/sqrt(32) * log2(e), folded into wq/bq at transpose time.
#define QSCALE (0.17677669529663689f * 1.4426950408889634f)

// ---------------------------------------------------------------------------
// Fused init_avg_h + BN1 column stats: one pass over x.
__global__ __launch_bounds__(128) void initstats_kernel(const float* __restrict__ X,
                                                        float* __restrict__ out2,
                                                        float* __restrict__ csum,
                                                        float* __restrict__ csumsq) {
    int b = blockIdx.x, j = threadIdx.x;
    float s = 0.f, sq = 0.f;
    for (int r = 0; r < SG; ++r) {
        float v = X[(size_t)(b * SG + r) * DIN_ + j];
        s += v; sq += v * v;
    }
    out2[b * DIN_ + j] = s * (1.f / (float)SG);
    atomicAdd(&csum[j], s);
    atomicAdd(&csumsq[j], sq);
}

template <int C>
__global__ __launch_bounds__(C) void bnfin_kernel(const float* __restrict__ csum,
                                                  const float* __restrict__ csumsq,
                                                  const float* __restrict__ g,
                                                  const float* __restrict__ b,
                                                  float* __restrict__ scale,
                                                  float* __restrict__ shift) {
    int j = threadIdx.x;
    float mu  = csum[j] * (1.f / (float)NN);
    float var = csumsq[j] * (1.f / (float)NN) - mu * mu;
    float s = g[j] * rsqrtf(var + EPS_);
    scale[j] = s;
    shift[j] = b[j] - mu * s;
}

// BN apply, fp32 in -> bf16 out (BN1), float4-vectorized (G13).
__global__ __launch_bounds__(256) void bnapply4_kernel(const float* __restrict__ X,
                                                       const float* __restrict__ sc,
                                                       const float* __restrict__ sh,
                                                       unsigned short* __restrict__ Y) {
    int i4 = (blockIdx.x * 256 + threadIdx.x) * 4;
    int j = i4 & (DIN_ - 1);
    float4 v = *(const float4*)(X + i4);
    float4 s = *(const float4*)(sc + j);
    float4 h = *(const float4*)(sh + j);
    unsigned short o[4];
    o[0] = f2bf(v.x * s.x + h.x);
    o[1] = f2bf(v.y * s.y + h.y);
    o[2] = f2bf(v.z * s.z + h.z);
    o[3] = f2bf(v.w * s.w + h.w);
    *(uint2*)(Y + i4) = *(uint2*)o;
}

// All 8 weight cast+transposes in ONE dispatch (was 8 serialized launches).
// Segment = blockIdx.y; W[K,N] fp32 -> Wt[N,K] bf16, per-segment scalar scale.
struct WTArgs {
    const float* w[8];
    unsigned short* o[8];
    int K[8];
    int N[8];
    float s[8];
};
__global__ __launch_bounds__(256) void wtransall_kernel(WTArgs a) {
    int seg = blockIdx.y;
    int idx = blockIdx.x * 256 + threadIdx.x;
    int K = a.K[seg], N = a.N[seg];
    if (idx < K * N) {
        int n = idx / K, k = idx - n * K;
        a.o[seg][idx] = f2bf(a.w[seg][(size_t)k * N + n] * a.s[seg]);
    }
}

// Concat Q/K/V biases into one fp32[768]; Q part pre-scaled by QSCALE.
__global__ __launch_bounds__(256) void bcat_kernel(const float* __restrict__ bq,
                                                   const float* __restrict__ bk,
                                                   const float* __restrict__ bv,
                                                   float* __restrict__ o) {
    int j = threadIdx.x;
    if (blockIdx.x == 0) o[j] = bq[j] * QSCALE;
    else if (blockIdx.x == 1) o[DH_ + j] = bk[j];
    else o[2 * DH_ + j] = bv[j];
}

// ---------------------------------------------------------------------------
// CSR build
__global__ __launch_bounds__(256) void deg_kernel(const int* __restrict__ col,
                                                  int* __restrict__ deg) {
    int e = blockIdx.x * 256 + threadIdx.x;
    if (e < EE) atomicAdd(&deg[col[e]], 1);
}

__global__ __launch_bounds__(1024) void scan_kernel(const int* __restrict__ deg,
                                                    int* __restrict__ off,
                                                    float* __restrict__ dis) {
    __shared__ int sums[1024];
    int t = threadIdx.x;
    int base = t * 32;
    int loc[32];
    int run = 0;
#pragma unroll
    for (int i = 0; i < 32; ++i) { loc[i] = run; run += deg[base + i]; }
    sums[t] = run;
    __syncthreads();
    for (int d = 1; d < 1024; d <<= 1) {
        int tmp = (t >= d) ? sums[t - d] : 0;
        __syncthreads();
        sums[t] += tmp;
        __syncthreads();
    }
    int excl = sums[t] - run;
#pragma unroll
    for (int i = 0; i < 32; ++i) {
        off[base + i] = excl + loc[i];
        dis[base + i] = rsqrtf((float)(deg[base + i] + 1));
    }
    if (t == 1023) off[NN] = sums[1023];
}

__global__ __launch_bounds__(256) void scatter_kernel(const int* __restrict__ row,
                                                      const int* __restrict__ col,
                                                      const int* __restrict__ off,
                                                      int* __restrict__ cnt,
                                                      int* __restrict__ srow) {
    int e = blockIdx.x * 256 + threadIdx.x;
    if (e < EE) {
        int c = col[e];
        int p = off[c] + atomicAdd(&cnt[c], 1);
        srow[p] = row[e];
    }
}

// ---------------------------------------------------------------------------
// bf16 GCN aggregation, 4x-unrolled edge loop for MLP.
template <int C, int FUSE_BN>
__global__ __launch_bounds__(256) void aggb_kernel(const unsigned short* __restrict__ X,
                                                   const int* __restrict__ off,
                                                   const int* __restrict__ srow,
                                                   const float* __restrict__ dis,
                                                   const float* __restrict__ scl,
                                                   const float* __restrict__ shf,
                                                   unsigned short* __restrict__ Y) {
    constexpr int EPL = C / 64;
    int lane = threadIdx.x & 63;
    int c = blockIdx.x * 4 + (threadIdx.x >> 6);
    float dc = dis[c];
    float acc[EPL];
    float wsum = dc;
    {
        unsigned short t[EPL];
        const unsigned short* xc = X + (size_t)c * C + lane * EPL;
        if constexpr (EPL == 4) *(uint2*)t = *(const uint2*)xc;
        else *(unsigned int*)t = *(const unsigned int*)xc;
#pragma unroll
        for (int e2 = 0; e2 < EPL; ++e2) acc[e2] = dc * bf2f(t[e2]);
    }
    int s = off[c], en = off[c + 1];
    int i = s;
    for (; i + 4 <= en; i += 4) {
        int r0 = srow[i], r1 = srow[i + 1], r2 = srow[i + 2], r3 = srow[i + 3];
        float d0 = dis[r0], d1 = dis[r1], d2 = dis[r2], d3 = dis[r3];
        unsigned short t0[EPL], t1[EPL], t2[EPL], t3[EPL];
        const unsigned short* p0 = X + (size_t)r0 * C + lane * EPL;
        const unsigned short* p1 = X + (size_t)r1 * C + lane * EPL;
        const unsigned short* p2 = X + (size_t)r2 * C + lane * EPL;
        const unsigned short* p3 = X + (size_t)r3 * C + lane * EPL;
        if constexpr (EPL == 4) {
            *(uint2*)t0 = *(const uint2*)p0;
            *(uint2*)t1 = *(const uint2*)p1;
            *(uint2*)t2 = *(const uint2*)p2;
            *(uint2*)t3 = *(const uint2*)p3;
        } else {
            *(unsigned int*)t0 = *(const unsigned int*)p0;
            *(unsigned int*)t1 = *(const unsigned int*)p1;
            *(unsigned int*)t2 = *(const unsigned int*)p2;
            *(unsigned int*)t3 = *(const unsigned int*)p3;
        }
        wsum += d0 + d1 + d2 + d3;
#pragma unroll
        for (int e2 = 0; e2 < EPL; ++e2) {
            acc[e2] += d0 * bf2f(t0[e2]) + d1 * bf2f(t1[e2]) +
                       d2 * bf2f(t2[e2]) + d3 * bf2f(t3[e2]);
        }
    }
    for (; i < en; ++i) {
        int r = srow[i];
        float dr = dis[r];
        unsigned short t[EPL];
        const unsigned short* xr = X + (size_t)r * C + lane * EPL;
        if constexpr (EPL == 4) *(uint2*)t = *(const uint2*)xr;
        else *(unsigned int*)t = *(const unsigned int*)xr;
        wsum += dr;
#pragma unroll
        for (int e2 = 0; e2 < EPL; ++e2) acc[e2] += dr * bf2f(t[e2]);
    }
    unsigned short t[EPL];
#pragma unroll
    for (int e2 = 0; e2 < EPL; ++e2) {
        float v;
        if constexpr (FUSE_BN) {
            int j = lane * EPL + e2;
            v = dc * (scl[j] * acc[e2] + shf[j] * wsum);
        } else {
            v = dc * acc[e2];
        }
        t[e2] = f2bf(v);
    }
    unsigned short* yc = Y + (size_t)c * C + lane * EPL;
    if constexpr (EPL == 4) *(uint2*)yc = *(const uint2*)t;
    else *(unsigned int*)yc = *(const unsigned int*)t;
}

// ---------------------------------------------------------------------------
// MT=128 bf16 MFMA GEMM (QKV / ff1), proven round-5 structure: triple-buffered
// glds staging (depth-2 in flight, counted vmcnt), raw s_barrier, XCD swizzle,
// XOR-swizzled staging, coalesced LDS C-tile epilogue. 48 KB -> 3 blocks/CU.
__global__ __launch_bounds__(512, 8) void gemm_bf16_kernel(
    const unsigned short* __restrict__ A,
    const unsigned short* __restrict__ Bt,
    unsigned short* __restrict__ Cb,
    int M, int K, int N,
    const float* __restrict__ bias,
    const unsigned short* __restrict__ resb,
    const float* __restrict__ inter,
    int do_relu, int relu_first) {
    constexpr int LDP = 32;
    constexpr int CP = 136;
    constexpr int MI = 2;
    constexpr int STG = 8192;                // per-stage shorts: A 8KB | B 8KB
    constexpr int BOFS = 4096;
    __shared__ unsigned short Smem[3 * STG];
    unsigned short* Cs = Smem;               // union: staging dead after K-loop
    int gx = gridDim.x, gyP = gridDim.y >> 3;
    int d = blockIdx.y * gx + blockIdx.x;
    int xcd = d & 7, j2 = d >> 3;
    int bm = (xcd * gyP + j2 / gx) * 128;
    int bn = (j2 % gx) * 128;
    int tid = threadIdx.x;
    int wave = tid >> 6, lane = tid & 63;
    int wm = (wave >> 1) * 32;               // 4 m-waves x 2 n-waves
    int wn = (wave & 1) * 64;
    int lrc = lane & 15;
    int koct = lane >> 4;
    int rsw = (lrc >> 1) & 3;
    int rofs = (koct ^ rsw) * 8;
    int cg = (lane & 3) ^ ((lane >> 3) & 3);
    int skk = cg * 8;

    int sr = wave * 16 + (lane >> 2);
    const unsigned short* gA0 = A + (size_t)(bm + sr) * K + skk;
    const unsigned short* gB0 = Bt + (size_t)(bn + sr) * K + skk;
    int lofs = wave * 512 + lane * 8;

    f32x4 acc[MI][4];
#pragma unroll
    for (int i = 0; i < MI; ++i)
#pragma unroll
        for (int j = 0; j < 4; ++j) acc[i][j] = (f32x4){0.f, 0.f, 0.f, 0.f};

    glds16(gA0, Smem + lofs);
    glds16(gB0, Smem + BOFS + lofs);
    glds16(gA0 + 32, Smem + STG + lofs);
    glds16(gB0 + 32, Smem + STG + BOFS + lofs);

    int rb = 0;
    for (int k0 = 0; k0 < K; k0 += 32) {
        if (k0 + 64 < K) {
            int wb = rb + 2; if (wb >= 3) wb -= 3;
            unsigned short* ld = Smem + wb * STG;
            glds16(gA0 + k0 + 64, ld + lofs);
            glds16(gB0 + k0 + 64, ld + BOFS + lofs);
            WAIT_VM4();                       // drain stage t; t+1,t+2 in flight
        } else if (k0 + 32 < K) {
            WAIT_VM2();
        } else {
            WAIT_VM0();
        }
        __builtin_amdgcn_s_barrier();
        const unsigned short* Ab = Smem + rb * STG;
        const unsigned short* Bb = Ab + BOFS;
        bf16x8 af[MI], bfr[4];
#pragma unroll
        for (int i = 0; i < MI; ++i)
            af[i] = *(const bf16x8*)(Ab + (wm + i * 16 + lrc) * LDP + rofs);
#pragma unroll
        for (int j = 0; j < 4; ++j)
            bfr[j] = *(const bf16x8*)(Bb + (wn + j * 16 + lrc) * LDP + rofs);
#pragma unroll
        for (int i = 0; i < MI; ++i)
#pragma unroll
            for (int j = 0; j < 4; ++j)
                acc[i][j] = __builtin_amdgcn_mfma_f32_16x16x32_bf16(af[i], bfr[j],
                                                                    acc[i][j], 0, 0, 0);
        __builtin_amdgcn_s_barrier();
        rb = (rb + 1 == 3) ? 0 : rb + 1;
    }
#pragma unroll
    for (int i = 0; i < MI; ++i) {
#pragma unroll
        for (int r = 0; r < 4; ++r) {
            int lrow = wm + i * 16 + koct * 4 + r;
            int grow = bm + lrow;
#pragma unroll
            for (int j = 0; j < 4; ++j) {
                int lcol = wn + j * 16 + lrc;
                int gcol = bn + lcol;
                float v = acc[i][j][r];
                if (bias) v += bias[gcol];
                if (relu_first) v = fmaxf(v, 0.f);
                if (resb) v += bf2f(resb[(size_t)grow * N + gcol]);
                if (inter) v += inter[(grow >> 8) * N + gcol];
                if (do_relu && !relu_first) v = fmaxf(v, 0.f);
                Cs[lrow * CP + lcol] = f2bf(v);
            }
        }
    }
    __syncthreads();
#pragma unroll
    for (int it = 0; it < 4; ++it) {
        int row = it * 32 + (tid >> 4);
        int cc = (tid & 15) * 8;
        *(uint4*)(&Cb[(size_t)(bm + row) * N + bn + cc]) =
            *(const uint4*)(&Cs[row * CP + cc]);
    }
}

// ---------------------------------------------------------------------------
// 64x256 full-row-tile bf16 GEMM for N=256 layers (round-27 structure, kept).
// K-STEP = 64 double-buffered (2 x 40 KB = 80 KB = the 2-block/CU grid cap).
// Per step: 16 MFMA + 12 ds_read per wave; 8 waves x 32x64 wave-tile.
// Fusion modes:
//   MODE 0: plain copy-out                       (conv2)
//   MODE 1: copy-out + BN column-stats atomics   (conv1)
//   MODE 2: row LayerNorm -> write Cb            (oproj, in-place safe)
//   MODE 3: row LayerNorm -> column-sum atomics into outp (ff2+readout)
template <int MODE>
__global__ __launch_bounds__(512, 2) void gemm64n256_kernel(
    const unsigned short* __restrict__ A,
    const unsigned short* __restrict__ Bt,
    unsigned short* __restrict__ Cb,
    int K,
    const float* __restrict__ bias,
    const unsigned short* __restrict__ resb,
    const float* __restrict__ inter,
    int do_relu, int relu_first,
    float* __restrict__ stat0, float* __restrict__ stat1,
    const float* __restrict__ lng, const float* __restrict__ lnbt,
    float* __restrict__ outp) {
    constexpr int LDP = 32;
    constexpr int CP = 264;                  // 256 + 8 pad
    constexpr int STG = 20480;               // shorts per 64-k stage (40 KB)
    constexpr int AOFS1 = 2048;              // A chunk1
    constexpr int BOFS = 4096;               // B chunk0
    constexpr int BOFS1 = 12288;             // B chunk1
    __shared__ unsigned short Smem[2 * STG]; // 80 KB -> 2 blocks/CU (= grid cap)
    unsigned short* Cs = Smem;               // union (64*264 = 16896 shorts)
    int bm = blockIdx.x * 64;
    int tid = threadIdx.x;
    int wave = tid >> 6, lane = tid & 63;
    int wm = (wave >> 2) * 32;               // 2 m-waves x 4 n-waves
    int wn = (wave & 3) * 64;
    int lrc = lane & 15;
    int koct = lane >> 4;
    int rsw = (lrc >> 1) & 3;
    int rofs = (koct ^ rsw) * 8;
    int cg = (lane & 3) ^ ((lane >> 3) & 3);
    int skk = cg * 8;

    const unsigned short* gB0 = Bt + (size_t)(wave * 32 + (lane >> 2)) * K + skk;
    size_t g16 = (size_t)16 * K;
    int lofsB = BOFS + wave * 1024 + lane * 8;
    const unsigned short* gA0 = nullptr;
    int lofsA = 0;
    if (wave < 4) {
        gA0 = A + (size_t)(bm + wave * 16 + (lane >> 2)) * K + skk;
        lofsA = wave * 512 + lane * 8;
    }

    f32x4 acc[2][4];
#pragma unroll
    for (int i = 0; i < 2; ++i)
#pragma unroll
        for (int j = 0; j < 4; ++j) acc[i][j] = (f32x4){0.f, 0.f, 0.f, 0.f};

    // prologue: stage 0 (k 0..63) into buf 0
    glds16(gB0, Smem + lofsB);
    glds16(gB0 + g16, Smem + lofsB + 512);
    glds16(gB0 + 32, Smem + (BOFS1 - BOFS) + lofsB);
    glds16(gB0 + 32 + g16, Smem + (BOFS1 - BOFS) + lofsB + 512);
    if (wave < 4) {
        glds16(gA0, Smem + lofsA);
        glds16(gA0 + 32, Smem + AOFS1 + lofsA);
    }

    int cur = 0;
    for (int k0 = 0; k0 < K; k0 += 64) {
        int nk = k0 + 64;
        if (nk < K) {
            unsigned short* nb = Smem + (cur ^ 1) * STG;
            glds16(gB0 + nk, nb + lofsB);
            glds16(gB0 + nk + g16, nb + lofsB + 512);
            glds16(gB0 + nk + 32, nb + (BOFS1 - BOFS) + lofsB);
            glds16(gB0 + nk + 32 + g16, nb + (BOFS1 - BOFS) + lofsB + 512);
            if (wave < 4) {
                glds16(gA0 + nk, nb + lofsA);
                glds16(gA0 + nk + 32, nb + AOFS1 + lofsA);
                WAIT_VM6();                  // stage t done; t+1 (6) in flight
            } else {
                WAIT_VM4();
            }
        } else {
            WAIT_VM0();
        }
        __builtin_amdgcn_s_barrier();
        const unsigned short* Sb = Smem + cur * STG;
#pragma unroll
        for (int kk = 0; kk < 2; ++kk) {
            const unsigned short* Ab = Sb + kk * AOFS1;
            const unsigned short* Bb = Sb + BOFS + kk * (BOFS1 - BOFS);
            bf16x8 af[2], bfr[4];
#pragma unroll
            for (int i = 0; i < 2; ++i)
                af[i] = *(const bf16x8*)(Ab + (wm + i * 16 + lrc) * LDP + rofs);
#pragma unroll
            for (int j = 0; j < 4; ++j)
                bfr[j] = *(const bf16x8*)(Bb + (wn + j * 16 + lrc) * LDP + rofs);
#pragma unroll
            for (int i = 0; i < 2; ++i)
#pragma unroll
                for (int j = 0; j < 4; ++j)
                    acc[i][j] = __builtin_amdgcn_mfma_f32_16x16x32_bf16(af[i], bfr[j],
                                                                        acc[i][j], 0, 0, 0);
        }
        __builtin_amdgcn_s_barrier();
        cur ^= 1;
    }
    // Finalize into Cs (bias/relu/res/inter applied in regs).
#pragma unroll
    for (int i = 0; i < 2; ++i) {
#pragma unroll
        for (int r = 0; r < 4; ++r) {
            int lrow = wm + i * 16 + koct * 4 + r;
            int grow = bm + lrow;
#pragma unroll
            for (int j = 0; j < 4; ++j) {
                int lcol = wn + j * 16 + lrc;
                float v = acc[i][j][r];
                if (bias) v += bias[lcol];
                if (relu_first) v = fmaxf(v, 0.f);
                if (resb) v += bf2f(resb[(size_t)grow * 256 + lcol]);
                if (inter) v += inter[(grow >> 8) * 256 + lcol];
                if (do_relu && !relu_first) v = fmaxf(v, 0.f);
                Cs[lrow * CP + lcol] = f2bf(v);
            }
        }
    }
    __syncthreads();

    if constexpr (MODE == 0 || MODE == 1) {
        // Coalesced copy-out: 4 iters x 16 rows; one uint4 per thread.
#pragma unroll
        for (int it = 0; it < 4; ++it) {
            int row = it * 16 + (tid >> 5);
            int cc = (tid & 31) * 8;
            *(uint4*)(&Cb[(size_t)(bm + row) * 256 + cc]) =
                *(const uint4*)(&Cs[row * CP + cc]);
        }
        if constexpr (MODE == 1) {
            if (tid < 256) {
                float s = 0.f, sq = 0.f;
                for (int r = 0; r < 64; ++r) {
                    float v = bf2f(Cs[r * CP + tid]);
                    s += v; sq += v * v;
                }
                atomicAdd(&stat0[tid], s);
                atomicAdd(&stat1[tid], sq);
            }
        }
    } else {
        // LN modes: wave handles rows [wave*8, wave*8+8), lane owns cols lane*4..+3.
        float4 g4 = *(const float4*)(lng + lane * 4);
        float4 b4 = *(const float4*)(lnbt + lane * 4);
#pragma unroll
        for (int q = 0; q < 8; ++q) {
            int row = wave * 8 + q;
            unsigned short tv[4];
            *(uint2*)tv = *(const uint2*)(Cs + row * CP + lane * 4);
            float v0 = bf2f(tv[0]), v1 = bf2f(tv[1]), v2 = bf2f(tv[2]), v3 = bf2f(tv[3]);
            float sum = v0 + v1 + v2 + v3;
#pragma unroll
            for (int off = 32; off; off >>= 1) sum += __shfl_xor(sum, off);
            float mu = sum * (1.f / (float)DH_);
            float d0 = v0 - mu, d1 = v1 - mu, d2 = v2 - mu, d3 = v3 - mu;
            float vs = d0 * d0 + d1 * d1 + d2 * d2 + d3 * d3;
#pragma unroll
            for (int off = 32; off; off >>= 1) vs += __shfl_xor(vs, off);
            float rs = rsqrtf(vs * (1.f / (float)DH_) + EPS_);
            unsigned short ov[4];
            ov[0] = f2bf(d0 * rs * g4.x + b4.x);
            ov[1] = f2bf(d1 * rs * g4.y + b4.y);
            ov[2] = f2bf(d2 * rs * g4.z + b4.z);
            ov[3] = f2bf(d3 * rs * g4.w + b4.w);
            if constexpr (MODE == 2) {
                *(uint2*)(&Cb[(size_t)(bm + row) * 256 + lane * 4]) = *(uint2*)ov;
            } else {
                *(uint2*)(Cs + row * CP + lane * 4) = *(uint2*)ov;
            }
        }
        if constexpr (MODE == 3) {
            __syncthreads();
            if (tid < 256) {
                float s = 0.f;
                for (int r = 0; r < 64; ++r) s += bf2f(Cs[r * CP + tid]);
                atomicAdd(&outp[(bm >> 8) * 256 + tid], s);
            }
        }
    }
}

// ---------------------------------------------------------------------------
// MFMA flash attention, transposed-score, no online softmax.
// P kept fully in-register: QK^T C-fragment -> v_cvt_pk_bf16_f32 ->
// permlane32_swap + permlane16_swap -> PV A-fragment. No Ps LDS buffer.
__global__ __launch_bounds__(256, 4) void attn_mfma_kernel(
    const unsigned short* __restrict__ QKV,
    unsigned short* __restrict__ Ob) {
    int b = blockIdx.x >> 3, h = blockIdx.x & 7;
    __shared__ unsigned short Ks[256 * 32];    // XOR-swizzled chunks
    __shared__ unsigned short Vt[32 * 264];    // [d][key 256 + pad]
    __shared__ float Lc[4 * 64];               // per-wave l broadcast
    const unsigned short* kg = QKV + (size_t)b * 256 * 768 + 256 + h * 32;
    const unsigned short* vg = QKV + (size_t)b * 256 * 768 + 512 + h * 32;
    int tid = threadIdx.x;
#pragma unroll
    for (int it = 0; it < 4; ++it) {
        int c = it * 256 + tid;
        int row = c >> 2, ch = c & 3;
        int slot = ch ^ ((row >> 1) & 3);
        *(uint4*)(Ks + row * 32 + slot * 8) =
            *(const uint4*)(kg + (size_t)row * 768 + ch * 8);
    }
#pragma unroll
    for (int it = 0; it < 4; ++it) {
        int c = it * 256 + tid;
        int key = c >> 2, d0 = (c & 3) * 8;
        unsigned short tmp[8];
        *(uint4*)tmp = *(const uint4*)(vg + (size_t)key * 768 + d0);
#pragma unroll
        for (int j = 0; j < 8; ++j) Vt[(d0 + j) * 264 + key] = tmp[j];
    }
    __syncthreads();

    int wave = tid >> 6, lane = tid & 63;
    int lr = lane & 15, koct = lane >> 4;
    int s4 = (lr >> 1) & 3;
    int qrow0 = b * 256 + wave * 64;
    bf16x8 qf[4];
#pragma unroll
    for (int j = 0; j < 4; ++j)
        qf[j] = *(const bf16x8*)(QKV + (size_t)(qrow0 + j * 16 + lr) * 768 + h * 32 + koct * 8);

    f32x4 Oa[4][2];
    float lp[4];
#pragma unroll
    for (int i = 0; i < 4; ++i) {
        Oa[i][0] = (f32x4){0.f, 0.f, 0.f, 0.f};
        Oa[i][1] = (f32x4){0.f, 0.f, 0.f, 0.f};
        lp[i] = 0.f;
    }
    float* Lw = Lc + wave * 64;

    for (int kc = 0; kc < 256; kc += 32) {
        bf16x8 kf0 = *(const bf16x8*)(Ks + (kc + lr) * 32 + (koct ^ s4) * 8);
        bf16x8 kf1 = *(const bf16x8*)(Ks + (kc + 16 + lr) * 32 + (koct ^ s4) * 8);
        bf16x8 pfr[4];
#pragma unroll
        for (int j = 0; j < 4; ++j) {
            f32x4 St0 = __builtin_amdgcn_mfma_f32_16x16x32_bf16(kf0, qf[j],
                            (f32x4){0.f, 0.f, 0.f, 0.f}, 0, 0, 0);
            f32x4 St1 = __builtin_amdgcn_mfma_f32_16x16x32_bf16(kf1, qf[j],
                            (f32x4){0.f, 0.f, 0.f, 0.f}, 0, 0, 0);
            float p0[4], p1[4], ps = 0.f;
#pragma unroll
            for (int r = 0; r < 4; ++r) {
                p0[r] = exp2f(St0[r]); p1[r] = exp2f(St1[r]);
                ps += p0[r] + p1[r];
            }
            lp[j] += ps;
            unsigned int w0a, w0b, w1a, w1b;
            asm("v_cvt_pk_bf16_f32 %0, %1, %2" : "=v"(w0a) : "v"(p0[0]), "v"(p0[1]));
            asm("v_cvt_pk_bf16_f32 %0, %1, %2" : "=v"(w0b) : "v"(p0[2]), "v"(p0[3]));
            asm("v_cvt_pk_bf16_f32 %0, %1, %2" : "=v"(w1a) : "v"(p1[0]), "v"(p1[1]));
            asm("v_cvt_pk_bf16_f32 %0, %1, %2" : "=v"(w1b) : "v"(p1[2]), "v"(p1[3]));
            u32x2 sa = __builtin_amdgcn_permlane32_swap(w0a, w1a, false, false);
            u32x2 da = __builtin_amdgcn_permlane16_swap(sa[0], sa[1], false, false);
            u32x2 sb = __builtin_amdgcn_permlane32_swap(w0b, w1b, false, false);
            u32x2 db = __builtin_amdgcn_permlane16_swap(sb[0], sb[1], false, false);
            u32x4 pw = {da[0], db[0], da[1], db[1]};
            pfr[j] = __builtin_bit_cast(bf16x8, pw);
        }
        bf16x8 vf0 = *(const bf16x8*)(Vt + lr * 264 + kc + koct * 8);
        bf16x8 vf1 = *(const bf16x8*)(Vt + (16 + lr) * 264 + kc + koct * 8);
#pragma unroll
        for (int i = 0; i < 4; ++i) {
            Oa[i][0] = __builtin_amdgcn_mfma_f32_16x16x32_bf16(pfr[i], vf0, Oa[i][0], 0, 0, 0);
            Oa[i][1] = __builtin_amdgcn_mfma_f32_16x16x32_bf16(pfr[i], vf1, Oa[i][1], 0, 0, 0);
        }
    }
#pragma unroll
    for (int j = 0; j < 4; ++j) {
        lp[j] += __shfl_xor(lp[j], 16);
        lp[j] += __shfl_xor(lp[j], 32);
    }
    if (koct == 0) {
#pragma unroll
        for (int j = 0; j < 4; ++j) Lw[j * 16 + lr] = lp[j];
    }
    __builtin_amdgcn_s_waitcnt(0);
#pragma unroll
    for (int i = 0; i < 4; ++i) {
        f32x4 l4 = *(const f32x4*)(Lw + i * 16 + koct * 4);
#pragma unroll
        for (int r = 0; r < 4; ++r) {
            float inv = 1.f / l4[r];
            int row = qrow0 + i * 16 + koct * 4 + r;
#pragma unroll
            for (int jn = 0; jn < 2; ++jn) {
                int col = h * 32 + jn * 16 + lr;
                Ob[(size_t)row * 256 + col] = f2bf(Oa[i][jn][r] * inv);
            }
        }
    }
}

// ---------------------------------------------------------------------------
extern "C" void kernel_launch(void* const* d_in, const int* in_sizes, int n_in,
                              void* d_out, int out_size, void* d_ws, size_t ws_size,
                              hipStream_t stream) {
    const float* x       = (const float*)d_in[0];
    const int*   ei      = (const int*)d_in[1];
    const float* inter_f = (const float*)d_in[3];
    const float* bn1_g = (const float*)d_in[4],  *bn1_b = (const float*)d_in[5];
    const float* bn2_g = (const float*)d_in[6],  *bn2_b = (const float*)d_in[7];
    const float* w_conv1 = (const float*)d_in[8],  *b_conv1 = (const float*)d_in[9];
    const float* w_conv2 = (const float*)d_in[10], *b_conv2 = (const float*)d_in[11];
    const float* wq = (const float*)d_in[12], *bq = (const float*)d_in[13];
    const float* wk = (const float*)d_in[14], *bk = (const float*)d_in[15];
    const float* wv = (const float*)d_in[16], *bv = (const float*)d_in[17];
    const float* wo = (const float*)d_in[18], *bo = (const float*)d_in[19];
    const float* ln1_g = (const float*)d_in[20], *ln1_b = (const float*)d_in[21];
    const float* ln2_g = (const float*)d_in[22], *ln2_b = (const float*)d_in[23];
    const float* w_ff1 = (const float*)d_in[24], *b_ff1 = (const float*)d_in[25];
    const float* w_ff2 = (const float*)d_in[26], *b_ff2 = (const float*)d_in[27];
    float* out = (float*)d_out;

    char* base = (char*)d_ws;
    size_t o = 0;
    auto alloc = [&](size_t bytes) -> void* {
        void* p = base + o;
        o = (o + bytes + 255) & ~(size_t)255;
        return p;
    };
    int*   deg    = (int*)alloc(NN * 4);
    int*   off    = (int*)alloc((NN + 1) * 4);
    int*   cnt    = (int*)alloc(NN * 4);
    int*   srow   = (int*)alloc(EE * 4);
    float* dis    = (float*)alloc(NN * 4);
    float* csum   = (float*)alloc(256 * 4);   // BN1 stats (contiguous 4 KB
    float* csumsq = (float*)alloc(256 * 4);   //  block with csum2/csumsq2,
    float* csum2  = (float*)alloc(256 * 4);   //  zeroed in one memset)
    float* csumsq2= (float*)alloc(256 * 4);
    float* scl    = (float*)alloc(256 * 4);
    float* shf    = (float*)alloc(256 * 4);
    float* bqkv   = (float*)alloc(768 * 4);
    const size_t SLOT = (size_t)NN * DH_;  // 8M elements (16 MB bf16)
    unsigned short* Arena = (unsigned short*)alloc((size_t)NN * DFF_ * 2);
    unsigned short* TB = (unsigned short*)alloc(SLOT * 2);  // tb
    unsigned short* B0 = (unsigned short*)alloc(SLOT * 2);  // Xb->h1b->Ob->t2b
    unsigned short* wc1t  = (unsigned short*)alloc((size_t)DIN_ * DH_ * 2);
    unsigned short* wc2t  = (unsigned short*)alloc((size_t)DH_ * DH_ * 2);
    unsigned short* wqkvt = (unsigned short*)alloc((size_t)DH_ * DH_ * 3 * 2);
    unsigned short* wot   = (unsigned short*)alloc((size_t)DH_ * DH_ * 2);
    unsigned short* wf1t  = (unsigned short*)alloc((size_t)DH_ * DFF_ * 2);
    unsigned short* wf2t  = (unsigned short*)alloc((size_t)DFF_ * DH_ * 2);
    unsigned short* Xa   = Arena;                            // NN*DIN (4M)
    unsigned short* X2a  = Arena + (size_t)NN * DIN_;        // [4M..12M)
    unsigned short* QKVb = Arena;                            // [0..24M)
    unsigned short* Fb   = Arena;                            // [0..32M)
    unsigned short* tb   = TB;

    hipMemsetAsync(deg, 0, NN * 4, stream);
    hipMemsetAsync(cnt, 0, NN * 4, stream);
    hipMemsetAsync(csum, 0, 4096, stream);                   // all 4 stat arrays
    hipMemsetAsync(out, 0, BG * DH_ * 4, stream);            // readout atomics target

    // All weight transposes in ONE dispatch (bf16; wq pre-scaled by QSCALE)
    WTArgs wa;
    wa.w[0] = w_conv1; wa.o[0] = wc1t;                wa.K[0] = DIN_; wa.N[0] = DH_;  wa.s[0] = 1.f;
    wa.w[1] = w_conv2; wa.o[1] = wc2t;                wa.K[1] = DH_;  wa.N[1] = DH_;  wa.s[1] = 1.f;
    wa.w[2] = wq;      wa.o[2] = wqkvt;               wa.K[2] = DH_;  wa.N[2] = DH_;  wa.s[2] = QSCALE;
    wa.w[3] = wk;      wa.o[3] = wqkvt + DH_ * DH_;   wa.K[3] = DH_;  wa.N[3] = DH_;  wa.s[3] = 1.f;
    wa.w[4] = wv;      wa.o[4] = wqkvt + 2 * DH_ * DH_; wa.K[4] = DH_; wa.N[4] = DH_; wa.s[4] = 1.f;
    wa.w[5] = wo;      wa.o[5] = wot;                 wa.K[5] = DH_;  wa.N[5] = DH_;  wa.s[5] = 1.f;
    wa.w[6] = w_ff1;   wa.o[6] = wf1t;                wa.K[6] = DH_;  wa.N[6] = DFF_; wa.s[6] = 1.f;
    wa.w[7] = w_ff2;   wa.o[7] = wf2t;                wa.K[7] = DFF_; wa.N[7] = DH_;  wa.s[7] = 1.f;
    wtransall_kernel<<<dim3((DH_ * DFF_ + 255) / 256, 8), 256, 0, stream>>>(wa);
    bcat_kernel<<<3, 256, 0, stream>>>(bq, bk, bv, bqkv);

    // Fused init_avg_h + BN1 stats (one pass over x)
    initstats_kernel<<<BG, 128, 0, stream>>>(x, out + BG * DH_, csum, csumsq);
    bnfin_kernel<DIN_><<<1, DIN_, 0, stream>>>(csum, csumsq, bn1_g, bn1_b, scl, shf);
    bnapply4_kernel<<<NN * DIN_ / 1024, 256, 0, stream>>>(x, scl, shf, B0);

    // CSR build
    deg_kernel<<<EE / 256, 256, 0, stream>>>(ei + EE, deg);
    scan_kernel<<<1, 1024, 0, stream>>>(deg, off, dis);
    scatter_kernel<<<EE / 256, 256, 0, stream>>>(ei, ei + EE, off, cnt, srow);

    // agg1 (A·X)·W == A·(X·W): Xa = Anorm @ Xb (bf16, 128 cols)
    aggb_kernel<DIN_, 0><<<NN / 4, 256, 0, stream>>>(B0, off, srow, dis,
                                                     nullptr, nullptr, Xa);
    // conv1 (MODE 1): h1b = relu(Xa @ w_conv1 + b) -> B0 ; fused BN2 stats
    gemm64n256_kernel<1><<<NN / 64, 512, 0, stream>>>(
        Xa, wc1t, B0, DIN_, b_conv1, nullptr, nullptr, 1, 0,
        csum2, csumsq2, nullptr, nullptr, nullptr);
    bnfin_kernel<DH_><<<1, DH_, 0, stream>>>(csum2, csumsq2, bn2_g, bn2_b, scl, shf);

    // agg2 with fused BN apply: X2a = Anorm @ (h1b*s + b)
    aggb_kernel<DH_, 1><<<NN / 4, 256, 0, stream>>>(B0, off, srow, dis,
                                                    scl, shf, X2a);
    // conv2 (MODE 0): tb = h1b + relu(X2a @ w_conv2 + b) + inter[graph] -> TB
    gemm64n256_kernel<0><<<NN / 64, 512, 0, stream>>>(
        X2a, wc2t, tb, DH_, b_conv2, B0, inter_f, 1, 1,
        nullptr, nullptr, nullptr, nullptr, nullptr);

    // Fused QKV (N=768, MT=128): QKVb = tb @ [wq*s|wk|wv] + bqkv
    gemm_bf16_kernel<<<dim3(768 / 128, NN / 128), 512, 0, stream>>>(
        tb, wqkvt, QKVb, NN, DH_, 768, bqkv, nullptr, nullptr, 0, 0);

    // MFMA flash attention -> Ob (B0; h1b dead)
    attn_mfma_kernel<<<BG * NH, 256, 0, stream>>>(QKVb, B0);

    // O-proj (MODE 2): t2b = LN1(Ob @ wo + bo + tb) -> B0 in-place
    gemm64n256_kernel<2><<<NN / 64, 512, 0, stream>>>(
        B0, wot, B0, DH_, bo, tb, nullptr, 0, 0,
        nullptr, nullptr, ln1_g, ln1_b, nullptr);

    // ff1 (N=1024, MT=128): Fb = relu(t2b @ w_ff1 + b1)
    gemm_bf16_kernel<<<dim3(DFF_ / 128, NN / 128), 512, 0, stream>>>(
        B0, wf1t, Fb, NN, DH_, DFF_, b_ff1, nullptr, nullptr, 1, 0);

    // ff2 (MODE 3): LN2(Fb @ w_ff2 + b2 + t2b) -> per-graph column sums -> out
    gemm64n256_kernel<3><<<NN / 64, 512, 0, stream>>>(
        Fb, wf2t, nullptr, DFF_, b_ff2, B0, nullptr, 0, 0,
        nullptr, nullptr, ln2_g, ln2_b, out);
}

// Round 12
// 476.733 us; speedup vs baseline: 1.1899x; 1.0455x over previous
//
#include <hip/hip_runtime.h>
#include <math.h>

// Problem constants (fixed by the reference)
#define NN   32768
#define BG   128
#define SG   256
#define EE   524288
#define DIN_ 128
#define DH_  256
#define NH   8
#define HD_  32
#define DFF_ 1024
#define EPS_ 1e-5f

typedef __attribute__((ext_vector_type(8))) short bf16x8;
typedef __attribute__((ext_vector_type(4))) float f32x4;
typedef __attribute__((ext_vector_type(2))) unsigned int u32x2;
typedef __attribute__((ext_vector_type(4))) unsigned int u32x4;

__device__ __forceinline__ unsigned short f2bf(float f) {
    unsigned int u = __builtin_bit_cast(unsigned int, f);
    unsigned int r = u + 0x7FFFu + ((u >> 16) & 1u);
    return (unsigned short)(r >> 16);
}
__device__ __forceinline__ float bf2f(unsigned short u) {
    return __builtin_bit_cast(float, (unsigned int)u << 16);
}
// Async global->LDS DMA, 16 B per lane (dest = wave-uniform base + lane*16).
__device__ __forceinline__ void glds16(const unsigned short* g, unsigned short* l) {
    __builtin_amdgcn_global_load_lds(
        (const __attribute__((address_space(1))) void*)g,
        (__attribute__((address_space(3))) void*)l, 16, 0, 0);
}
// s_waitcnt with vmcnt(N) only (exp/lgkm masked off).
#define WAIT_VM0() __builtin_amdgcn_s_waitcnt(0x0F70)
#define WAIT_VM2() __builtin_amdgcn_s_waitcnt(0x0F72)
#define WAIT_VM4() __builtin_amdgcn_s_waitcnt(0x0F74)
#define WAIT_VM6() __builtin_amdgcn_s_waitcnt(0x0F76)

// Softmax pre-scale: 1/sqrt(32) * log2(e), folded into wq/bq at transpose time.
#define QSCALE (0.17677669529663689f * 1.4426950408889634f)

// ---------------------------------------------------------------------------
// Fused init_avg_h + BN1 column stats + zeroing of the readout atomics target.
// Block b: rows [b*256, b*256+256) of x; also zeroes outz[b*256 .. +256).
__global__ __launch_bounds__(128) void initstats_kernel(const float* __restrict__ X,
                                                        float* __restrict__ out2,
                                                        float* __restrict__ outz,
                                                        float* __restrict__ csum,
                                                        float* __restrict__ csumsq) {
    int b = blockIdx.x, j = threadIdx.x;
    outz[b * 256 + j] = 0.f;
    outz[b * 256 + 128 + j] = 0.f;
    float s = 0.f, sq = 0.f;
    for (int r = 0; r < SG; ++r) {
        float v = X[(size_t)(b * SG + r) * DIN_ + j];
        s += v; sq += v * v;
    }
    out2[b * DIN_ + j] = s * (1.f / (float)SG);
    atomicAdd(&csum[j], s);
    atomicAdd(&csumsq[j], sq);
}

// BN apply with INLINE stats finalization (kills the bnfin<128> launch):
// scale/shift recomputed per thread from csum/csumsq (identical math).
__global__ __launch_bounds__(256) void bnapply4_kernel(const float* __restrict__ X,
                                                       const float* __restrict__ csum,
                                                       const float* __restrict__ csumsq,
                                                       const float* __restrict__ g,
                                                       const float* __restrict__ b,
                                                       unsigned short* __restrict__ Y) {
    int i4 = (blockIdx.x * 256 + threadIdx.x) * 4;
    int j = i4 & (DIN_ - 1);
    float4 v  = *(const float4*)(X + i4);
    float4 cs = *(const float4*)(csum + j);
    float4 cq = *(const float4*)(csumsq + j);
    float4 gg = *(const float4*)(g + j);
    float4 bb = *(const float4*)(b + j);
    unsigned short o[4];
    {
        float mu = cs.x * (1.f / (float)NN);
        float sc = gg.x * rsqrtf(cq.x * (1.f / (float)NN) - mu * mu + EPS_);
        o[0] = f2bf(v.x * sc + (bb.x - mu * sc));
    }
    {
        float mu = cs.y * (1.f / (float)NN);
        float sc = gg.y * rsqrtf(cq.y * (1.f / (float)NN) - mu * mu + EPS_);
        o[1] = f2bf(v.y * sc + (bb.y - mu * sc));
    }
    {
        float mu = cs.z * (1.f / (float)NN);
        float sc = gg.z * rsqrtf(cq.z * (1.f / (float)NN) - mu * mu + EPS_);
        o[2] = f2bf(v.z * sc + (bb.z - mu * sc));
    }
    {
        float mu = cs.w * (1.f / (float)NN);
        float sc = gg.w * rsqrtf(cq.w * (1.f / (float)NN) - mu * mu + EPS_);
        o[3] = f2bf(v.w * sc + (bb.w - mu * sc));
    }
    *(uint2*)(Y + i4) = *(uint2*)o;
}

// All 8 weight cast+transposes + QKV bias concat in ONE dispatch.
// Segments 0-7 = transposes (blockIdx.y); segment 8 = bias concat.
struct WTArgs {
    const float* w[8];
    unsigned short* o[8];
    int K[8];
    int N[8];
    float s[8];
    const float* bq;
    const float* bk;
    const float* bv;
    float* bqkv;
};
__global__ __launch_bounds__(256) void wtransall_kernel(WTArgs a) {
    int seg = blockIdx.y;
    int idx = blockIdx.x * 256 + threadIdx.x;
    if (seg == 8) {
        if (idx < 256) a.bqkv[idx] = a.bq[idx] * QSCALE;
        else if (idx < 512) a.bqkv[idx] = a.bk[idx - 256];
        else if (idx < 768) a.bqkv[idx] = a.bv[idx - 512];
        return;
    }
    int K = a.K[seg], N = a.N[seg];
    if (idx < K * N) {
        int n = idx / K, k = idx - n * K;
        a.o[seg][idx] = f2bf(a.w[seg][(size_t)k * N + n] * a.s[seg]);
    }
}

// ---------------------------------------------------------------------------
// CSR build
__global__ __launch_bounds__(256) void deg_kernel(const int* __restrict__ col,
                                                  int* __restrict__ deg) {
    int e = blockIdx.x * 256 + threadIdx.x;
    if (e < EE) atomicAdd(&deg[col[e]], 1);
}

__global__ __launch_bounds__(1024) void scan_kernel(const int* __restrict__ deg,
                                                    int* __restrict__ off,
                                                    float* __restrict__ dis) {
    __shared__ int sums[1024];
    int t = threadIdx.x;
    int base = t * 32;
    int loc[32];
    int run = 0;
#pragma unroll
    for (int i = 0; i < 32; ++i) { loc[i] = run; run += deg[base + i]; }
    sums[t] = run;
    __syncthreads();
    for (int d = 1; d < 1024; d <<= 1) {
        int tmp = (t >= d) ? sums[t - d] : 0;
        __syncthreads();
        sums[t] += tmp;
        __syncthreads();
    }
    int excl = sums[t] - run;
#pragma unroll
    for (int i = 0; i < 32; ++i) {
        off[base + i] = excl + loc[i];
        dis[base + i] = rsqrtf((float)(deg[base + i] + 1));
    }
    if (t == 1023) off[NN] = sums[1023];
}

__global__ __launch_bounds__(256) void scatter_kernel(const int* __restrict__ row,
                                                      const int* __restrict__ col,
                                                      const int* __restrict__ off,
                                                      int* __restrict__ cnt,
                                                      int* __restrict__ srow) {
    int e = blockIdx.x * 256 + threadIdx.x;
    if (e < EE) {
        int c = col[e];
        int p = off[c] + atomicAdd(&cnt[c], 1);
        srow[p] = row[e];
    }
}

// ---------------------------------------------------------------------------
// bf16 GCN aggregation, 4x-unrolled edge loop for MLP.
// FUSE_BN path computes BN scale/shift INLINE from column stats (kills the
// bnfin<256> launch; identical arithmetic to the old two-step).
template <int C, int FUSE_BN>
__global__ __launch_bounds__(256) void aggb_kernel(const unsigned short* __restrict__ X,
                                                   const int* __restrict__ off,
                                                   const int* __restrict__ srow,
                                                   const float* __restrict__ dis,
                                                   const float* __restrict__ csum,
                                                   const float* __restrict__ csumsq,
                                                   const float* __restrict__ bg,
                                                   const float* __restrict__ bb,
                                                   unsigned short* __restrict__ Y) {
    constexpr int EPL = C / 64;
    int lane = threadIdx.x & 63;
    int c = blockIdx.x * 4 + (threadIdx.x >> 6);
    float dc = dis[c];
    float acc[EPL];
    float wsum = dc;
    {
        unsigned short t[EPL];
        const unsigned short* xc = X + (size_t)c * C + lane * EPL;
        if constexpr (EPL == 4) *(uint2*)t = *(const uint2*)xc;
        else *(unsigned int*)t = *(const unsigned int*)xc;
#pragma unroll
        for (int e2 = 0; e2 < EPL; ++e2) acc[e2] = dc * bf2f(t[e2]);
    }
    int s = off[c], en = off[c + 1];
    int i = s;
    for (; i + 4 <= en; i += 4) {
        int r0 = srow[i], r1 = srow[i + 1], r2 = srow[i + 2], r3 = srow[i + 3];
        float d0 = dis[r0], d1 = dis[r1], d2 = dis[r2], d3 = dis[r3];
        unsigned short t0[EPL], t1[EPL], t2[EPL], t3[EPL];
        const unsigned short* p0 = X + (size_t)r0 * C + lane * EPL;
        const unsigned short* p1 = X + (size_t)r1 * C + lane * EPL;
        const unsigned short* p2 = X + (size_t)r2 * C + lane * EPL;
        const unsigned short* p3 = X + (size_t)r3 * C + lane * EPL;
        if constexpr (EPL == 4) {
            *(uint2*)t0 = *(const uint2*)p0;
            *(uint2*)t1 = *(const uint2*)p1;
            *(uint2*)t2 = *(const uint2*)p2;
            *(uint2*)t3 = *(const uint2*)p3;
        } else {
            *(unsigned int*)t0 = *(const unsigned int*)p0;
            *(unsigned int*)t1 = *(const unsigned int*)p1;
            *(unsigned int*)t2 = *(const unsigned int*)p2;
            *(unsigned int*)t3 = *(const unsigned int*)p3;
        }
        wsum += d0 + d1 + d2 + d3;
#pragma unroll
        for (int e2 = 0; e2 < EPL; ++e2) {
            acc[e2] += d0 * bf2f(t0[e2]) + d1 * bf2f(t1[e2]) +
                       d2 * bf2f(t2[e2]) + d3 * bf2f(t3[e2]);
        }
    }
    for (; i < en; ++i) {
        int r = srow[i];
        float dr = dis[r];
        unsigned short t[EPL];
        const unsigned short* xr = X + (size_t)r * C + lane * EPL;
        if constexpr (EPL == 4) *(uint2*)t = *(const uint2*)xr;
        else *(unsigned int*)t = *(const unsigned int*)xr;
        wsum += dr;
#pragma unroll
        for (int e2 = 0; e2 < EPL; ++e2) acc[e2] += dr * bf2f(t[e2]);
    }
    unsigned short t[EPL];
#pragma unroll
    for (int e2 = 0; e2 < EPL; ++e2) {
        float v;
        if constexpr (FUSE_BN) {
            int j = lane * EPL + e2;
            float mu = csum[j] * (1.f / (float)NN);
            float var = csumsq[j] * (1.f / (float)NN) - mu * mu;
            float sc = bg[j] * rsqrtf(var + EPS_);
            float sh = bb[j] - mu * sc;
            v = dc * (sc * acc[e2] + sh * wsum);
        } else {
            v = dc * acc[e2];
        }
        t[e2] = f2bf(v);
    }
    unsigned short* yc = Y + (size_t)c * C + lane * EPL;
    if constexpr (EPL == 4) *(uint2*)yc = *(const uint2*)t;
    else *(unsigned int*)yc = *(const unsigned int*)t;
}

// ---------------------------------------------------------------------------
// MT=128 bf16 MFMA GEMM (QKV / ff1), proven round-5 structure: triple-buffered
// glds staging (depth-2 in flight, counted vmcnt), raw s_barrier, XCD swizzle,
// XOR-swizzled staging, coalesced LDS C-tile epilogue. 48 KB -> 3 blocks/CU.
__global__ __launch_bounds__(512, 8) void gemm_bf16_kernel(
    const unsigned short* __restrict__ A,
    const unsigned short* __restrict__ Bt,
    unsigned short* __restrict__ Cb,
    int M, int K, int N,
    const float* __restrict__ bias,
    const unsigned short* __restrict__ resb,
    const float* __restrict__ inter,
    int do_relu, int relu_first) {
    constexpr int LDP = 32;
    constexpr int CP = 136;
    constexpr int MI = 2;
    constexpr int STG = 8192;                // per-stage shorts: A 8KB | B 8KB
    constexpr int BOFS = 4096;
    __shared__ unsigned short Smem[3 * STG];
    unsigned short* Cs = Smem;               // union: staging dead after K-loop
    int gx = gridDim.x, gyP = gridDim.y >> 3;
    int d = blockIdx.y * gx + blockIdx.x;
    int xcd = d & 7, j2 = d >> 3;
    int bm = (xcd * gyP + j2 / gx) * 128;
    int bn = (j2 % gx) * 128;
    int tid = threadIdx.x;
    int wave = tid >> 6, lane = tid & 63;
    int wm = (wave >> 1) * 32;               // 4 m-waves x 2 n-waves
    int wn = (wave & 1) * 64;
    int lrc = lane & 15;
    int koct = lane >> 4;
    int rsw = (lrc >> 1) & 3;
    int rofs = (koct ^ rsw) * 8;
    int cg = (lane & 3) ^ ((lane >> 3) & 3);
    int skk = cg * 8;

    int sr = wave * 16 + (lane >> 2);
    const unsigned short* gA0 = A + (size_t)(bm + sr) * K + skk;
    const unsigned short* gB0 = Bt + (size_t)(bn + sr) * K + skk;
    int lofs = wave * 512 + lane * 8;

    f32x4 acc[MI][4];
#pragma unroll
    for (int i = 0; i < MI; ++i)
#pragma unroll
        for (int j = 0; j < 4; ++j) acc[i][j] = (f32x4){0.f, 0.f, 0.f, 0.f};

    glds16(gA0, Smem + lofs);
    glds16(gB0, Smem + BOFS + lofs);
    glds16(gA0 + 32, Smem + STG + lofs);
    glds16(gB0 + 32, Smem + STG + BOFS + lofs);

    int rb = 0;
    for (int k0 = 0; k0 < K; k0 += 32) {
        if (k0 + 64 < K) {
            int wb = rb + 2; if (wb >= 3) wb -= 3;
            unsigned short* ld = Smem + wb * STG;
            glds16(gA0 + k0 + 64, ld + lofs);
            glds16(gB0 + k0 + 64, ld + BOFS + lofs);
            WAIT_VM4();                       // drain stage t; t+1,t+2 in flight
        } else if (k0 + 32 < K) {
            WAIT_VM2();
        } else {
            WAIT_VM0();
        }
        __builtin_amdgcn_s_barrier();
        const unsigned short* Ab = Smem + rb * STG;
        const unsigned short* Bb = Ab + BOFS;
        bf16x8 af[MI], bfr[4];
#pragma unroll
        for (int i = 0; i < MI; ++i)
            af[i] = *(const bf16x8*)(Ab + (wm + i * 16 + lrc) * LDP + rofs);
#pragma unroll
        for (int j = 0; j < 4; ++j)
            bfr[j] = *(const bf16x8*)(Bb + (wn + j * 16 + lrc) * LDP + rofs);
#pragma unroll
        for (int i = 0; i < MI; ++i)
#pragma unroll
            for (int j = 0; j < 4; ++j)
                acc[i][j] = __builtin_amdgcn_mfma_f32_16x16x32_bf16(af[i], bfr[j],
                                                                    acc[i][j], 0, 0, 0);
        __builtin_amdgcn_s_barrier();
        rb = (rb + 1 == 3) ? 0 : rb + 1;
    }
#pragma unroll
    for (int i = 0; i < MI; ++i) {
#pragma unroll
        for (int r = 0; r < 4; ++r) {
            int lrow = wm + i * 16 + koct * 4 + r;
            int grow = bm + lrow;
#pragma unroll
            for (int j = 0; j < 4; ++j) {
                int lcol = wn + j * 16 + lrc;
                int gcol = bn + lcol;
                float v = acc[i][j][r];
                if (bias) v += bias[gcol];
                if (relu_first) v = fmaxf(v, 0.f);
                if (resb) v += bf2f(resb[(size_t)grow * N + gcol]);
                if (inter) v += inter[(grow >> 8) * N + gcol];
                if (do_relu && !relu_first) v = fmaxf(v, 0.f);
                Cs[lrow * CP + lcol] = f2bf(v);
            }
        }
    }
    __syncthreads();
#pragma unroll
    for (int it = 0; it < 4; ++it) {
        int row = it * 32 + (tid >> 4);
        int cc = (tid & 15) * 8;
        *(uint4*)(&Cb[(size_t)(bm + row) * N + bn + cc]) =
            *(const uint4*)(&Cs[row * CP + cc]);
    }
}

// ---------------------------------------------------------------------------
// 64x256 full-row-tile bf16 GEMM for N=256 layers (round-27 structure, kept).
// K-STEP = 64 double-buffered (2 x 40 KB = 80 KB = the 2-block/CU grid cap).
// Per step: 16 MFMA + 12 ds_read per wave; 8 waves x 32x64 wave-tile.
// Fusion modes:
//   MODE 0: plain copy-out                       (conv2)
//   MODE 1: copy-out + BN column-stats atomics   (conv1)
//   MODE 2: row LayerNorm -> write Cb            (oproj, in-place safe)
//   MODE 3: row LayerNorm -> column-sum atomics into outp (ff2+readout)
template <int MODE>
__global__ __launch_bounds__(512, 2) void gemm64n256_kernel(
    const unsigned short* __restrict__ A,
    const unsigned short* __restrict__ Bt,
    unsigned short* __restrict__ Cb,
    int K,
    const float* __restrict__ bias,
    const unsigned short* __restrict__ resb,
    const float* __restrict__ inter,
    int do_relu, int relu_first,
    float* __restrict__ stat0, float* __restrict__ stat1,
    const float* __restrict__ lng, const float* __restrict__ lnbt,
    float* __restrict__ outp) {
    constexpr int LDP = 32;
    constexpr int CP = 264;                  // 256 + 8 pad
    constexpr int STG = 20480;               // shorts per 64-k stage (40 KB)
    constexpr int AOFS1 = 2048;              // A chunk1
    constexpr int BOFS = 4096;               // B chunk0
    constexpr int BOFS1 = 12288;             // B chunk1
    __shared__ unsigned short Smem[2 * STG]; // 80 KB -> 2 blocks/CU (= grid cap)
    unsigned short* Cs = Smem;               // union (64*264 = 16896 shorts)
    int bm = blockIdx.x * 64;
    int tid = threadIdx.x;
    int wave = tid >> 6, lane = tid & 63;
    int wm = (wave >> 2) * 32;               // 2 m-waves x 4 n-waves
    int wn = (wave & 3) * 64;
    int lrc = lane & 15;
    int koct = lane >> 4;
    int rsw = (lrc >> 1) & 3;
    int rofs = (koct ^ rsw) * 8;
    int cg = (lane & 3) ^ ((lane >> 3) & 3);
    int skk = cg * 8;

    const unsigned short* gB0 = Bt + (size_t)(wave * 32 + (lane >> 2)) * K + skk;
    size_t g16 = (size_t)16 * K;
    int lofsB = BOFS + wave * 1024 + lane * 8;
    const unsigned short* gA0 = nullptr;
    int lofsA = 0;
    if (wave < 4) {
        gA0 = A + (size_t)(bm + wave * 16 + (lane >> 2)) * K + skk;
        lofsA = wave * 512 + lane * 8;
    }

    f32x4 acc[2][4];
#pragma unroll
    for (int i = 0; i < 2; ++i)
#pragma unroll
        for (int j = 0; j < 4; ++j) acc[i][j] = (f32x4){0.f, 0.f, 0.f, 0.f};

    // prologue: stage 0 (k 0..63) into buf 0
    glds16(gB0, Smem + lofsB);
    glds16(gB0 + g16, Smem + lofsB + 512);
    glds16(gB0 + 32, Smem + (BOFS1 - BOFS) + lofsB);
    glds16(gB0 + 32 + g16, Smem + (BOFS1 - BOFS) + lofsB + 512);
    if (wave < 4) {
        glds16(gA0, Smem + lofsA);
        glds16(gA0 + 32, Smem + AOFS1 + lofsA);
    }

    int cur = 0;
    for (int k0 = 0; k0 < K; k0 += 64) {
        int nk = k0 + 64;
        if (nk < K) {
            unsigned short* nb = Smem + (cur ^ 1) * STG;
            glds16(gB0 + nk, nb + lofsB);
            glds16(gB0 + nk + g16, nb + lofsB + 512);
            glds16(gB0 + nk + 32, nb + (BOFS1 - BOFS) + lofsB);
            glds16(gB0 + nk + 32 + g16, nb + (BOFS1 - BOFS) + lofsB + 512);
            if (wave < 4) {
                glds16(gA0 + nk, nb + lofsA);
                glds16(gA0 + nk + 32, nb + AOFS1 + lofsA);
                WAIT_VM6();                  // stage t done; t+1 (6) in flight
            } else {
                WAIT_VM4();
            }
        } else {
            WAIT_VM0();
        }
        __builtin_amdgcn_s_barrier();
        const unsigned short* Sb = Smem + cur * STG;
#pragma unroll
        for (int kk = 0; kk < 2; ++kk) {
            const unsigned short* Ab = Sb + kk * AOFS1;
            const unsigned short* Bb = Sb + BOFS + kk * (BOFS1 - BOFS);
            bf16x8 af[2], bfr[4];
#pragma unroll
            for (int i = 0; i < 2; ++i)
                af[i] = *(const bf16x8*)(Ab + (wm + i * 16 + lrc) * LDP + rofs);
#pragma unroll
            for (int j = 0; j < 4; ++j)
                bfr[j] = *(const bf16x8*)(Bb + (wn + j * 16 + lrc) * LDP + rofs);
#pragma unroll
            for (int i = 0; i < 2; ++i)
#pragma unroll
                for (int j = 0; j < 4; ++j)
                    acc[i][j] = __builtin_amdgcn_mfma_f32_16x16x32_bf16(af[i], bfr[j],
                                                                        acc[i][j], 0, 0, 0);
        }
        __builtin_amdgcn_s_barrier();
        cur ^= 1;
    }
    // Finalize into Cs (bias/relu/res/inter applied in regs).
#pragma unroll
    for (int i = 0; i < 2; ++i) {
#pragma unroll
        for (int r = 0; r < 4; ++r) {
            int lrow = wm + i * 16 + koct * 4 + r;
            int grow = bm + lrow;
#pragma unroll
            for (int j = 0; j < 4; ++j) {
                int lcol = wn + j * 16 + lrc;
                float v = acc[i][j][r];
                if (bias) v += bias[lcol];
                if (relu_first) v = fmaxf(v, 0.f);
                if (resb) v += bf2f(resb[(size_t)grow * 256 + lcol]);
                if (inter) v += inter[(grow >> 8) * 256 + lcol];
                if (do_relu && !relu_first) v = fmaxf(v, 0.f);
                Cs[lrow * CP + lcol] = f2bf(v);
            }
        }
    }
    __syncthreads();

    if constexpr (MODE == 0 || MODE == 1) {
        // Coalesced copy-out: 4 iters x 16 rows; one uint4 per thread.
#pragma unroll
        for (int it = 0; it < 4; ++it) {
            int row = it * 16 + (tid >> 5);
            int cc = (tid & 31) * 8;
            *(uint4*)(&Cb[(size_t)(bm + row) * 256 + cc]) =
                *(const uint4*)(&Cs[row * CP + cc]);
        }
        if constexpr (MODE == 1) {
            if (tid < 256) {
                float s = 0.f, sq = 0.f;
                for (int r = 0; r < 64; ++r) {
                    float v = bf2f(Cs[r * CP + tid]);
                    s += v; sq += v * v;
                }
                atomicAdd(&stat0[tid], s);
                atomicAdd(&stat1[tid], sq);
            }
        }
    } else {
        // LN modes: wave handles rows [wave*8, wave*8+8), lane owns cols lane*4..+3.
        float4 g4 = *(const float4*)(lng + lane * 4);
        float4 b4 = *(const float4*)(lnbt + lane * 4);
#pragma unroll
        for (int q = 0; q < 8; ++q) {
            int row = wave * 8 + q;
            unsigned short tv[4];
            *(uint2*)tv = *(const uint2*)(Cs + row * CP + lane * 4);
            float v0 = bf2f(tv[0]), v1 = bf2f(tv[1]), v2 = bf2f(tv[2]), v3 = bf2f(tv[3]);
            float sum = v0 + v1 + v2 + v3;
#pragma unroll
            for (int off = 32; off; off >>= 1) sum += __shfl_xor(sum, off);
            float mu = sum * (1.f / (float)DH_);
            float d0 = v0 - mu, d1 = v1 - mu, d2 = v2 - mu, d3 = v3 - mu;
            float vs = d0 * d0 + d1 * d1 + d2 * d2 + d3 * d3;
#pragma unroll
            for (int off = 32; off; off >>= 1) vs += __shfl_xor(vs, off);
            float rs = rsqrtf(vs * (1.f / (float)DH_) + EPS_);
            unsigned short ov[4];
            ov[0] = f2bf(d0 * rs * g4.x + b4.x);
            ov[1] = f2bf(d1 * rs * g4.y + b4.y);
            ov[2] = f2bf(d2 * rs * g4.z + b4.z);
            ov[3] = f2bf(d3 * rs * g4.w + b4.w);
            if constexpr (MODE == 2) {
                *(uint2*)(&Cb[(size_t)(bm + row) * 256 + lane * 4]) = *(uint2*)ov;
            } else {
                *(uint2*)(Cs + row * CP + lane * 4) = *(uint2*)ov;
            }
        }
        if constexpr (MODE == 3) {
            __syncthreads();
            if (tid < 256) {
                float s = 0.f;
                for (int r = 0; r < 64; ++r) s += bf2f(Cs[r * CP + tid]);
                atomicAdd(&outp[(bm >> 8) * 256 + tid], s);
            }
        }
    }
}

// ---------------------------------------------------------------------------
// MFMA flash attention, transposed-score, no online softmax.
// P kept fully in-register: QK^T C-fragment -> v_cvt_pk_bf16_f32 ->
// permlane32_swap + permlane16_swap -> PV A-fragment. No Ps LDS buffer.
__global__ __launch_bounds__(256, 4) void attn_mfma_kernel(
    const unsigned short* __restrict__ QKV,
    unsigned short* __restrict__ Ob) {
    int b = blockIdx.x >> 3, h = blockIdx.x & 7;
    __shared__ unsigned short Ks[256 * 32];    // XOR-swizzled chunks
    __shared__ unsigned short Vt[32 * 264];    // [d][key 256 + pad]
    __shared__ float Lc[4 * 64];               // per-wave l broadcast
    const unsigned short* kg = QKV + (size_t)b * 256 * 768 + 256 + h * 32;
    const unsigned short* vg = QKV + (size_t)b * 256 * 768 + 512 + h * 32;
    int tid = threadIdx.x;
#pragma unroll
    for (int it = 0; it < 4; ++it) {
        int c = it * 256 + tid;
        int row = c >> 2, ch = c & 3;
        int slot = ch ^ ((row >> 1) & 3);
        *(uint4*)(Ks + row * 32 + slot * 8) =
            *(const uint4*)(kg + (size_t)row * 768 + ch * 8);
    }
#pragma unroll
    for (int it = 0; it < 4; ++it) {
        int c = it * 256 + tid;
        int key = c >> 2, d0 = (c & 3) * 8;
        unsigned short tmp[8];
        *(uint4*)tmp = *(const uint4*)(vg + (size_t)key * 768 + d0);
#pragma unroll
        for (int j = 0; j < 8; ++j) Vt[(d0 + j) * 264 + key] = tmp[j];
    }
    __syncthreads();

    int wave = tid >> 6, lane = tid & 63;
    int lr = lane & 15, koct = lane >> 4;
    int s4 = (lr >> 1) & 3;
    int qrow0 = b * 256 + wave * 64;
    bf16x8 qf[4];
#pragma unroll
    for (int j = 0; j < 4; ++j)
        qf[j] = *(const bf16x8*)(QKV + (size_t)(qrow0 + j * 16 + lr) * 768 + h * 32 + koct * 8);

    f32x4 Oa[4][2];
    float lp[4];
#pragma unroll
    for (int i = 0; i < 4; ++i) {
        Oa[i][0] = (f32x4){0.f, 0.f, 0.f, 0.f};
        Oa[i][1] = (f32x4){0.f, 0.f, 0.f, 0.f};
        lp[i] = 0.f;
    }
    float* Lw = Lc + wave * 64;

    for (int kc = 0; kc < 256; kc += 32) {
        bf16x8 kf0 = *(const bf16x8*)(Ks + (kc + lr) * 32 + (koct ^ s4) * 8);
        bf16x8 kf1 = *(const bf16x8*)(Ks + (kc + 16 + lr) * 32 + (koct ^ s4) * 8);
        bf16x8 pfr[4];
#pragma unroll
        for (int j = 0; j < 4; ++j) {
            f32x4 St0 = __builtin_amdgcn_mfma_f32_16x16x32_bf16(kf0, qf[j],
                            (f32x4){0.f, 0.f, 0.f, 0.f}, 0, 0, 0);
            f32x4 St1 = __builtin_amdgcn_mfma_f32_16x16x32_bf16(kf1, qf[j],
                            (f32x4){0.f, 0.f, 0.f, 0.f}, 0, 0, 0);
            float p0[4], p1[4], ps = 0.f;
#pragma unroll
            for (int r = 0; r < 4; ++r) {
                p0[r] = exp2f(St0[r]); p1[r] = exp2f(St1[r]);
                ps += p0[r] + p1[r];
            }
            lp[j] += ps;
            unsigned int w0a, w0b, w1a, w1b;
            asm("v_cvt_pk_bf16_f32 %0, %1, %2" : "=v"(w0a) : "v"(p0[0]), "v"(p0[1]));
            asm("v_cvt_pk_bf16_f32 %0, %1, %2" : "=v"(w0b) : "v"(p0[2]), "v"(p0[3]));
            asm("v_cvt_pk_bf16_f32 %0, %1, %2" : "=v"(w1a) : "v"(p1[0]), "v"(p1[1]));
            asm("v_cvt_pk_bf16_f32 %0, %1, %2" : "=v"(w1b) : "v"(p1[2]), "v"(p1[3]));
            u32x2 sa = __builtin_amdgcn_permlane32_swap(w0a, w1a, false, false);
            u32x2 da = __builtin_amdgcn_permlane16_swap(sa[0], sa[1], false, false);
            u32x2 sb = __builtin_amdgcn_permlane32_swap(w0b, w1b, false, false);
            u32x2 db = __builtin_amdgcn_permlane16_swap(sb[0], sb[1], false, false);
            u32x4 pw = {da[0], db[0], da[1], db[1]};
            pfr[j] = __builtin_bit_cast(bf16x8, pw);
        }
        bf16x8 vf0 = *(const bf16x8*)(Vt + lr * 264 + kc + koct * 8);
        bf16x8 vf1 = *(const bf16x8*)(Vt + (16 + lr) * 264 + kc + koct * 8);
#pragma unroll
        for (int i = 0; i < 4; ++i) {
            Oa[i][0] = __builtin_amdgcn_mfma_f32_16x16x32_bf16(pfr[i], vf0, Oa[i][0], 0, 0, 0);
            Oa[i][1] = __builtin_amdgcn_mfma_f32_16x16x32_bf16(pfr[i], vf1, Oa[i][1], 0, 0, 0);
        }
    }
#pragma unroll
    for (int j = 0; j < 4; ++j) {
        lp[j] += __shfl_xor(lp[j], 16);
        lp[j] += __shfl_xor(lp[j], 32);
    }
    if (koct == 0) {
#pragma unroll
        for (int j = 0; j < 4; ++j) Lw[j * 16 + lr] = lp[j];
    }
    __builtin_amdgcn_s_waitcnt(0);
#pragma unroll
    for (int i = 0; i < 4; ++i) {
        f32x4 l4 = *(const f32x4*)(Lw + i * 16 + koct * 4);
#pragma unroll
        for (int r = 0; r < 4; ++r) {
            float inv = 1.f / l4[r];
            int row = qrow0 + i * 16 + koct * 4 + r;
#pragma unroll
            for (int jn = 0; jn < 2; ++jn) {
                int col = h * 32 + jn * 16 + lr;
                Ob[(size_t)row * 256 + col] = f2bf(Oa[i][jn][r] * inv);
            }
        }
    }
}

// ---------------------------------------------------------------------------
extern "C" void kernel_launch(void* const* d_in, const int* in_sizes, int n_in,
                              void* d_out, int out_size, void* d_ws, size_t ws_size,
                              hipStream_t stream) {
    const float* x       = (const float*)d_in[0];
    const int*   ei      = (const int*)d_in[1];
    const float* inter_f = (const float*)d_in[3];
    const float* bn1_g = (const float*)d_in[4],  *bn1_b = (const float*)d_in[5];
    const float* bn2_g = (const float*)d_in[6],  *bn2_b = (const float*)d_in[7];
    const float* w_conv1 = (const float*)d_in[8],  *b_conv1 = (const float*)d_in[9];
    const float* w_conv2 = (const float*)d_in[10], *b_conv2 = (const float*)d_in[11];
    const float* wq = (const float*)d_in[12], *bq = (const float*)d_in[13];
    const float* wk = (const float*)d_in[14], *bk = (const float*)d_in[15];
    const float* wv = (const float*)d_in[16], *bv = (const float*)d_in[17];
    const float* wo = (const float*)d_in[18], *bo = (const float*)d_in[19];
    const float* ln1_g = (const float*)d_in[20], *ln1_b = (const float*)d_in[21];
    const float* ln2_g = (const float*)d_in[22], *ln2_b = (const float*)d_in[23];
    const float* w_ff1 = (const float*)d_in[24], *b_ff1 = (const float*)d_in[25];
    const float* w_ff2 = (const float*)d_in[26], *b_ff2 = (const float*)d_in[27];
    float* out = (float*)d_out;

    char* base = (char*)d_ws;
    size_t o = 0;
    auto alloc = [&](size_t bytes) -> void* {
        void* p = base + o;
        o = (o + bytes + 255) & ~(size_t)255;
        return p;
    };
    // Zero-init region first (contiguous: deg | cnt | csum | csumsq | csum2 | csumsq2)
    int*   deg    = (int*)alloc(NN * 4);
    int*   cnt    = (int*)alloc(NN * 4);
    float* csum   = (float*)alloc(256 * 4);
    float* csumsq = (float*)alloc(256 * 4);
    float* csum2  = (float*)alloc(256 * 4);
    float* csumsq2= (float*)alloc(256 * 4);
    int*   off    = (int*)alloc((NN + 1) * 4);
    int*   srow   = (int*)alloc(EE * 4);
    float* dis    = (float*)alloc(NN * 4);
    float* bqkv   = (float*)alloc(768 * 4);
    const size_t SLOT = (size_t)NN * DH_;  // 8M elements (16 MB bf16)
    unsigned short* Arena = (unsigned short*)alloc((size_t)NN * DFF_ * 2);
    unsigned short* TB = (unsigned short*)alloc(SLOT * 2);  // tb
    unsigned short* B0 = (unsigned short*)alloc(SLOT * 2);  // Xb->h1b->Ob->t2b
    unsigned short* wc1t  = (unsigned short*)alloc((size_t)DIN_ * DH_ * 2);
    unsigned short* wc2t  = (unsigned short*)alloc((size_t)DH_ * DH_ * 2);
    unsigned short* wqkvt = (unsigned short*)alloc((size_t)DH_ * DH_ * 3 * 2);
    unsigned short* wot   = (unsigned short*)alloc((size_t)DH_ * DH_ * 2);
    unsigned short* wf1t  = (unsigned short*)alloc((size_t)DH_ * DFF_ * 2);
    unsigned short* wf2t  = (unsigned short*)alloc((size_t)DFF_ * DH_ * 2);
    unsigned short* Xa   = Arena;                            // NN*DIN (4M)
    unsigned short* X2a  = Arena + (size_t)NN * DIN_;        // [4M..12M)
    unsigned short* QKVb = Arena;                            // [0..24M)
    unsigned short* Fb   = Arena;                            // [0..32M)
    unsigned short* tb   = TB;

    // ONE memset for deg+cnt+all 4 stat arrays (contiguous, 256-aligned).
    hipMemsetAsync(deg, 0, 2 * NN * 4 + 4 * 1024, stream);

    // All weight transposes + QKV bias concat in ONE dispatch.
    WTArgs wa;
    wa.w[0] = w_conv1; wa.o[0] = wc1t;                wa.K[0] = DIN_; wa.N[0] = DH_;  wa.s[0] = 1.f;
    wa.w[1] = w_conv2; wa.o[1] = wc2t;                wa.K[1] = DH_;  wa.N[1] = DH_;  wa.s[1] = 1.f;
    wa.w[2] = wq;      wa.o[2] = wqkvt;               wa.K[2] = DH_;  wa.N[2] = DH_;  wa.s[2] = QSCALE;
    wa.w[3] = wk;      wa.o[3] = wqkvt + DH_ * DH_;   wa.K[3] = DH_;  wa.N[3] = DH_;  wa.s[3] = 1.f;
    wa.w[4] = wv;      wa.o[4] = wqkvt + 2 * DH_ * DH_; wa.K[4] = DH_; wa.N[4] = DH_; wa.s[4] = 1.f;
    wa.w[5] = wo;      wa.o[5] = wot;                 wa.K[5] = DH_;  wa.N[5] = DH_;  wa.s[5] = 1.f;
    wa.w[6] = w_ff1;   wa.o[6] = wf1t;                wa.K[6] = DH_;  wa.N[6] = DFF_; wa.s[6] = 1.f;
    wa.w[7] = w_ff2;   wa.o[7] = wf2t;                wa.K[7] = DFF_; wa.N[7] = DH_;  wa.s[7] = 1.f;
    wa.bq = bq; wa.bk = bk; wa.bv = bv; wa.bqkv = bqkv;
    wtransall_kernel<<<dim3((DH_ * DFF_ + 255) / 256, 9), 256, 0, stream>>>(wa);

    // Fused init_avg_h + BN1 stats + out-zeroing (one pass over x)
    initstats_kernel<<<BG, 128, 0, stream>>>(x, out + BG * DH_, out, csum, csumsq);
    // BN1 apply with inline stats finalization
    bnapply4_kernel<<<NN * DIN_ / 1024, 256, 0, stream>>>(x, csum, csumsq,
                                                          bn1_g, bn1_b, B0);

    // CSR build
    deg_kernel<<<EE / 256, 256, 0, stream>>>(ei + EE, deg);
    scan_kernel<<<1, 1024, 0, stream>>>(deg, off, dis);
    scatter_kernel<<<EE / 256, 256, 0, stream>>>(ei, ei + EE, off, cnt, srow);

    // agg1 (A·X)·W == A·(X·W): Xa = Anorm @ Xb (bf16, 128 cols)
    aggb_kernel<DIN_, 0><<<NN / 4, 256, 0, stream>>>(B0, off, srow, dis,
                                                     nullptr, nullptr, nullptr,
                                                     nullptr, Xa);
    // conv1 (MODE 1): h1b = relu(Xa @ w_conv1 + b) -> B0 ; fused BN2 stats
    gemm64n256_kernel<1><<<NN / 64, 512, 0, stream>>>(
        Xa, wc1t, B0, DIN_, b_conv1, nullptr, nullptr, 1, 0,
        csum2, csumsq2, nullptr, nullptr, nullptr);

    // agg2 with fused BN apply (inline stats finalization; kills bnfin<256>)
    aggb_kernel<DH_, 1><<<NN / 4, 256, 0, stream>>>(B0, off, srow, dis,
                                                    csum2, csumsq2, bn2_g, bn2_b,
                                                    X2a);
    // conv2 (MODE 0): tb = h1b + relu(X2a @ w_conv2 + b) + inter[graph] -> TB
    gemm64n256_kernel<0><<<NN / 64, 512, 0, stream>>>(
        X2a, wc2t, tb, DH_, b_conv2, B0, inter_f, 1, 1,
        nullptr, nullptr, nullptr, nullptr, nullptr);

    // Fused QKV (N=768, MT=128): QKVb = tb @ [wq*s|wk|wv] + bqkv
    gemm_bf16_kernel<<<dim3(768 / 128, NN / 128), 512, 0, stream>>>(
        tb, wqkvt, QKVb, NN, DH_, 768, bqkv, nullptr, nullptr, 0, 0);

    // MFMA flash attention -> Ob (B0; h1b dead)
    attn_mfma_kernel<<<BG * NH, 256, 0, stream>>>(QKVb, B0);

    // O-proj (MODE 2): t2b = LN1(Ob @ wo + bo + tb) -> B0 in-place
    gemm64n256_kernel<2><<<NN / 64, 512, 0, stream>>>(
        B0, wot, B0, DH_, bo, tb, nullptr, 0, 0,
        nullptr, nullptr, ln1_g, ln1_b, nullptr);

    // ff1 (N=1024, MT=128): Fb = relu(t2b @ w_ff1 + b1)
    gemm_bf16_kernel<<<dim3(DFF_ / 128, NN / 128), 512, 0, stream>>>(
        B0, wf1t, Fb, NN, DH_, DFF_, b_ff1, nullptr, nullptr, 1, 0);

    // ff2 (MODE 3): LN2(Fb @ w_ff2 + b2 + t2b) -> per-graph column sums -> out
    gemm64n256_kernel<3><<<NN / 64, 512, 0, stream>>>(
        Fb, wf2t, nullptr, DFF_, b_ff2, B0, nullptr, 0, 0,
        nullptr, nullptr, ln2_g, ln2_b, out);
}

// Round 13
// 474.331 us; speedup vs baseline: 1.1960x; 1.0051x over previous
//
#include <hip/hip_runtime.h>
#include <math.h>

// Problem constants (fixed by the reference)
#define NN   32768
#define BG   128
#define SG   256
#define EE   524288
#define DIN_ 128
#define DH_  256
#define NH   8
#define HD_  32
#define DFF_ 1024
#define EPS_ 1e-5f

typedef __attribute__((ext_vector_type(8))) short bf16x8;
typedef __attribute__((ext_vector_type(4))) float f32x4;
typedef __attribute__((ext_vector_type(2))) unsigned int u32x2;
typedef __attribute__((ext_vector_type(4))) unsigned int u32x4;

__device__ __forceinline__ unsigned short f2bf(float f) {
    unsigned int u = __builtin_bit_cast(unsigned int, f);
    unsigned int r = u + 0x7FFFu + ((u >> 16) & 1u);
    return (unsigned short)(r >> 16);
}
__device__ __forceinline__ float bf2f(unsigned short u) {
    return __builtin_bit_cast(float, (unsigned int)u << 16);
}
// Async global->LDS DMA, 16 B per lane (dest = wave-uniform base + lane*16).
__device__ __forceinline__ void glds16(const unsigned short* g, unsigned short* l) {
    __builtin_amdgcn_global_load_lds(
        (const __attribute__((address_space(1))) void*)g,
        (__attribute__((address_space(3))) void*)l, 16, 0, 0);
}
// s_waitcnt with vmcnt(N) only (exp/lgkm masked off).
#define WAIT_VM0() __builtin_amdgcn_s_waitcnt(0x0F70)
#define WAIT_VM2() __builtin_amdgcn_s_waitcnt(0x0F72)
#define WAIT_VM4() __builtin_amdgcn_s_waitcnt(0x0F74)
#define WAIT_VM6() __builtin_amdgcn_s_waitcnt(0x0F76)

// Softmax pre-scale: 1/sqrt(32) * log2(e), folded into wq/bq at transpose time.
#define QSCALE (0.17677669529663689f * 1.4426950408889634f)

// ---------------------------------------------------------------------------
// MEGA-PREP: all independent prologue work in ONE dispatch.
// blockIdx.y segments: 0-7 weight cast+transpose, 8 QKV bias concat,
// 9 edge-degree histogram, 10 fused init_avg_h + BN1 stats + out-zeroing.
struct PrepArgs {
    const float* w[8];
    unsigned short* o[8];
    int K[8];
    int N[8];
    float s[8];
    const float* bq;
    const float* bk;
    const float* bv;
    float* bqkv;
    const int* col;      // edge targets
    int* deg;
    const float* X;      // raw x
    float* out2;         // init_avg_h target
    float* outz;         // readout atomics target (zeroed here)
    float* csum;
    float* csumsq;
};
__global__ __launch_bounds__(256) void prep_kernel(PrepArgs a) {
    int seg = blockIdx.y;
    int idx = blockIdx.x * 256 + threadIdx.x;
    if (seg < 8) {
        int K = a.K[seg], N = a.N[seg];
        if (idx < K * N) {
            int n = idx / K, k = idx - n * K;
            a.o[seg][idx] = f2bf(a.w[seg][(size_t)k * N + n] * a.s[seg]);
        }
    } else if (seg == 8) {
        if (idx < 256) a.bqkv[idx] = a.bq[idx] * QSCALE;
        else if (idx < 512) a.bqkv[idx] = a.bk[idx - 256];
        else if (idx < 768) a.bqkv[idx] = a.bv[idx - 512];
    } else if (seg == 9) {
        if (idx < EE) atomicAdd(&a.deg[a.col[idx]], 1);
    } else {
        int b = blockIdx.x, j = threadIdx.x;
        if (b < BG && j < 128) {
            a.outz[b * 256 + j] = 0.f;
            a.outz[b * 256 + 128 + j] = 0.f;
            float s = 0.f, sq = 0.f;
            for (int r = 0; r < SG; ++r) {
                float v = a.X[(size_t)(b * SG + r) * DIN_ + j];
                s += v; sq += v * v;
            }
            a.out2[b * DIN_ + j] = s * (1.f / (float)SG);
            atomicAdd(&a.csum[j], s);
            atomicAdd(&a.csumsq[j], sq);
        }
    }
}

// ---------------------------------------------------------------------------
// Fused CSR-scan (block 0) + BN1 apply (blocks 1..1024), 1024 threads.
// scan: exclusive prefix over deg -> off, dis; bnapply: inline stats
// finalization from csum/csumsq (identical math to old bnfin+apply).
__global__ __launch_bounds__(1024) void scanbn_kernel(
    const int* __restrict__ deg, int* __restrict__ off, float* __restrict__ dis,
    const float* __restrict__ X,
    const float* __restrict__ csum, const float* __restrict__ csumsq,
    const float* __restrict__ g, const float* __restrict__ b,
    unsigned short* __restrict__ Y) {
    __shared__ int sums[1024];
    if (blockIdx.x == 0) {
        int t = threadIdx.x;
        int base = t * 32;
        int loc[32];
        int run = 0;
#pragma unroll
        for (int i = 0; i < 32; ++i) { loc[i] = run; run += deg[base + i]; }
        sums[t] = run;
        __syncthreads();
        for (int d = 1; d < 1024; d <<= 1) {
            int tmp = (t >= d) ? sums[t - d] : 0;
            __syncthreads();
            sums[t] += tmp;
            __syncthreads();
        }
        int excl = sums[t] - run;
#pragma unroll
        for (int i = 0; i < 32; ++i) {
            off[base + i] = excl + loc[i];
            dis[base + i] = rsqrtf((float)(deg[base + i] + 1));
        }
        if (t == 1023) off[NN] = sums[1023];
    } else {
        int i4 = ((blockIdx.x - 1) * 1024 + threadIdx.x) * 4;
        int j = i4 & (DIN_ - 1);
        float4 v  = *(const float4*)(X + i4);
        float4 cs = *(const float4*)(csum + j);
        float4 cq = *(const float4*)(csumsq + j);
        float4 gg = *(const float4*)(g + j);
        float4 bb = *(const float4*)(b + j);
        unsigned short o[4];
        {
            float mu = cs.x * (1.f / (float)NN);
            float sc = gg.x * rsqrtf(cq.x * (1.f / (float)NN) - mu * mu + EPS_);
            o[0] = f2bf(v.x * sc + (bb.x - mu * sc));
        }
        {
            float mu = cs.y * (1.f / (float)NN);
            float sc = gg.y * rsqrtf(cq.y * (1.f / (float)NN) - mu * mu + EPS_);
            o[1] = f2bf(v.y * sc + (bb.y - mu * sc));
        }
        {
            float mu = cs.z * (1.f / (float)NN);
            float sc = gg.z * rsqrtf(cq.z * (1.f / (float)NN) - mu * mu + EPS_);
            o[2] = f2bf(v.z * sc + (bb.z - mu * sc));
        }
        {
            float mu = cs.w * (1.f / (float)NN);
            float sc = gg.w * rsqrtf(cq.w * (1.f / (float)NN) - mu * mu + EPS_);
            o[3] = f2bf(v.w * sc + (bb.w - mu * sc));
        }
        *(uint2*)(Y + i4) = *(uint2*)o;
    }
}

__global__ __launch_bounds__(256) void scatter_kernel(const int* __restrict__ row,
                                                      const int* __restrict__ col,
                                                      const int* __restrict__ off,
                                                      int* __restrict__ cnt,
                                                      int* __restrict__ srow) {
    int e = blockIdx.x * 256 + threadIdx.x;
    if (e < EE) {
        int c = col[e];
        int p = off[c] + atomicAdd(&cnt[c], 1);
        srow[p] = row[e];
    }
}

// ---------------------------------------------------------------------------
// bf16 GCN aggregation, 4x-unrolled edge loop for MLP.
// FUSE_BN path computes BN scale/shift INLINE from column stats.
template <int C, int FUSE_BN>
__global__ __launch_bounds__(256) void aggb_kernel(const unsigned short* __restrict__ X,
                                                   const int* __restrict__ off,
                                                   const int* __restrict__ srow,
                                                   const float* __restrict__ dis,
                                                   const float* __restrict__ csum,
                                                   const float* __restrict__ csumsq,
                                                   const float* __restrict__ bg,
                                                   const float* __restrict__ bb,
                                                   unsigned short* __restrict__ Y) {
    constexpr int EPL = C / 64;
    int lane = threadIdx.x & 63;
    int c = blockIdx.x * 4 + (threadIdx.x >> 6);
    float dc = dis[c];
    float acc[EPL];
    float wsum = dc;
    {
        unsigned short t[EPL];
        const unsigned short* xc = X + (size_t)c * C + lane * EPL;
        if constexpr (EPL == 4) *(uint2*)t = *(const uint2*)xc;
        else *(unsigned int*)t = *(const unsigned int*)xc;
#pragma unroll
        for (int e2 = 0; e2 < EPL; ++e2) acc[e2] = dc * bf2f(t[e2]);
    }
    int s = off[c], en = off[c + 1];
    int i = s;
    for (; i + 4 <= en; i += 4) {
        int r0 = srow[i], r1 = srow[i + 1], r2 = srow[i + 2], r3 = srow[i + 3];
        float d0 = dis[r0], d1 = dis[r1], d2 = dis[r2], d3 = dis[r3];
        unsigned short t0[EPL], t1[EPL], t2[EPL], t3[EPL];
        const unsigned short* p0 = X + (size_t)r0 * C + lane * EPL;
        const unsigned short* p1 = X + (size_t)r1 * C + lane * EPL;
        const unsigned short* p2 = X + (size_t)r2 * C + lane * EPL;
        const unsigned short* p3 = X + (size_t)r3 * C + lane * EPL;
        if constexpr (EPL == 4) {
            *(uint2*)t0 = *(const uint2*)p0;
            *(uint2*)t1 = *(const uint2*)p1;
            *(uint2*)t2 = *(const uint2*)p2;
            *(uint2*)t3 = *(const uint2*)p3;
        } else {
            *(unsigned int*)t0 = *(const unsigned int*)p0;
            *(unsigned int*)t1 = *(const unsigned int*)p1;
            *(unsigned int*)t2 = *(const unsigned int*)p2;
            *(unsigned int*)t3 = *(const unsigned int*)p3;
        }
        wsum += d0 + d1 + d2 + d3;
#pragma unroll
        for (int e2 = 0; e2 < EPL; ++e2) {
            acc[e2] += d0 * bf2f(t0[e2]) + d1 * bf2f(t1[e2]) +
                       d2 * bf2f(t2[e2]) + d3 * bf2f(t3[e2]);
        }
    }
    for (; i < en; ++i) {
        int r = srow[i];
        float dr = dis[r];
        unsigned short t[EPL];
        const unsigned short* xr = X + (size_t)r * C + lane * EPL;
        if constexpr (EPL == 4) *(uint2*)t = *(const uint2*)xr;
        else *(unsigned int*)t = *(const unsigned int*)xr;
        wsum += dr;
#pragma unroll
        for (int e2 = 0; e2 < EPL; ++e2) acc[e2] += dr * bf2f(t[e2]);
    }
    unsigned short t[EPL];
#pragma unroll
    for (int e2 = 0; e2 < EPL; ++e2) {
        float v;
        if constexpr (FUSE_BN) {
            int j = lane * EPL + e2;
            float mu = csum[j] * (1.f / (float)NN);
            float var = csumsq[j] * (1.f / (float)NN) - mu * mu;
            float sc = bg[j] * rsqrtf(var + EPS_);
            float sh = bb[j] - mu * sc;
            v = dc * (sc * acc[e2] + sh * wsum);
        } else {
            v = dc * acc[e2];
        }
        t[e2] = f2bf(v);
    }
    unsigned short* yc = Y + (size_t)c * C + lane * EPL;
    if constexpr (EPL == 4) *(uint2*)yc = *(const uint2*)t;
    else *(unsigned int*)yc = *(const unsigned int*)t;
}

// ---------------------------------------------------------------------------
// MT=128 bf16 MFMA GEMM (QKV / ff1), proven round-5 structure: triple-buffered
// glds staging (depth-2 in flight, counted vmcnt), raw s_barrier, XCD swizzle,
// XOR-swizzled staging, coalesced LDS C-tile epilogue. 48 KB -> 3 blocks/CU.
__global__ __launch_bounds__(512, 8) void gemm_bf16_kernel(
    const unsigned short* __restrict__ A,
    const unsigned short* __restrict__ Bt,
    unsigned short* __restrict__ Cb,
    int M, int K, int N,
    const float* __restrict__ bias,
    const unsigned short* __restrict__ resb,
    const float* __restrict__ inter,
    int do_relu, int relu_first) {
    constexpr int LDP = 32;
    constexpr int CP = 136;
    constexpr int MI = 2;
    constexpr int STG = 8192;                // per-stage shorts: A 8KB | B 8KB
    constexpr int BOFS = 4096;
    __shared__ unsigned short Smem[3 * STG];
    unsigned short* Cs = Smem;               // union: staging dead after K-loop
    int gx = gridDim.x, gyP = gridDim.y >> 3;
    int d = blockIdx.y * gx + blockIdx.x;
    int xcd = d & 7, j2 = d >> 3;
    int bm = (xcd * gyP + j2 / gx) * 128;
    int bn = (j2 % gx) * 128;
    int tid = threadIdx.x;
    int wave = tid >> 6, lane = tid & 63;
    int wm = (wave >> 1) * 32;               // 4 m-waves x 2 n-waves
    int wn = (wave & 1) * 64;
    int lrc = lane & 15;
    int koct = lane >> 4;
    int rsw = (lrc >> 1) & 3;
    int rofs = (koct ^ rsw) * 8;
    int cg = (lane & 3) ^ ((lane >> 3) & 3);
    int skk = cg * 8;

    int sr = wave * 16 + (lane >> 2);
    const unsigned short* gA0 = A + (size_t)(bm + sr) * K + skk;
    const unsigned short* gB0 = Bt + (size_t)(bn + sr) * K + skk;
    int lofs = wave * 512 + lane * 8;

    f32x4 acc[MI][4];
#pragma unroll
    for (int i = 0; i < MI; ++i)
#pragma unroll
        for (int j = 0; j < 4; ++j) acc[i][j] = (f32x4){0.f, 0.f, 0.f, 0.f};

    glds16(gA0, Smem + lofs);
    glds16(gB0, Smem + BOFS + lofs);
    glds16(gA0 + 32, Smem + STG + lofs);
    glds16(gB0 + 32, Smem + STG + BOFS + lofs);

    int rb = 0;
    for (int k0 = 0; k0 < K; k0 += 32) {
        if (k0 + 64 < K) {
            int wb = rb + 2; if (wb >= 3) wb -= 3;
            unsigned short* ld = Smem + wb * STG;
            glds16(gA0 + k0 + 64, ld + lofs);
            glds16(gB0 + k0 + 64, ld + BOFS + lofs);
            WAIT_VM4();                       // drain stage t; t+1,t+2 in flight
        } else if (k0 + 32 < K) {
            WAIT_VM2();
        } else {
            WAIT_VM0();
        }
        __builtin_amdgcn_s_barrier();
        const unsigned short* Ab = Smem + rb * STG;
        const unsigned short* Bb = Ab + BOFS;
        bf16x8 af[MI], bfr[4];
#pragma unroll
        for (int i = 0; i < MI; ++i)
            af[i] = *(const bf16x8*)(Ab + (wm + i * 16 + lrc) * LDP + rofs);
#pragma unroll
        for (int j = 0; j < 4; ++j)
            bfr[j] = *(const bf16x8*)(Bb + (wn + j * 16 + lrc) * LDP + rofs);
#pragma unroll
        for (int i = 0; i < MI; ++i)
#pragma unroll
            for (int j = 0; j < 4; ++j)
                acc[i][j] = __builtin_amdgcn_mfma_f32_16x16x32_bf16(af[i], bfr[j],
                                                                    acc[i][j], 0, 0, 0);
        __builtin_amdgcn_s_barrier();
        rb = (rb + 1 == 3) ? 0 : rb + 1;
    }
#pragma unroll
    for (int i = 0; i < MI; ++i) {
#pragma unroll
        for (int r = 0; r < 4; ++r) {
            int lrow = wm + i * 16 + koct * 4 + r;
            int grow = bm + lrow;
#pragma unroll
            for (int j = 0; j < 4; ++j) {
                int lcol = wn + j * 16 + lrc;
                int gcol = bn + lcol;
                float v = acc[i][j][r];
                if (bias) v += bias[gcol];
                if (relu_first) v = fmaxf(v, 0.f);
                if (resb) v += bf2f(resb[(size_t)grow * N + gcol]);
                if (inter) v += inter[(grow >> 8) * N + gcol];
                if (do_relu && !relu_first) v = fmaxf(v, 0.f);
                Cs[lrow * CP + lcol] = f2bf(v);
            }
        }
    }
    __syncthreads();
#pragma unroll
    for (int it = 0; it < 4; ++it) {
        int row = it * 32 + (tid >> 4);
        int cc = (tid & 15) * 8;
        *(uint4*)(&Cb[(size_t)(bm + row) * N + bn + cc]) =
            *(const uint4*)(&Cs[row * CP + cc]);
    }
}

// ---------------------------------------------------------------------------
// 64x256 full-row-tile bf16 GEMM for N=256 layers (round-27 structure, kept).
// K-STEP = 64 double-buffered (2 x 40 KB = 80 KB = the 2-block/CU grid cap).
// Per step: 16 MFMA + 12 ds_read per wave; 8 waves x 32x64 wave-tile.
// Fusion modes:
//   MODE 0: plain copy-out                       (conv2)
//   MODE 1: copy-out + BN column-stats atomics   (conv1)
//   MODE 2: row LayerNorm -> write Cb            (oproj, in-place safe)
//   MODE 3: row LayerNorm -> column-sum atomics into outp (ff2+readout)
template <int MODE>
__global__ __launch_bounds__(512, 2) void gemm64n256_kernel(
    const unsigned short* __restrict__ A,
    const unsigned short* __restrict__ Bt,
    unsigned short* __restrict__ Cb,
    int K,
    const float* __restrict__ bias,
    const unsigned short* __restrict__ resb,
    const float* __restrict__ inter,
    int do_relu, int relu_first,
    float* __restrict__ stat0, float* __restrict__ stat1,
    const float* __restrict__ lng, const float* __restrict__ lnbt,
    float* __restrict__ outp) {
    constexpr int LDP = 32;
    constexpr int CP = 264;                  // 256 + 8 pad
    constexpr int STG = 20480;               // shorts per 64-k stage (40 KB)
    constexpr int AOFS1 = 2048;              // A chunk1
    constexpr int BOFS = 4096;               // B chunk0
    constexpr int BOFS1 = 12288;             // B chunk1
    __shared__ unsigned short Smem[2 * STG]; // 80 KB -> 2 blocks/CU (= grid cap)
    unsigned short* Cs = Smem;               // union (64*264 = 16896 shorts)
    int bm = blockIdx.x * 64;
    int tid = threadIdx.x;
    int wave = tid >> 6, lane = tid & 63;
    int wm = (wave >> 2) * 32;               // 2 m-waves x 4 n-waves
    int wn = (wave & 3) * 64;
    int lrc = lane & 15;
    int koct = lane >> 4;
    int rsw = (lrc >> 1) & 3;
    int rofs = (koct ^ rsw) * 8;
    int cg = (lane & 3) ^ ((lane >> 3) & 3);
    int skk = cg * 8;

    const unsigned short* gB0 = Bt + (size_t)(wave * 32 + (lane >> 2)) * K + skk;
    size_t g16 = (size_t)16 * K;
    int lofsB = BOFS + wave * 1024 + lane * 8;
    const unsigned short* gA0 = nullptr;
    int lofsA = 0;
    if (wave < 4) {
        gA0 = A + (size_t)(bm + wave * 16 + (lane >> 2)) * K + skk;
        lofsA = wave * 512 + lane * 8;
    }

    f32x4 acc[2][4];
#pragma unroll
    for (int i = 0; i < 2; ++i)
#pragma unroll
        for (int j = 0; j < 4; ++j) acc[i][j] = (f32x4){0.f, 0.f, 0.f, 0.f};

    // prologue: stage 0 (k 0..63) into buf 0
    glds16(gB0, Smem + lofsB);
    glds16(gB0 + g16, Smem + lofsB + 512);
    glds16(gB0 + 32, Smem + (BOFS1 - BOFS) + lofsB);
    glds16(gB0 + 32 + g16, Smem + (BOFS1 - BOFS) + lofsB + 512);
    if (wave < 4) {
        glds16(gA0, Smem + lofsA);
        glds16(gA0 + 32, Smem + AOFS1 + lofsA);
    }

    int cur = 0;
    for (int k0 = 0; k0 < K; k0 += 64) {
        int nk = k0 + 64;
        if (nk < K) {
            unsigned short* nb = Smem + (cur ^ 1) * STG;
            glds16(gB0 + nk, nb + lofsB);
            glds16(gB0 + nk + g16, nb + lofsB + 512);
            glds16(gB0 + nk + 32, nb + (BOFS1 - BOFS) + lofsB);
            glds16(gB0 + nk + 32 + g16, nb + (BOFS1 - BOFS) + lofsB + 512);
            if (wave < 4) {
                glds16(gA0 + nk, nb + lofsA);
                glds16(gA0 + nk + 32, nb + AOFS1 + lofsA);
                WAIT_VM6();                  // stage t done; t+1 (6) in flight
            } else {
                WAIT_VM4();
            }
        } else {
            WAIT_VM0();
        }
        __builtin_amdgcn_s_barrier();
        const unsigned short* Sb = Smem + cur * STG;
#pragma unroll
        for (int kk = 0; kk < 2; ++kk) {
            const unsigned short* Ab = Sb + kk * AOFS1;
            const unsigned short* Bb = Sb + BOFS + kk * (BOFS1 - BOFS);
            bf16x8 af[2], bfr[4];
#pragma unroll
            for (int i = 0; i < 2; ++i)
                af[i] = *(const bf16x8*)(Ab + (wm + i * 16 + lrc) * LDP + rofs);
#pragma unroll
            for (int j = 0; j < 4; ++j)
                bfr[j] = *(const bf16x8*)(Bb + (wn + j * 16 + lrc) * LDP + rofs);
#pragma unroll
            for (int i = 0; i < 2; ++i)
#pragma unroll
                for (int j = 0; j < 4; ++j)
                    acc[i][j] = __builtin_amdgcn_mfma_f32_16x16x32_bf16(af[i], bfr[j],
                                                                        acc[i][j], 0, 0, 0);
        }
        __builtin_amdgcn_s_barrier();
        cur ^= 1;
    }
    // Finalize into Cs (bias/relu/res/inter applied in regs).
#pragma unroll
    for (int i = 0; i < 2; ++i) {
#pragma unroll
        for (int r = 0; r < 4; ++r) {
            int lrow = wm + i * 16 + koct * 4 + r;
            int grow = bm + lrow;
#pragma unroll
            for (int j = 0; j < 4; ++j) {
                int lcol = wn + j * 16 + lrc;
                float v = acc[i][j][r];
                if (bias) v += bias[lcol];
                if (relu_first) v = fmaxf(v, 0.f);
                if (resb) v += bf2f(resb[(size_t)grow * 256 + lcol]);
                if (inter) v += inter[(grow >> 8) * 256 + lcol];
                if (do_relu && !relu_first) v = fmaxf(v, 0.f);
                Cs[lrow * CP + lcol] = f2bf(v);
            }
        }
    }
    __syncthreads();

    if constexpr (MODE == 0 || MODE == 1) {
        // Coalesced copy-out: 4 iters x 16 rows; one uint4 per thread.
#pragma unroll
        for (int it = 0; it < 4; ++it) {
            int row = it * 16 + (tid >> 5);
            int cc = (tid & 31) * 8;
            *(uint4*)(&Cb[(size_t)(bm + row) * 256 + cc]) =
                *(const uint4*)(&Cs[row * CP + cc]);
        }
        if constexpr (MODE == 1) {
            if (tid < 256) {
                float s = 0.f, sq = 0.f;
                for (int r = 0; r < 64; ++r) {
                    float v = bf2f(Cs[r * CP + tid]);
                    s += v; sq += v * v;
                }
                atomicAdd(&stat0[tid], s);
                atomicAdd(&stat1[tid], sq);
            }
        }
    } else {
        // LN modes: wave handles rows [wave*8, wave*8+8), lane owns cols lane*4..+3.
        float4 g4 = *(const float4*)(lng + lane * 4);
        float4 b4 = *(const float4*)(lnbt + lane * 4);
#pragma unroll
        for (int q = 0; q < 8; ++q) {
            int row = wave * 8 + q;
            unsigned short tv[4];
            *(uint2*)tv = *(const uint2*)(Cs + row * CP + lane * 4);
            float v0 = bf2f(tv[0]), v1 = bf2f(tv[1]), v2 = bf2f(tv[2]), v3 = bf2f(tv[3]);
            float sum = v0 + v1 + v2 + v3;
#pragma unroll
            for (int off = 32; off; off >>= 1) sum += __shfl_xor(sum, off);
            float mu = sum * (1.f / (float)DH_);
            float d0 = v0 - mu, d1 = v1 - mu, d2 = v2 - mu, d3 = v3 - mu;
            float vs = d0 * d0 + d1 * d1 + d2 * d2 + d3 * d3;
#pragma unroll
            for (int off = 32; off; off >>= 1) vs += __shfl_xor(vs, off);
            float rs = rsqrtf(vs * (1.f / (float)DH_) + EPS_);
            unsigned short ov[4];
            ov[0] = f2bf(d0 * rs * g4.x + b4.x);
            ov[1] = f2bf(d1 * rs * g4.y + b4.y);
            ov[2] = f2bf(d2 * rs * g4.z + b4.z);
            ov[3] = f2bf(d3 * rs * g4.w + b4.w);
            if constexpr (MODE == 2) {
                *(uint2*)(&Cb[(size_t)(bm + row) * 256 + lane * 4]) = *(uint2*)ov;
            } else {
                *(uint2*)(Cs + row * CP + lane * 4) = *(uint2*)ov;
            }
        }
        if constexpr (MODE == 3) {
            __syncthreads();
            if (tid < 256) {
                float s = 0.f;
                for (int r = 0; r < 64; ++r) s += bf2f(Cs[r * CP + tid]);
                atomicAdd(&outp[(bm >> 8) * 256 + tid], s);
            }
        }
    }
}

// ---------------------------------------------------------------------------
// MFMA flash attention, transposed-score, no online softmax.
// P kept fully in-register: QK^T C-fragment -> v_cvt_pk_bf16_f32 ->
// permlane32_swap + permlane16_swap -> PV A-fragment. No Ps LDS buffer.
__global__ __launch_bounds__(256, 4) void attn_mfma_kernel(
    const unsigned short* __restrict__ QKV,
    unsigned short* __restrict__ Ob) {
    int b = blockIdx.x >> 3, h = blockIdx.x & 7;
    __shared__ unsigned short Ks[256 * 32];    // XOR-swizzled chunks
    __shared__ unsigned short Vt[32 * 264];    // [d][key 256 + pad]
    __shared__ float Lc[4 * 64];               // per-wave l broadcast
    const unsigned short* kg = QKV + (size_t)b * 256 * 768 + 256 + h * 32;
    const unsigned short* vg = QKV + (size_t)b * 256 * 768 + 512 + h * 32;
    int tid = threadIdx.x;
#pragma unroll
    for (int it = 0; it < 4; ++it) {
        int c = it * 256 + tid;
        int row = c >> 2, ch = c & 3;
        int slot = ch ^ ((row >> 1) & 3);
        *(uint4*)(Ks + row * 32 + slot * 8) =
            *(const uint4*)(kg + (size_t)row * 768 + ch * 8);
    }
#pragma unroll
    for (int it = 0; it < 4; ++it) {
        int c = it * 256 + tid;
        int key = c >> 2, d0 = (c & 3) * 8;
        unsigned short tmp[8];
        *(uint4*)tmp = *(const uint4*)(vg + (size_t)key * 768 + d0);
#pragma unroll
        for (int j = 0; j < 8; ++j) Vt[(d0 + j) * 264 + key] = tmp[j];
    }
    __syncthreads();

    int wave = tid >> 6, lane = tid & 63;
    int lr = lane & 15, koct = lane >> 4;
    int s4 = (lr >> 1) & 3;
    int qrow0 = b * 256 + wave * 64;
    bf16x8 qf[4];
#pragma unroll
    for (int j = 0; j < 4; ++j)
        qf[j] = *(const bf16x8*)(QKV + (size_t)(qrow0 + j * 16 + lr) * 768 + h * 32 + koct * 8);

    f32x4 Oa[4][2];
    float lp[4];
#pragma unroll
    for (int i = 0; i < 4; ++i) {
        Oa[i][0] = (f32x4){0.f, 0.f, 0.f, 0.f};
        Oa[i][1] = (f32x4){0.f, 0.f, 0.f, 0.f};
        lp[i] = 0.f;
    }
    float* Lw = Lc + wave * 64;

    for (int kc = 0; kc < 256; kc += 32) {
        bf16x8 kf0 = *(const bf16x8*)(Ks + (kc + lr) * 32 + (koct ^ s4) * 8);
        bf16x8 kf1 = *(const bf16x8*)(Ks + (kc + 16 + lr) * 32 + (koct ^ s4) * 8);
        bf16x8 pfr[4];
#pragma unroll
        for (int j = 0; j < 4; ++j) {
            f32x4 St0 = __builtin_amdgcn_mfma_f32_16x16x32_bf16(kf0, qf[j],
                            (f32x4){0.f, 0.f, 0.f, 0.f}, 0, 0, 0);
            f32x4 St1 = __builtin_amdgcn_mfma_f32_16x16x32_bf16(kf1, qf[j],
                            (f32x4){0.f, 0.f, 0.f, 0.f}, 0, 0, 0);
            float p0[4], p1[4], ps = 0.f;
#pragma unroll
            for (int r = 0; r < 4; ++r) {
                p0[r] = exp2f(St0[r]); p1[r] = exp2f(St1[r]);
                ps += p0[r] + p1[r];
            }
            lp[j] += ps;
            unsigned int w0a, w0b, w1a, w1b;
            asm("v_cvt_pk_bf16_f32 %0, %1, %2" : "=v"(w0a) : "v"(p0[0]), "v"(p0[1]));
            asm("v_cvt_pk_bf16_f32 %0, %1, %2" : "=v"(w0b) : "v"(p0[2]), "v"(p0[3]));
            asm("v_cvt_pk_bf16_f32 %0, %1, %2" : "=v"(w1a) : "v"(p1[0]), "v"(p1[1]));
            asm("v_cvt_pk_bf16_f32 %0, %1, %2" : "=v"(w1b) : "v"(p1[2]), "v"(p1[3]));
            u32x2 sa = __builtin_amdgcn_permlane32_swap(w0a, w1a, false, false);
            u32x2 da = __builtin_amdgcn_permlane16_swap(sa[0], sa[1], false, false);
            u32x2 sb = __builtin_amdgcn_permlane32_swap(w0b, w1b, false, false);
            u32x2 db = __builtin_amdgcn_permlane16_swap(sb[0], sb[1], false, false);
            u32x4 pw = {da[0], db[0], da[1], db[1]};
            pfr[j] = __builtin_bit_cast(bf16x8, pw);
        }
        bf16x8 vf0 = *(const bf16x8*)(Vt + lr * 264 + kc + koct * 8);
        bf16x8 vf1 = *(const bf16x8*)(Vt + (16 + lr) * 264 + kc + koct * 8);
#pragma unroll
        for (int i = 0; i < 4; ++i) {
            Oa[i][0] = __builtin_amdgcn_mfma_f32_16x16x32_bf16(pfr[i], vf0, Oa[i][0], 0, 0, 0);
            Oa[i][1] = __builtin_amdgcn_mfma_f32_16x16x32_bf16(pfr[i], vf1, Oa[i][1], 0, 0, 0);
        }
    }
#pragma unroll
    for (int j = 0; j < 4; ++j) {
        lp[j] += __shfl_xor(lp[j], 16);
        lp[j] += __shfl_xor(lp[j], 32);
    }
    if (koct == 0) {
#pragma unroll
        for (int j = 0; j < 4; ++j) Lw[j * 16 + lr] = lp[j];
    }
    __builtin_amdgcn_s_waitcnt(0);
#pragma unroll
    for (int i = 0; i < 4; ++i) {
        f32x4 l4 = *(const f32x4*)(Lw + i * 16 + koct * 4);
#pragma unroll
        for (int r = 0; r < 4; ++r) {
            float inv = 1.f / l4[r];
            int row = qrow0 + i * 16 + koct * 4 + r;
#pragma unroll
            for (int jn = 0; jn < 2; ++jn) {
                int col = h * 32 + jn * 16 + lr;
                Ob[(size_t)row * 256 + col] = f2bf(Oa[i][jn][r] * inv);
            }
        }
    }
}

// ---------------------------------------------------------------------------
extern "C" void kernel_launch(void* const* d_in, const int* in_sizes, int n_in,
                              void* d_out, int out_size, void* d_ws, size_t ws_size,
                              hipStream_t stream) {
    const float* x       = (const float*)d_in[0];
    const int*   ei      = (const int*)d_in[1];
    const float* inter_f = (const float*)d_in[3];
    const float* bn1_g = (const float*)d_in[4],  *bn1_b = (const float*)d_in[5];
    const float* bn2_g = (const float*)d_in[6],  *bn2_b = (const float*)d_in[7];
    const float* w_conv1 = (const float*)d_in[8],  *b_conv1 = (const float*)d_in[9];
    const float* w_conv2 = (const float*)d_in[10], *b_conv2 = (const float*)d_in[11];
    const float* wq = (const float*)d_in[12], *bq = (const float*)d_in[13];
    const float* wk = (const float*)d_in[14], *bk = (const float*)d_in[15];
    const float* wv = (const float*)d_in[16], *bv = (const float*)d_in[17];
    const float* wo = (const float*)d_in[18], *bo = (const float*)d_in[19];
    const float* ln1_g = (const float*)d_in[20], *ln1_b = (const float*)d_in[21];
    const float* ln2_g = (const float*)d_in[22], *ln2_b = (const float*)d_in[23];
    const float* w_ff1 = (const float*)d_in[24], *b_ff1 = (const float*)d_in[25];
    const float* w_ff2 = (const float*)d_in[26], *b_ff2 = (const float*)d_in[27];
    float* out = (float*)d_out;

    char* base = (char*)d_ws;
    size_t o = 0;
    auto alloc = [&](size_t bytes) -> void* {
        void* p = base + o;
        o = (o + bytes + 255) & ~(size_t)255;
        return p;
    };
    // Zero-init region first (contiguous: deg | cnt | csum | csumsq | csum2 | csumsq2)
    int*   deg    = (int*)alloc(NN * 4);
    int*   cnt    = (int*)alloc(NN * 4);
    float* csum   = (float*)alloc(256 * 4);
    float* csumsq = (float*)alloc(256 * 4);
    float* csum2  = (float*)alloc(256 * 4);
    float* csumsq2= (float*)alloc(256 * 4);
    int*   off    = (int*)alloc((NN + 1) * 4);
    int*   srow   = (int*)alloc(EE * 4);
    float* dis    = (float*)alloc(NN * 4);
    float* bqkv   = (float*)alloc(768 * 4);
    const size_t SLOT = (size_t)NN * DH_;  // 8M elements (16 MB bf16)
    unsigned short* Arena = (unsigned short*)alloc((size_t)NN * DFF_ * 2);
    unsigned short* TB = (unsigned short*)alloc(SLOT * 2);  // tb
    unsigned short* B0 = (unsigned short*)alloc(SLOT * 2);  // Xb->h1b->Ob->t2b
    unsigned short* wc1t  = (unsigned short*)alloc((size_t)DIN_ * DH_ * 2);
    unsigned short* wc2t  = (unsigned short*)alloc((size_t)DH_ * DH_ * 2);
    unsigned short* wqkvt = (unsigned short*)alloc((size_t)DH_ * DH_ * 3 * 2);
    unsigned short* wot   = (unsigned short*)alloc((size_t)DH_ * DH_ * 2);
    unsigned short* wf1t  = (unsigned short*)alloc((size_t)DH_ * DFF_ * 2);
    unsigned short* wf2t  = (unsigned short*)alloc((size_t)DFF_ * DH_ * 2);
    unsigned short* Xa   = Arena;                            // NN*DIN (4M)
    unsigned short* X2a  = Arena + (size_t)NN * DIN_;        // [4M..12M)
    unsigned short* QKVb = Arena;                            // [0..24M)
    unsigned short* Fb   = Arena;                            // [0..32M)
    unsigned short* tb   = TB;

    // ONE memset for deg+cnt+all 4 stat arrays (contiguous, 256-aligned).
    hipMemsetAsync(deg, 0, 2 * NN * 4 + 4 * 1024, stream);

    // MEGA-PREP: weight transposes + bias concat + deg histogram + initstats.
    PrepArgs pa;
    pa.w[0] = w_conv1; pa.o[0] = wc1t;                pa.K[0] = DIN_; pa.N[0] = DH_;  pa.s[0] = 1.f;
    pa.w[1] = w_conv2; pa.o[1] = wc2t;                pa.K[1] = DH_;  pa.N[1] = DH_;  pa.s[1] = 1.f;
    pa.w[2] = wq;      pa.o[2] = wqkvt;               pa.K[2] = DH_;  pa.N[2] = DH_;  pa.s[2] = QSCALE;
    pa.w[3] = wk;      pa.o[3] = wqkvt + DH_ * DH_;   pa.K[3] = DH_;  pa.N[3] = DH_;  pa.s[3] = 1.f;
    pa.w[4] = wv;      pa.o[4] = wqkvt + 2 * DH_ * DH_; pa.K[4] = DH_; pa.N[4] = DH_; pa.s[4] = 1.f;
    pa.w[5] = wo;      pa.o[5] = wot;                 pa.K[5] = DH_;  pa.N[5] = DH_;  pa.s[5] = 1.f;
    pa.w[6] = w_ff1;   pa.o[6] = wf1t;                pa.K[6] = DH_;  pa.N[6] = DFF_; pa.s[6] = 1.f;
    pa.w[7] = w_ff2;   pa.o[7] = wf2t;                pa.K[7] = DFF_; pa.N[7] = DH_;  pa.s[7] = 1.f;
    pa.bq = bq; pa.bk = bk; pa.bv = bv; pa.bqkv = bqkv;
    pa.col = ei + EE; pa.deg = deg;
    pa.X = x; pa.out2 = out + BG * DH_; pa.outz = out;
    pa.csum = csum; pa.csumsq = csumsq;
    prep_kernel<<<dim3(EE / 256, 11), 256, 0, stream>>>(pa);

    // Fused CSR scan (block 0) + BN1 apply (blocks 1..1024)
    scanbn_kernel<<<1 + NN * DIN_ / 4096, 1024, 0, stream>>>(
        deg, off, dis, x, csum, csumsq, bn1_g, bn1_b, B0);

    scatter_kernel<<<EE / 256, 256, 0, stream>>>(ei, ei + EE, off, cnt, srow);

    // agg1 (A·X)·W == A·(X·W): Xa = Anorm @ Xb (bf16, 128 cols)
    aggb_kernel<DIN_, 0><<<NN / 4, 256, 0, stream>>>(B0, off, srow, dis,
                                                     nullptr, nullptr, nullptr,
                                                     nullptr, Xa);
    // conv1 (MODE 1): h1b = relu(Xa @ w_conv1 + b) -> B0 ; fused BN2 stats
    gemm64n256_kernel<1><<<NN / 64, 512, 0, stream>>>(
        Xa, wc1t, B0, DIN_, b_conv1, nullptr, nullptr, 1, 0,
        csum2, csumsq2, nullptr, nullptr, nullptr);

    // agg2 with fused BN apply (inline stats finalization)
    aggb_kernel<DH_, 1><<<NN / 4, 256, 0, stream>>>(B0, off, srow, dis,
                                                    csum2, csumsq2, bn2_g, bn2_b,
                                                    X2a);
    // conv2 (MODE 0): tb = h1b + relu(X2a @ w_conv2 + b) + inter[graph] -> TB
    gemm64n256_kernel<0><<<NN / 64, 512, 0, stream>>>(
        X2a, wc2t, tb, DH_, b_conv2, B0, inter_f, 1, 1,
        nullptr, nullptr, nullptr, nullptr, nullptr);

    // Fused QKV (N=768, MT=128): QKVb = tb @ [wq*s|wk|wv] + bqkv
    gemm_bf16_kernel<<<dim3(768 / 128, NN / 128), 512, 0, stream>>>(
        tb, wqkvt, QKVb, NN, DH_, 768, bqkv, nullptr, nullptr, 0, 0);

    // MFMA flash attention -> Ob (B0; h1b dead)
    attn_mfma_kernel<<<BG * NH, 256, 0, stream>>>(QKVb, B0);

    // O-proj (MODE 2): t2b = LN1(Ob @ wo + bo + tb) -> B0 in-place
    gemm64n256_kernel<2><<<NN / 64, 512, 0, stream>>>(
        B0, wot, B0, DH_, bo, tb, nullptr, 0, 0,
        nullptr, nullptr, ln1_g, ln1_b, nullptr);

    // ff1 (N=1024, MT=128): Fb = relu(t2b @ w_ff1 + b1)
    gemm_bf16_kernel<<<dim3(DFF_ / 128, NN / 128), 512, 0, stream>>>(
        B0, wf1t, Fb, NN, DH_, DFF_, b_ff1, nullptr, nullptr, 1, 0);

    // ff2 (MODE 3): LN2(Fb @ w_ff2 + b2 + t2b) -> per-graph column sums -> out
    gemm64n256_kernel<3><<<NN / 64, 512, 0, stream>>>(
        Fb, wf2t, nullptr, DFF_, b_ff2, B0, nullptr, 0, 0,
        nullptr, nullptr, ln2_g, ln2_b, out);
}